// Round 13
// baseline (937.377 us; speedup 1.0000x reference)
//
#include <hip/hip_runtime.h>

typedef unsigned int u32;
typedef unsigned short u16;
typedef short s16x8 __attribute__((ext_vector_type(8)));
typedef u16 u16x8 __attribute__((ext_vector_type(8)));
typedef float f32x4 __attribute__((ext_vector_type(4)));

#define FIN 384
#define HD  128
#define PD  128
#define RD  16

#define GLOAD16(g, l)                                                          \
  __builtin_amdgcn_global_load_lds(                                            \
      (const __attribute__((address_space(1))) void*)(g),                      \
      (__attribute__((address_space(3))) void*)(l), 16, 0, 0)

__device__ __forceinline__ u16 f2bf(float f) {
  u32 u = __float_as_uint(f);
  u32 r = (u + 0x7fffu + ((u >> 16) & 1u)) >> 16;   // RNE
  return (u16)r;
}
__device__ __forceinline__ float bf2f(u16 h) {
  return __uint_as_float(((u32)h) << 16);
}

// XCD-aware bijective block remap (m204): assumes dispatch XCD ~ blockIdx%8.
// Consecutive wgid -> ctile fastest, so each XCD gets complete row-panels.
__device__ __forceinline__ int xcd_wgid() {
  int nwg = gridDim.x, orig = blockIdx.x;
  int q = nwg >> 3, r = nwg & 7, xcd = orig & 7, idx = orig >> 3;
  return (xcd < r ? xcd * (q + 1) : r * (q + 1) + (xcd - r) * q) + idx;
}

// ---------------------------------------------------------------------------
// One descriptor-driven convert kernel for all weights + x.
// mode 0: transpose; mode 1: copy; mode 2: Wr2 Q-permute (q=h*16+r).
// ---------------------------------------------------------------------------
struct CvtEnt { const float* s; u16* d; int K, N, mode, blk0; };
struct CvtDesc { CvtEnt e[12]; int n; };

__global__ void cvt_all_k(CvtDesc dsc) {
  int b = blockIdx.x;
  int ei = 0;
  while (ei + 1 < dsc.n && dsc.e[ei + 1].blk0 <= b) ++ei;
  CvtEnt E = dsc.e[ei];
  int i = (b - E.blk0) * 256 + (int)threadIdx.x;
  int tot = E.K * E.N;
  if (i >= tot) return;
  float v;
  if (E.mode == 0) {
    int c = i / E.K, k = i - c * E.K;
    v = E.s[(size_t)k * E.N + c];
  } else if (E.mode == 1) {
    v = E.s[i];
  } else {
    int q = i / 384, f = i - q * 384;
    v = E.s[(size_t)(q >> 4) * 6144 + (q & 15) * 384 + f];
  }
  E.d[i] = f2bf(v);
}

// ---------------------------------------------------------------------------
// Graph preprocessing (concatenated src|dst arrays, one scan over 2n)
// ---------------------------------------------------------------------------
__global__ void hist_k(const int* __restrict__ src, const int* __restrict__ dst,
                       u32* __restrict__ cnt, int n, int E) {
  int i = blockIdx.x * 256 + threadIdx.x;
  if (i < E) {
    atomicAdd(&cnt[src[i]], 1u);
    atomicAdd(&cnt[n + dst[i]], 1u);
  }
}

__global__ __launch_bounds__(1024)
void scanA_k(const u32* __restrict__ cnt, u32* __restrict__ off,
             u32* __restrict__ bsum, int n2) {
  __shared__ u32 sh[1024];
  int i = blockIdx.x * 1024 + (int)threadIdx.x;
  u32 v = (i < n2) ? cnt[i] : 0u;
  sh[threadIdx.x] = v;
  __syncthreads();
  for (int s = 1; s < 1024; s <<= 1) {
    u32 t = (threadIdx.x >= (u32)s) ? sh[threadIdx.x - s] : 0u;
    __syncthreads();
    sh[threadIdx.x] += t;
    __syncthreads();
  }
  if (i < n2) off[i] = sh[threadIdx.x] - v;       // local exclusive
  if (threadIdx.x == 1023) bsum[blockIdx.x] = sh[1023];
}

__global__ void scanB_k(u32* __restrict__ bsum, int nb) {   // 1 wave, chunks of 64
  int l = threadIdx.x;
  u32 carry = 0u;
  for (int base = 0; base < nb; base += 64) {
    u32 v = (base + l < nb) ? bsum[base + l] : 0u;
    for (int s = 1; s < 64; s <<= 1) {
      u32 t = __shfl_up(v, s);
      if (l >= s) v += t;
    }
    if (base + l < nb) bsum[base + l] = v + carry;
    carry += __shfl(v, 63);
  }
}

__global__ __launch_bounds__(1024)
void scanC_k(u32* __restrict__ off, u32* __restrict__ cur,
             const u32* __restrict__ bsum, int n2) {
  int b = blockIdx.x;
  int i = b * 1024 + (int)threadIdx.x;
  if (i >= n2) return;
  u32 add = (b > 0) ? bsum[b - 1] : 0u;
  u32 o = off[i] + add;
  off[i] = o;
  cur[i] = o;
}

__global__ void fill_k(const int* __restrict__ src, const int* __restrict__ dst,
                       u32* __restrict__ cur, u32* __restrict__ adj, int n, int E) {
  int i = blockIdx.x * 256 + threadIdx.x;
  if (i >= E) return;
  int s = src[i], d = dst[i];
  u32 ps = atomicAdd(&cur[s], 1u);
  adj[ps] = (u32)d;
  u32 pd = atomicAdd(&cur[n + d], 1u);
  adj[pd] = (u32)s;
}

__global__ void dinv_k(const u32* __restrict__ cd, float* __restrict__ dinv, int n) {
  int i = blockIdx.x * 256 + threadIdx.x;
  if (i < n) dinv[i] = 1.0f / sqrtf((float)(cd[i] + 1u));
}

// ---------------------------------------------------------------------------
// GCN aggregation, bf16 in, fp32/bf16 out; 4-edge ILP
// ---------------------------------------------------------------------------
template <int WF32, int WBF>
__global__ void gcn_agg_k(const u16* __restrict__ xw, const float* __restrict__ dinv,
                          const u32* __restrict__ off, const u32* __restrict__ cnt,
                          const u32* __restrict__ nbr, const float* __restrict__ bias,
                          float* __restrict__ outf, u16* __restrict__ outb, int n) {
  int node = (blockIdx.x * blockDim.x + threadIdx.x) >> 6;
  int lane = threadIdx.x & 63;
  if (node >= n) return;
  float di = dinv[node];
  ushort2 v = ((const ushort2*)(xw + (size_t)node * HD))[lane];
  float ax = di * di * bf2f(v.x), ay = di * di * bf2f(v.y);
  u32 i = off[node], end = i + cnt[node];
  for (; i + 4 <= end; i += 4) {
    int s0 = (int)nbr[i],     s1 = (int)nbr[i + 1];
    int s2 = (int)nbr[i + 2], s3 = (int)nbr[i + 3];
    float w0 = di * dinv[s0], w1 = di * dinv[s1];
    float w2 = di * dinv[s2], w3 = di * dinv[s3];
    ushort2 u0 = ((const ushort2*)(xw + (size_t)s0 * HD))[lane];
    ushort2 u1 = ((const ushort2*)(xw + (size_t)s1 * HD))[lane];
    ushort2 u2 = ((const ushort2*)(xw + (size_t)s2 * HD))[lane];
    ushort2 u3 = ((const ushort2*)(xw + (size_t)s3 * HD))[lane];
    ax = fmaf(w0, bf2f(u0.x), ax); ay = fmaf(w0, bf2f(u0.y), ay);
    ax = fmaf(w1, bf2f(u1.x), ax); ay = fmaf(w1, bf2f(u1.y), ay);
    ax = fmaf(w2, bf2f(u2.x), ax); ay = fmaf(w2, bf2f(u2.y), ay);
    ax = fmaf(w3, bf2f(u3.x), ax); ay = fmaf(w3, bf2f(u3.y), ay);
  }
  for (; i < end; ++i) {
    int s0 = (int)nbr[i];
    float w0 = di * dinv[s0];
    ushort2 u0 = ((const ushort2*)(xw + (size_t)s0 * HD))[lane];
    ax = fmaf(w0, bf2f(u0.x), ax);
    ay = fmaf(w0, bf2f(u0.y), ay);
  }
  float2 b = ((const float2*)bias)[lane];
  ax += b.x; ay += b.y;
  if (WF32) ((float2*)(outf + (size_t)node * HD))[lane] = make_float2(ax, ay);
  if (WBF) {
    ushort2 ob; ob.x = f2bf(ax); ob.y = f2bf(ay);
    ((ushort2*)(outb + (size_t)node * HD))[lane] = ob;
  }
}

// ---------------------------------------------------------------------------
// Fused edge scores + scatter-softmax + aggregate + residual (one wave/node).
// Fast path (degree <= 64): scores kept in one register/lane, no global
// round-trip, exp computed once. Fallback = original 3-pass global path.
// ---------------------------------------------------------------------------
__global__ void attn_fused_k(const u32* __restrict__ off, const u32* __restrict__ cnt,
                             const u32* __restrict__ adj,
                             const u16* __restrict__ ti, int TS,
                             const u16* __restrict__ gi, int GS,
                             const u16* __restrict__ vmat, int VS,
                             const u16* __restrict__ xb,
                             float* __restrict__ scores,
                             u16* __restrict__ xf, int n) {
  int node = (blockIdx.x * blockDim.x + threadIdx.x) >> 6;
  int lane = threadIdx.x & 63;
  if (node >= n) return;
  u32 o = off[node], c = cnt[node];
  u32 end = o + c;
  float acc[6] = {0.f, 0.f, 0.f, 0.f, 0.f, 0.f};
  const float sc = 0.05103103630798288f;   // 1/sqrt(384)
  if (c > 0) {
    const u16* tp = ti + (size_t)node * TS;
    float tf[6];
#pragma unroll
    for (int q = 0; q < 3; ++q) {
      ushort2 tv = *(const ushort2*)(tp + q * 128 + lane * 2);
      tf[q * 2] = bf2f(tv.x);
      tf[q * 2 + 1] = bf2f(tv.y);
    }
    if (c <= 64) {
      // ---- fast path: per-lane register scores ----
      float sreg = -1e30f;
      u32 i = o;
      for (; i + 2 <= end; i += 2) {
        int d0 = (int)adj[i], d1 = (int)adj[i + 1];
        const u16* g0 = gi + (size_t)d0 * GS;
        const u16* g1 = gi + (size_t)d1 * GS;
        float dot0 = 0.f, dot1 = 0.f;
#pragma unroll
        for (int q = 0; q < 3; ++q) {
          ushort2 a = *(const ushort2*)(g0 + q * 128 + lane * 2);
          ushort2 b = *(const ushort2*)(g1 + q * 128 + lane * 2);
          dot0 = fmaf(tf[q * 2], bf2f(a.x), dot0);
          dot0 = fmaf(tf[q * 2 + 1], bf2f(a.y), dot0);
          dot1 = fmaf(tf[q * 2], bf2f(b.x), dot1);
          dot1 = fmaf(tf[q * 2 + 1], bf2f(b.y), dot1);
        }
#pragma unroll
        for (int s2 = 32; s2 >= 1; s2 >>= 1) {
          dot0 += __shfl_xor(dot0, s2);
          dot1 += __shfl_xor(dot1, s2);
        }
        int idx = (int)(i - o);
        if (lane == idx) sreg = dot0 * sc;
        if (lane == idx + 1) sreg = dot1 * sc;
      }
      if (i < end) {
        int d0 = (int)adj[i];
        const u16* g0 = gi + (size_t)d0 * GS;
        float dot0 = 0.f;
#pragma unroll
        for (int q = 0; q < 3; ++q) {
          ushort2 a = *(const ushort2*)(g0 + q * 128 + lane * 2);
          dot0 = fmaf(tf[q * 2], bf2f(a.x), dot0);
          dot0 = fmaf(tf[q * 2 + 1], bf2f(a.y), dot0);
        }
#pragma unroll
        for (int s2 = 32; s2 >= 1; s2 >>= 1) dot0 += __shfl_xor(dot0, s2);
        if (lane == (int)(i - o)) sreg = dot0 * sc;
      }
      float mx = sreg;
#pragma unroll
      for (int s2 = 32; s2 >= 1; s2 >>= 1) mx = fmaxf(mx, __shfl_xor(mx, s2));
      float ew = (lane < (int)c) ? expf(sreg - mx) : 0.f;
      float den = ew;
#pragma unroll
      for (int s2 = 32; s2 >= 1; s2 >>= 1) den += __shfl_xor(den, s2);
      float wreg = ew / den;
      i = o;
      for (; i + 2 <= end; i += 2) {
        int d0 = (int)adj[i], d1 = (int)adj[i + 1];
        int idx = (int)(i - o);
        float w0 = __shfl(wreg, idx);
        float w1 = __shfl(wreg, idx + 1);
        const u16* v0 = vmat + (size_t)d0 * VS;
        const u16* v1 = vmat + (size_t)d1 * VS;
#pragma unroll
        for (int q = 0; q < 3; ++q) {
          ushort2 a = *(const ushort2*)(v0 + q * 128 + lane * 2);
          ushort2 b = *(const ushort2*)(v1 + q * 128 + lane * 2);
          acc[q * 2]     = fmaf(w0, bf2f(a.x), acc[q * 2]);
          acc[q * 2 + 1] = fmaf(w0, bf2f(a.y), acc[q * 2 + 1]);
          acc[q * 2]     = fmaf(w1, bf2f(b.x), acc[q * 2]);
          acc[q * 2 + 1] = fmaf(w1, bf2f(b.y), acc[q * 2 + 1]);
        }
      }
      if (i < end) {
        int d0 = (int)adj[i];
        float w0 = __shfl(wreg, (int)(i - o));
        const u16* v0 = vmat + (size_t)d0 * VS;
#pragma unroll
        for (int q = 0; q < 3; ++q) {
          ushort2 a = *(const ushort2*)(v0 + q * 128 + lane * 2);
          acc[q * 2]     = fmaf(w0, bf2f(a.x), acc[q * 2]);
          acc[q * 2 + 1] = fmaf(w0, bf2f(a.y), acc[q * 2 + 1]);
        }
      }
    } else {
      // ---- fallback: 3-pass global scores (degree > 64) ----
      float mx = -1e30f;
      u32 i = o;
      for (; i < end; ++i) {
        int d0 = (int)adj[i];
        const u16* g0 = gi + (size_t)d0 * GS;
        float dot0 = 0.f;
#pragma unroll
        for (int q = 0; q < 3; ++q) {
          ushort2 a = *(const ushort2*)(g0 + q * 128 + lane * 2);
          dot0 = fmaf(tf[q * 2], bf2f(a.x), dot0);
          dot0 = fmaf(tf[q * 2 + 1], bf2f(a.y), dot0);
        }
#pragma unroll
        for (int s2 = 32; s2 >= 1; s2 >>= 1) dot0 += __shfl_xor(dot0, s2);
        dot0 *= sc;
        if (lane == 0) scores[i] = dot0;
        mx = fmaxf(mx, dot0);
      }
      float den = 0.f;
      for (u32 k = o + lane; k < end; k += 64) den += expf(scores[k] - mx);
#pragma unroll
      for (int s2 = 32; s2 >= 1; s2 >>= 1) den += __shfl_xor(den, s2);
      float invden = 1.0f / den;
      for (i = o; i < end; ++i) {
        int d0 = (int)adj[i];
        float w0 = expf(scores[i] - mx) * invden;
        const u16* v0 = vmat + (size_t)d0 * VS;
#pragma unroll
        for (int q = 0; q < 3; ++q) {
          ushort2 a = *(const ushort2*)(v0 + q * 128 + lane * 2);
          acc[q * 2]     = fmaf(w0, bf2f(a.x), acc[q * 2]);
          acc[q * 2 + 1] = fmaf(w0, bf2f(a.y), acc[q * 2 + 1]);
        }
      }
    }
  }
  const u16* xp = xb + (size_t)node * FIN;
  u16* op = xf + (size_t)node * FIN;
#pragma unroll
  for (int q = 0; q < 3; ++q) {
    ushort2 xv = *(const ushort2*)(xp + q * 128 + lane * 2);
    ushort2 ov;
    ov.x = f2bf(acc[q * 2] + bf2f(xv.x));
    ov.y = f2bf(acc[q * 2 + 1] + bf2f(xv.y));
    *(ushort2*)(op + q * 128 + lane * 2) = ov;
  }
}

// ---------------------------------------------------------------------------
// MFMA bf16 GEMM (2-phase 128x128), 1-D grid + XCD swizzle (T1).
// EPI 0/1/2: none / +bias / relu(+bias); split-bias at bsplit.
// EPI 4 (left): temp preloaded into registers BEFORE the K-loop (hides L2
//   latency under MFMA); slice-stream bf16 ptP[ctile][row][wc*4+j].
// EPI 6 (tv+gcn1 merged, Nc=896): col<768 -> Cp; col>=768 -> Cbf2.
// ---------------------------------------------------------------------------
template <int EPI, int OUTBF>
__global__ __launch_bounds__(256)
void mgemm_k(const u16* __restrict__ Abf, int As, const u16* __restrict__ WT,
             const float* __restrict__ bias, const float* __restrict__ bias_b, int bsplit,
             void* __restrict__ Cp, u16* __restrict__ Cbf2,
             float* __restrict__ tmp, int M, int K, int Nc, int ncx) {
  __shared__ u16 Albuf[2][128 * 32];
  __shared__ u16 Blbuf[2][128 * 32];
  const int t = threadIdx.x;
  const int lane = t & 63;
  const int wave = t >> 6;
  const int wr = wave >> 1, wc = wave & 1;
  const int wgid = xcd_wgid();
  const int ctile = wgid % ncx;
  const int row0 = (wgid / ncx) * 128;
  const int col0 = ctile * 128;
  const int sr = t >> 2;
  const int sk = (t & 3) * 8;
  const int nt = K >> 5;

  f32x4 acc[4][4] = {};

  // EPI4: preload temp for all 16 (m,r) rows; completes under the K-loop.
  float tvp[16];
  if constexpr (EPI == 4) {
#pragma unroll
    for (int mr = 0; mr < 16; ++mr) {
      int row = row0 + wr * 64 + (mr >> 2) * 16 + (lane >> 4) * 4 + (mr & 3);
      tvp[mr] = (row < M) ? tmp[(size_t)row * RD + (lane & 15)] : 0.f;
    }
  }

  auto stage = [&](int buf, int k0) {
#pragma unroll
    for (int h = 0; h < 2; ++h) {
      int ar = row0 + h * 64 + sr;
      if (ar >= M) ar = M - 1;
      GLOAD16(Abf + (size_t)ar * As + k0 + sk, &Albuf[buf][h * 2048 + wave * 512]);
    }
#pragma unroll
    for (int h = 0; h < 2; ++h) {
      int bc = col0 + h * 64 + sr;
      if (bc >= Nc) bc = Nc - 1;
      GLOAD16(WT + (size_t)bc * K + k0 + sk, &Blbuf[buf][h * 2048 + wave * 512]);
    }
  };

  stage(0, 0);
  int buf = 0;
  for (int tk = 0; tk < nt; ++tk) {
    __syncthreads();
    if (tk + 1 < nt) stage(buf ^ 1, (tk + 1) << 5);
    const u16* Al = Albuf[buf];
    const u16* Bl = Blbuf[buf];
    s16x8 a[4], b[4];
#pragma unroll
    for (int m = 0; m < 4; ++m)
      a[m] = *(const s16x8*)(Al + (wr * 64 + m * 16 + (lane & 15)) * 32 + (lane >> 4) * 8);
#pragma unroll
    for (int j = 0; j < 4; ++j)
      b[j] = *(const s16x8*)(Bl + (wc * 64 + j * 16 + (lane & 15)) * 32 + (lane >> 4) * 8);
#pragma unroll
    for (int m = 0; m < 4; ++m)
#pragma unroll
      for (int j = 0; j < 4; ++j)
        acc[m][j] = __builtin_amdgcn_mfma_f32_16x16x32_bf16(a[m], b[j], acc[m][j], 0, 0, 0);
    buf ^= 1;
  }

  if constexpr (EPI <= 2) {
#pragma unroll
    for (int m = 0; m < 4; ++m) {
      int rbase = row0 + wr * 64 + m * 16 + (lane >> 4) * 4;
#pragma unroll
      for (int j = 0; j < 4; ++j) {
        int col = col0 + wc * 64 + j * 16 + (lane & 15);
        if (col >= Nc) continue;
        float bv = 0.f;
        if (EPI >= 1) bv = (col < bsplit) ? bias[col] : bias_b[col - bsplit];
#pragma unroll
        for (int r = 0; r < 4; ++r) {
          int row = rbase + r;
          if (row >= M) continue;
          float v = acc[m][j][r] + bv;
          if (EPI == 2) v = fmaxf(v, 0.f);
          if (OUTBF) ((u16*)Cp)[(size_t)row * Nc + col] = f2bf(v);
          else       ((float*)Cp)[(size_t)row * Nc + col] = v;
        }
      }
    }
  } else if constexpr (EPI == 6) {
#pragma unroll
    for (int m = 0; m < 4; ++m) {
      int rbase = row0 + wr * 64 + m * 16 + (lane >> 4) * 4;
#pragma unroll
      for (int j = 0; j < 4; ++j) {
        int col = col0 + wc * 64 + j * 16 + (lane & 15);
        if (col < 2 * FIN) {
          float bv = (col < bsplit) ? bias[col] : bias_b[col - bsplit];
#pragma unroll
          for (int r = 0; r < 4; ++r) {
            int row = rbase + r;
            if (row >= M) continue;
            ((u16*)Cp)[(size_t)row * (2 * FIN) + col] = f2bf(acc[m][j][r] + bv);
          }
        } else {
          int c2 = col - 2 * FIN;
#pragma unroll
          for (int r = 0; r < 4; ++r) {
            int row = rbase + r;
            if (row >= M) continue;
            Cbf2[(size_t)row * HD + c2] = f2bf(acc[m][j][r]);
          }
        }
      }
    }
  } else {  // EPI == 4: bf16 slice-stream to ptP[ctile][row][wc*4+j]
    u16* slice = (u16*)Cp + (size_t)ctile * M * 8;
#pragma unroll
    for (int m = 0; m < 4; ++m) {
#pragma unroll
      for (int r = 0; r < 4; ++r) {
        int row = row0 + wr * 64 + m * 16 + (lane >> 4) * 4 + r;
        float tv = tvp[m * 4 + r];
#pragma unroll
        for (int j = 0; j < 4; ++j) {
          float s = (acc[m][j][r] + bias[col0 + wc * 64 + j * 16 + (lane & 15)]) * tv;
          s += __shfl_xor(s, 1); s += __shfl_xor(s, 2);
          s += __shfl_xor(s, 4); s += __shfl_xor(s, 8);
          if ((lane & 15) == 0 && row < M)
            slice[(size_t)row * 8 + wc * 4 + j] = f2bf(s);
        }
      }
    }
  }
}

// ---------------------------------------------------------------------------
// pt gather: pt[row][ct*8+pl] = bf2f(ptP[ct][row][pl]); coalesced full rows,
// fp32 + bf16 outputs.
// ---------------------------------------------------------------------------
__global__ void ptgather_k(const u16* __restrict__ ptP, float* __restrict__ pt,
                           u16* __restrict__ ptb, int n) {
  int g = blockIdx.x * 256 + threadIdx.x;
  if (g >= n * 16) return;
  int row = g >> 4, ct = g & 15;
  const u16* sp = ptP + ((size_t)ct * n + (size_t)row) * 8;
  ushort4 a = ((const ushort4*)sp)[0];
  ushort4 b = ((const ushort4*)sp)[1];
  float* dp = pt + (size_t)row * PD + ct * 8;
  ((float4*)dp)[0] = make_float4(bf2f(a.x), bf2f(a.y), bf2f(a.z), bf2f(a.w));
  ((float4*)dp)[1] = make_float4(bf2f(b.x), bf2f(b.y), bf2f(b.z), bf2f(b.w));
  u16* db = ptb + (size_t)row * PD + ct * 8;
  ((ushort4*)db)[0] = a;
  ((ushort4*)db)[1] = b;
}

// ---------------------------------------------------------------------------
// Y-GEMM, 8-phase 256x256/BK=64/8-wave (T3+T4+T2+T5), race-verified (r8),
// 1-D grid + XCD swizzle (ncx=12 col-groups).
// ---------------------------------------------------------------------------
#define VM6  asm volatile("s_waitcnt vmcnt(6)" ::: "memory")
#define VM0  asm volatile("s_waitcnt vmcnt(0)" ::: "memory")
#define VMNOP
#define BARR asm volatile("s_barrier" ::: "memory")

__global__ __launch_bounds__(512)
void ygemm8_k(const u16* __restrict__ X, const u16* __restrict__ QT,
              const u16* __restrict__ Ar, float* __restrict__ tmpP, int M) {
  __shared__ u16 Al[2][16384];
  __shared__ u16 Bl[2][16384];
  const int t = threadIdx.x;
  const int lane = t & 63;
  const int wave = t >> 6;
  const int wr = wave >> 2;
  const int wcn = wave & 3;
  const int wgid = xcd_wgid();
  const int ctile = wgid % 12;
  const int row0 = (wgid / 12) * 256;
  const int col0 = ctile * 256;

  const int srow = t >> 3;
  const int sgk  = (((t & 7) ^ (srow & 7)) << 3);
  const int sdst = t * 8;

  const int pc0 = (((lane >> 4)) ^ (lane & 7)) << 3;
  const int pc1 = ((((lane >> 4) + 4)) ^ (lane & 7)) << 3;
  const int arow = (wr * 128 + (lane & 15)) << 6;
  const int brow = (wcn * 64 + (lane & 15)) << 6;

  f32x4 acc[8][4] = {};
  s16x8 a[4][2], b[4][2];

#define STGA8(bf, h, kt) do {                                                  \
    int r0_ = row0 + (h) * 128 + srow;                                         \
    int r1_ = r0_ + 64;                                                        \
    if (r0_ >= M) r0_ = M - 1;                                                 \
    if (r1_ >= M) r1_ = M - 1;                                                 \
    GLOAD16(X + (size_t)r0_ * 384 + (kt) * 64 + sgk, &Al[bf][(h) * 8192 + sdst]);        \
    GLOAD16(X + (size_t)r1_ * 384 + (kt) * 64 + sgk, &Al[bf][(h) * 8192 + 4096 + sdst]); \
  } while (0)

#define STGB8(bf, h, kt) do {                                                  \
    int c0_ = col0 + (h) * 128 + srow;                                         \
    GLOAD16(QT + (size_t)c0_ * 384 + (kt) * 64 + sgk, &Bl[bf][(h) * 8192 + sdst]);       \
    GLOAD16(QT + (size_t)(c0_ + 64) * 384 + (kt) * 64 + sgk,                   \
            &Bl[bf][(h) * 8192 + 4096 + sdst]);                                \
  } while (0)

#define LDA8(bf, mh) do {                                                      \
    _Pragma("unroll") for (int m2_ = 0; m2_ < 4; ++m2_) {                      \
      const u16* p_ = &Al[bf][arow + ((mh) * 4 + m2_) * 1024];                 \
      a[m2_][0] = *(const s16x8*)(p_ + pc0);                                   \
      a[m2_][1] = *(const s16x8*)(p_ + pc1);                                   \
    }                                                                          \
  } while (0)

#define LDB8(bf, jh) do {                                                      \
    _Pragma("unroll") for (int j2_ = 0; j2_ < 2; ++j2_) {                      \
      const u16* p_ = &Bl[bf][brow + ((jh) * 2 + j2_) * 1024];                 \
      b[(jh) * 2 + j2_][0] = *(const s16x8*)(p_ + pc0);                        \
      b[(jh) * 2 + j2_][1] = *(const s16x8*)(p_ + pc1);                        \
    }                                                                          \
  } while (0)

#define MQ8(mh, jh) do {                                                       \
    __builtin_amdgcn_s_setprio(1);                                             \
    _Pragma("unroll") for (int m2_ = 0; m2_ < 4; ++m2_)                        \
      _Pragma("unroll") for (int j2_ = 0; j2_ < 2; ++j2_)                      \
        _Pragma("unroll") for (int ks_ = 0; ks_ < 2; ++ks_)                    \
          acc[(mh) * 4 + m2_][(jh) * 2 + j2_] =                                \
              __builtin_amdgcn_mfma_f32_16x16x32_bf16(                         \
                  a[m2_][ks_], b[(jh) * 2 + j2_][ks_],                         \
                  acc[(mh) * 4 + m2_][(jh) * 2 + j2_], 0, 0, 0);               \
    __builtin_amdgcn_s_setprio(0);                                             \
  } while (0)

  STGA8(0, 0, 0); STGA8(0, 1, 0); STGB8(0, 0, 0); STGB8(0, 1, 0);
  STGA8(1, 0, 1); STGB8(1, 0, 1); STGB8(1, 1, 1);
  VM6; BARR;

#define ITER8(i, VMP3, VMP7, DOSTG)                                                          \
  /*ph0*/ LDA8(0,0); LDB8(0,0); STGA8(1,1,2*(i)+1);                   BARR; MQ8(0,0); BARR;  \
  /*ph1*/ LDB8(0,1);                                                  BARR; MQ8(0,1); BARR;  \
  /*ph2*/ LDA8(0,1); if (DOSTG) STGB8(0,0,2*(i)+2);                   BARR; MQ8(1,0); BARR;  \
  /*ph3*/ if (DOSTG) { STGB8(0,1,2*(i)+2); STGA8(0,0,2*(i)+2); } VMP3; BARR; MQ8(1,1); BARR; \
  /*ph4*/ LDA8(1,0); LDB8(1,0); if (DOSTG) STGA8(0,1,2*(i)+2);        BARR; MQ8(0,0); BARR;  \
  /*ph5*/ LDB8(1,1);                                                  BARR; MQ8(0,1); BARR;  \
  /*ph6*/ LDA8(1,1); if (DOSTG) STGB8(1,0,2*(i)+3);                   BARR; MQ8(1,0); BARR;  \
  /*ph7*/ if (DOSTG) { STGB8(1,1,2*(i)+3); STGA8(1,0,2*(i)+3); } VMP7; BARR; MQ8(1,1); BARR;

  ITER8(0, VM6, VM6, 1)
  ITER8(1, VM6, VM6, 1)
  ITER8(2, VM0, VMNOP, 0)

  // fold: s[m][rr] = sum_j relu_r[row, h0+j] * acc[m][j][rr]
  const int h0 = (col0 >> 4) + wcn * 4;
  float s[8][4];
#pragma unroll
  for (int m = 0; m < 8; ++m) {
#pragma unroll
    for (int rr = 0; rr < 4; ++rr) {
      int row = row0 + wr * 128 + m * 16 + (lane >> 4) * 4 + rr;
      int rc = row < M ? row : M - 1;
      ushort4 arv = *(const ushort4*)(Ar + (size_t)rc * 384 + h0);
      s[m][rr] = bf2f(arv.x) * acc[m][0][rr] + bf2f(arv.y) * acc[m][1][rr] +
                 bf2f(arv.z) * acc[m][2][rr] + bf2f(arv.w) * acc[m][3][rr];
    }
  }

  __syncthreads();
  float* redA = (float*)&Al[0][0];
  float* redB = redA + 4096;
  const int r16 = lane & 15;
  const int rlb = wr * 128 + (lane >> 4) * 4;
  if (wcn & 1) {
    float* red = (wcn == 1) ? redA : redB;
#pragma unroll
    for (int m = 0; m < 8; ++m)
#pragma unroll
      for (int rr = 0; rr < 4; ++rr)
        red[(rlb + m * 16 + rr) * 16 + r16] = s[m][rr];
  }
  __syncthreads();
  if (!(wcn & 1)) {
    float* red = (wcn == 0) ? redA : redB;
#pragma unroll
    for (int m = 0; m < 8; ++m)
#pragma unroll
      for (int rr = 0; rr < 4; ++rr)
        s[m][rr] += red[(rlb + m * 16 + rr) * 16 + r16];
  }
  __syncthreads();
  if (wcn == 2) {
#pragma unroll
    for (int m = 0; m < 8; ++m)
#pragma unroll
      for (int rr = 0; rr < 4; ++rr)
        redA[(rlb + m * 16 + rr) * 16 + r16] = s[m][rr];
  }
  __syncthreads();
  if (wcn == 0) {
    float* slice = tmpP + (size_t)ctile * M * RD;
#pragma unroll
    for (int m = 0; m < 8; ++m)
#pragma unroll
      for (int rr = 0; rr < 4; ++rr) {
        int row = row0 + rlb + m * 16 + rr;
        if (row < M)
          slice[(size_t)row * RD + r16] =
              s[m][rr] + redA[(rlb + m * 16 + rr) * 16 + r16];
      }
  }
#undef STGA8
#undef STGB8
#undef LDA8
#undef LDB8
#undef MQ8
#undef ITER8
}

// ---------------------------------------------------------------------------
// combine: temp[i] = sum_{s=0..12} tmpP[s][i]   (slice 12 = x@Br bias term)
// ---------------------------------------------------------------------------
__global__ void combine_k(const float* __restrict__ tmpP, float* __restrict__ temp,
                          size_t sl, int tot4) {
  int i = blockIdx.x * 256 + threadIdx.x;
  if (i >= tot4) return;
  float4 s = ((const float4*)(tmpP + 12 * sl))[i];
#pragma unroll
  for (int c = 0; c < 12; ++c) {
    float4 p = ((const float4*)(tmpP + (size_t)c * sl))[i];
    s.x += p.x; s.y += p.y; s.z += p.z; s.w += p.w;
  }
  ((float4*)temp)[i] = s;
}

// ---------------------------------------------------------------------------
// Final: in-place row-normalize p_t, p_g; alignment = dot of normalized rows.
// ---------------------------------------------------------------------------
__global__ void final_k(float* __restrict__ out, int n) {
  int node = (blockIdx.x * blockDim.x + threadIdx.x) >> 6;
  int lane = threadIdx.x & 63;
  if (node >= n) return;
  float* pt = out + n + (size_t)node * PD;
  float* pg = out + n + (size_t)n * PD + (size_t)node * PD;
  float2 t = ((float2*)pt)[lane];
  float2 g = ((float2*)pg)[lane];
  float tt = t.x * t.x + t.y * t.y;
  float gg = g.x * g.x + g.y * g.y;
  float tg = t.x * g.x + t.y * g.y;
#pragma unroll
  for (int s = 32; s >= 1; s >>= 1) {
    tt += __shfl_xor(tt, s);
    gg += __shfl_xor(gg, s);
    tg += __shfl_xor(tg, s);
  }
  float invt = 1.0f / fmaxf(sqrtf(tt), 1e-12f);
  float invg = 1.0f / fmaxf(sqrtf(gg), 1e-12f);
  ((float2*)pt)[lane] = make_float2(t.x * invt, t.y * invt);
  ((float2*)pg)[lane] = make_float2(g.x * invg, g.y * invg);
  if (lane == 0) out[node] = tg * invt * invg;
}

// ---------------------------------------------------------------------------
struct MgArgs {
  const u16* A; int As; const u16* WT;
  const float* b; const float* b2; int bsplit;
  void* C; u16* C2; float* tmp;
  int M, K, Nc;
};
template <int EPI, int OUTBF>
static void mg(const MgArgs& a, hipStream_t s) {
  int ncx = (a.Nc + 127) / 128, nry = (a.M + 127) / 128;
  mgemm_k<EPI, OUTBF><<<dim3(ncx * nry), 256, 0, s>>>(
      a.A, a.As, a.WT, a.b, a.b2, a.bsplit, a.C, a.C2, a.tmp,
      a.M, a.K, a.Nc, ncx);
}

extern "C" void kernel_launch(void* const* d_in, const int* in_sizes, int n_in,
                              void* d_out, int out_size, void* d_ws, size_t ws_size,
                              hipStream_t stream) {
  const float* x      = (const float*)d_in[0];
  const int*   ei     = (const int*)d_in[1];
  const float* W_gcn1 = (const float*)d_in[2];
  const float* b_gcn1 = (const float*)d_in[3];
  const float* W_ti   = (const float*)d_in[4];
  const float* b_ti   = (const float*)d_in[5];
  const float* W_gi   = (const float*)d_in[6];
  const float* b_gi   = (const float*)d_in[7];
  const float* W_v    = (const float*)d_in[8];
  const float* b_v    = (const float*)d_in[9];
  const float* Wl1    = (const float*)d_in[10];
  const float* bl1    = (const float*)d_in[11];
  const float* Wl2    = (const float*)d_in[12];
  const float* bl2    = (const float*)d_in[13];
  const float* Wr1    = (const float*)d_in[14];
  const float* br1    = (const float*)d_in[15];
  const float* Wr2    = (const float*)d_in[16];
  const float* br2    = (const float*)d_in[17];
  const float* W_gcn2 = (const float*)d_in[18];
  const float* b_gcn2 = (const float*)d_in[19];
  const float* W_gp   = (const float*)d_in[20];
  const float* b_gp   = (const float*)d_in[21];

  const int n = in_sizes[0] / FIN;   // 50000
  const int E = in_sizes[1] / 2;     // 500000
  const int* src = ei;
  const int* dst = ei + E;

  // -------- workspace carve (tmpP/ptP overlay gibf+xfbf) --------
  char* wsp = (char*)d_ws;
  auto carve = [&](size_t bytes) -> void* {
    void* p = (void*)wsp;
    wsp += (bytes + 255) & ~(size_t)255;
    return p;
  };
  u32* cnt      = (u32*)carve((size_t)2 * n * 4);   // [src | dst]
  u32* off      = (u32*)carve((size_t)2 * n * 4);
  u32* cur      = (u32*)carve((size_t)2 * n * 4);
  u32* bsum     = (u32*)carve(512);
  u32* adj      = (u32*)carve((size_t)2 * E * 4);   // [src-CSR dsts | dst-CSR srcs]
  float* dinv   = (float*)carve((size_t)n * 4);
  float* scores = (float*)carve((size_t)E * 4);
  float* temp   = (float*)carve((size_t)n * RD * 4);

  u16* xbf    = (u16*)carve((size_t)n * FIN * 2);       // x bf16 (pristine)
  u16* tvbf   = (u16*)carve((size_t)n * 2 * FIN * 2);   // [t_info | v]; later lrbf
  u16* bufHbf = (u16*)carve((size_t)n * HD * 2);        // xw (both GCNs)
  u16* gembf  = (u16*)carve((size_t)n * HD * 2);
  u16* ptbf   = (u16*)carve((size_t)n * PD * 2);
  u16* g2bf   = (u16*)carve((size_t)n * HD * 2);

  // gibf and xfbf adjacent; tmpP (13 x n*16 fp32 = 41.6 MB) overlays them;
  // ptP (16 x n*8 bf16 = 12.8 MB) reuses the same region after combine.
  u16* gibf   = (u16*)carve((size_t)n * FIN * 2);       // g_info
  u16* xfbf   = (u16*)carve((size_t)n * FIN * 2);       // x_fused
  size_t tmpP_bytes = (size_t)13 * n * RD * 4;
  size_t overlay    = (size_t)2 * n * FIN * 2;
  carve(tmpP_bytes > overlay ? tmpP_bytes - overlay : 0);
  float* tmpP = (float*)gibf;
  u16* ptP    = (u16*)gibf;   // reused after combine_k (slices dead)

  u16* WtvT   = (u16*)carve((size_t)2 * FIN * FIN * 2); // [768][384]
  u16* WgcnT  = (u16*)carve((size_t)HD * FIN * 2);      // [128][384], contiguous
  u16* WgiT   = (u16*)carve((size_t)FIN * HD * 2);      // [384][128]
  u16* WlrT   = (u16*)carve((size_t)FIN * FIN * 2);     // [384][384]
  u16* Wl2T   = (u16*)carve((size_t)2048 * 192 * 2);
  u16* QT     = (u16*)carve((size_t)3072 * FIN * 2);    // permuted Wr2
  u16* BrT    = (u16*)carve((size_t)RD * FIN * 2);      // br2 reshaped [16][384]
  u16* Wgcn2T = (u16*)carve((size_t)HD * PD * 2);
  u16* WgpT   = (u16*)carve((size_t)PD * PD * 2);

  u16* lrbf = tvbf;   // [relu_l | relu_r], stride 384; tv dead after attn

  float* out    = (float*)d_out;
  float* pt_raw = out + n;
  float* pg_raw = out + n + (size_t)n * PD;
  float* g2     = out + n + (size_t)2 * n * PD;

  // 0) all converts in one launch
  CvtDesc dsc;
  int nent = 0, blk = 0;
  auto addent = [&](const float* s, u16* d, int K, int N, int mode) {
    dsc.e[nent] = {s, d, K, N, mode, blk};
    blk += (K * N + 255) / 256;
    ++nent;
  };
  addent(x,      xbf,    n * FIN, 1, 1);
  addent(W_ti,   WtvT,   FIN, FIN, 0);
  addent(W_v,    WtvT + (size_t)FIN * FIN, FIN, FIN, 0);
  addent(W_gcn1, WgcnT,  FIN, HD,  0);
  addent(W_gi,   WgiT,   HD,  FIN, 0);
  addent(Wl1,    WlrT,   FIN, 192, 0);
  addent(Wr1,    WlrT + (size_t)192 * FIN, FIN, 192, 0);
  addent(Wl2,    Wl2T,   192, 2048, 0);
  addent(Wr2,    QT,     FIN, 3072, 2);
  addent(br2,    BrT,    RD * FIN, 1, 1);
  addent(W_gcn2, Wgcn2T, PD, HD, 0);
  addent(W_gp,   WgpT,   PD, PD, 0);
  dsc.n = nent;
  cvt_all_k<<<blk, 256, 0, stream>>>(dsc);

  // 1) CSR build + degrees (one concatenated scan over 2n)
  hipMemsetAsync(cnt, 0, (size_t)2 * n * 4, stream);
  hist_k<<<(E + 255) / 256, 256, 0, stream>>>(src, dst, cnt, n, E);
  int n2 = 2 * n;
  int nb = (n2 + 1023) / 1024;
  scanA_k<<<nb, 1024, 0, stream>>>(cnt, off, bsum, n2);
  scanB_k<<<1, 64, 0, stream>>>(bsum, nb);
  scanC_k<<<nb, 1024, 0, stream>>>(off, cur, bsum, n2);
  fill_k<<<(E + 255) / 256, 256, 0, stream>>>(src, dst, cur, adj, n, E);
  dinv_k<<<(n + 255) / 256, 256, 0, stream>>>(cnt + n, dinv, n);

  MgArgs a{};

  // 2+3a) merged GEMM: [t_info | v | xw_gcn1], Nc=896 (EPI 6)
  a = {xbf, FIN, WtvT, b_ti, b_v, FIN, tvbf, bufHbf, nullptr, n, FIN, 896};
  mg<6, 1>(a, stream);
  gcn_agg_k<0, 1><<<(n + 3) / 4, 256, 0, stream>>>(bufHbf, dinv, off + n, cnt + n, adj,
                                                   b_gcn1, nullptr, gembf, n);

  // 3b) g_info GEMM; fused scores+softmax+aggregate+residual
  a = {gembf, HD, WgiT, b_gi, nullptr, 1 << 30, gibf, nullptr, nullptr, n, HD, FIN};
  mg<1, 1>(a, stream);
  attn_fused_k<<<(n + 3) / 4, 256, 0, stream>>>(off, cnt, adj, tvbf, 2 * FIN, gibf, FIN,
                                                tvbf + FIN, 2 * FIN, xbf, scores, xfbf, n);

  // 4) Generators: [relu_l | relu_r] in one GEMM (overwrites tv buffer)
  a = {xfbf, FIN, WlrT, bl1, br1, 192, lrbf, nullptr, nullptr, n, FIN, FIN};
  mg<2, 1>(a, stream);

  // right path: x@Br into tmpP slice 12, 8-phase Y-GEMM partials into 0..11,
  // combine -> temp. (gibf/xfbf dead from here.)
  a = {xbf, FIN, BrT, nullptr, nullptr, 1 << 30, tmpP + (size_t)12 * n * RD, nullptr,
       nullptr, n, FIN, RD};
  mg<0, 0>(a, stream);
  ygemm8_k<<<dim3(12 * ((n + 255) / 256)), 512, 0, stream>>>(xbf, QT, lrbf + 192,
                                                             tmpP, n);
  combine_k<<<(n * RD / 4 + 255) / 256, 256, 0, stream>>>(tmpP, temp, (size_t)n * RD,
                                                          n * RD / 4);

  // left path fused: bf16 slice-streamed partials -> ptP[16][n][8], gather
  a = {lrbf, FIN, Wl2T, bl2, nullptr, 1 << 30, ptP, nullptr, temp, n, 192, PD * RD};
  mg<4, 0>(a, stream);
  ptgather_k<<<(n * 16 + 255) / 256, 256, 0, stream>>>(ptP, pt_raw, ptbf, n);

  // 5) GCN2 + projection
  a = {ptbf, PD, Wgcn2T, nullptr, nullptr, 1 << 30, bufHbf, nullptr, nullptr, n, PD, HD};
  mg<0, 1>(a, stream);
  gcn_agg_k<1, 1><<<(n + 3) / 4, 256, 0, stream>>>(bufHbf, dinv, off + n, cnt + n, adj,
                                                   b_gcn2, g2, g2bf, n);
  a = {g2bf, HD, WgpT, b_gp, nullptr, 1 << 30, pg_raw, nullptr, nullptr, n, HD, PD};
  mg<1, 0>(a, stream);

  // 6) normalize + alignment
  final_k<<<(n + 3) / 4, 256, 0, stream>>>(out, n);
}

// Round 14
// 907.908 us; speedup vs baseline: 1.0325x; 1.0325x over previous
//
#include <hip/hip_runtime.h>

typedef unsigned int u32;
typedef unsigned short u16;
typedef short s16x8 __attribute__((ext_vector_type(8)));
typedef u16 u16x8 __attribute__((ext_vector_type(8)));
typedef float f32x4 __attribute__((ext_vector_type(4)));

#define FIN 384
#define HD  128
#define PD  128
#define RD  16

#define GLOAD16(g, l)                                                          \
  __builtin_amdgcn_global_load_lds(                                            \
      (const __attribute__((address_space(1))) void*)(g),                      \
      (__attribute__((address_space(3))) void*)(l), 16, 0, 0)

__device__ __forceinline__ u16 f2bf(float f) {
  u32 u = __float_as_uint(f);
  u32 r = (u + 0x7fffu + ((u >> 16) & 1u)) >> 16;   // RNE
  return (u16)r;
}
__device__ __forceinline__ float bf2f(u16 h) {
  return __uint_as_float(((u32)h) << 16);
}

// XCD-aware bijective block remap (m204): assumes dispatch XCD ~ blockIdx%8.
// Consecutive wgid -> ctile fastest, so each XCD gets complete row-panels.
__device__ __forceinline__ int xcd_wgid() {
  int nwg = gridDim.x, orig = blockIdx.x;
  int q = nwg >> 3, r = nwg & 7, xcd = orig & 7, idx = orig >> 3;
  return (xcd < r ? xcd * (q + 1) : r * (q + 1) + (xcd - r) * q) + idx;
}

// ---------------------------------------------------------------------------
// One descriptor-driven convert kernel for all weights + x.
// mode 0: transpose; mode 1: copy; mode 2: Wr2 Q-permute (q=h*16+r).
// ---------------------------------------------------------------------------
struct CvtEnt { const float* s; u16* d; int K, N, mode, blk0; };
struct CvtDesc { CvtEnt e[12]; int n; };

__global__ void cvt_all_k(CvtDesc dsc) {
  int b = blockIdx.x;
  int ei = 0;
  while (ei + 1 < dsc.n && dsc.e[ei + 1].blk0 <= b) ++ei;
  CvtEnt E = dsc.e[ei];
  int i = (b - E.blk0) * 256 + (int)threadIdx.x;
  int tot = E.K * E.N;
  if (i >= tot) return;
  float v;
  if (E.mode == 0) {
    int c = i / E.K, k = i - c * E.K;
    v = E.s[(size_t)k * E.N + c];
  } else if (E.mode == 1) {
    v = E.s[i];
  } else {
    int q = i / 384, f = i - q * 384;
    v = E.s[(size_t)(q >> 4) * 6144 + (q & 15) * 384 + f];
  }
  E.d[i] = f2bf(v);
}

// ---------------------------------------------------------------------------
// Graph preprocessing (concatenated src|dst arrays, one scan over 2n)
// ---------------------------------------------------------------------------
__global__ void hist_k(const int* __restrict__ src, const int* __restrict__ dst,
                       u32* __restrict__ cnt, int n, int E) {
  int i = blockIdx.x * 256 + threadIdx.x;
  if (i < E) {
    atomicAdd(&cnt[src[i]], 1u);
    atomicAdd(&cnt[n + dst[i]], 1u);
  }
}

__global__ __launch_bounds__(1024)
void scanA_k(const u32* __restrict__ cnt, u32* __restrict__ off,
             u32* __restrict__ bsum, int n2) {
  __shared__ u32 sh[1024];
  int i = blockIdx.x * 1024 + (int)threadIdx.x;
  u32 v = (i < n2) ? cnt[i] : 0u;
  sh[threadIdx.x] = v;
  __syncthreads();
  for (int s = 1; s < 1024; s <<= 1) {
    u32 t = (threadIdx.x >= (u32)s) ? sh[threadIdx.x - s] : 0u;
    __syncthreads();
    sh[threadIdx.x] += t;
    __syncthreads();
  }
  if (i < n2) off[i] = sh[threadIdx.x] - v;       // local exclusive
  if (threadIdx.x == 1023) bsum[blockIdx.x] = sh[1023];
}

__global__ void scanB_k(u32* __restrict__ bsum, int nb) {   // 1 wave, chunks of 64
  int l = threadIdx.x;
  u32 carry = 0u;
  for (int base = 0; base < nb; base += 64) {
    u32 v = (base + l < nb) ? bsum[base + l] : 0u;
    for (int s = 1; s < 64; s <<= 1) {
      u32 t = __shfl_up(v, s);
      if (l >= s) v += t;
    }
    if (base + l < nb) bsum[base + l] = v + carry;
    carry += __shfl(v, 63);
  }
}

__global__ __launch_bounds__(1024)
void scanC_k(u32* __restrict__ off, u32* __restrict__ cur,
             const u32* __restrict__ bsum, int n2) {
  int b = blockIdx.x;
  int i = b * 1024 + (int)threadIdx.x;
  if (i >= n2) return;
  u32 add = (b > 0) ? bsum[b - 1] : 0u;
  u32 o = off[i] + add;
  off[i] = o;
  cur[i] = o;
}

__global__ void fill_k(const int* __restrict__ src, const int* __restrict__ dst,
                       u32* __restrict__ cur, u32* __restrict__ adj, int n, int E) {
  int i = blockIdx.x * 256 + threadIdx.x;
  if (i >= E) return;
  int s = src[i], d = dst[i];
  u32 ps = atomicAdd(&cur[s], 1u);
  adj[ps] = (u32)d;
  u32 pd = atomicAdd(&cur[n + d], 1u);
  adj[pd] = (u32)s;
}

__global__ void dinv_k(const u32* __restrict__ cd, float* __restrict__ dinv, int n) {
  int i = blockIdx.x * 256 + threadIdx.x;
  if (i < n) dinv[i] = 1.0f / sqrtf((float)(cd[i] + 1u));
}

// ---------------------------------------------------------------------------
// GCN aggregation, bf16 in, fp32/bf16 out; 4-edge ILP
// ---------------------------------------------------------------------------
template <int WF32, int WBF>
__global__ void gcn_agg_k(const u16* __restrict__ xw, const float* __restrict__ dinv,
                          const u32* __restrict__ off, const u32* __restrict__ cnt,
                          const u32* __restrict__ nbr, const float* __restrict__ bias,
                          float* __restrict__ outf, u16* __restrict__ outb, int n) {
  int node = (blockIdx.x * blockDim.x + threadIdx.x) >> 6;
  int lane = threadIdx.x & 63;
  if (node >= n) return;
  float di = dinv[node];
  ushort2 v = ((const ushort2*)(xw + (size_t)node * HD))[lane];
  float ax = di * di * bf2f(v.x), ay = di * di * bf2f(v.y);
  u32 i = off[node], end = i + cnt[node];
  for (; i + 4 <= end; i += 4) {
    int s0 = (int)nbr[i],     s1 = (int)nbr[i + 1];
    int s2 = (int)nbr[i + 2], s3 = (int)nbr[i + 3];
    float w0 = di * dinv[s0], w1 = di * dinv[s1];
    float w2 = di * dinv[s2], w3 = di * dinv[s3];
    ushort2 u0 = ((const ushort2*)(xw + (size_t)s0 * HD))[lane];
    ushort2 u1 = ((const ushort2*)(xw + (size_t)s1 * HD))[lane];
    ushort2 u2 = ((const ushort2*)(xw + (size_t)s2 * HD))[lane];
    ushort2 u3 = ((const ushort2*)(xw + (size_t)s3 * HD))[lane];
    ax = fmaf(w0, bf2f(u0.x), ax); ay = fmaf(w0, bf2f(u0.y), ay);
    ax = fmaf(w1, bf2f(u1.x), ax); ay = fmaf(w1, bf2f(u1.y), ay);
    ax = fmaf(w2, bf2f(u2.x), ax); ay = fmaf(w2, bf2f(u2.y), ay);
    ax = fmaf(w3, bf2f(u3.x), ax); ay = fmaf(w3, bf2f(u3.y), ay);
  }
  for (; i < end; ++i) {
    int s0 = (int)nbr[i];
    float w0 = di * dinv[s0];
    ushort2 u0 = ((const ushort2*)(xw + (size_t)s0 * HD))[lane];
    ax = fmaf(w0, bf2f(u0.x), ax);
    ay = fmaf(w0, bf2f(u0.y), ay);
  }
  float2 b = ((const float2*)bias)[lane];
  ax += b.x; ay += b.y;
  if (WF32) ((float2*)(outf + (size_t)node * HD))[lane] = make_float2(ax, ay);
  if (WBF) {
    ushort2 ob; ob.x = f2bf(ax); ob.y = f2bf(ay);
    ((ushort2*)(outb + (size_t)node * HD))[lane] = ob;
  }
}

// ---------------------------------------------------------------------------
// Fused edge scores + scatter-softmax + aggregate + residual (one wave/node).
// Fast path (degree <= 64): scores kept in one register/lane, no global
// round-trip, exp computed once. Fallback = 3-pass global path.
// ---------------------------------------------------------------------------
__global__ void attn_fused_k(const u32* __restrict__ off, const u32* __restrict__ cnt,
                             const u32* __restrict__ adj,
                             const u16* __restrict__ ti, int TS,
                             const u16* __restrict__ gi, int GS,
                             const u16* __restrict__ vmat, int VS,
                             const u16* __restrict__ xb,
                             float* __restrict__ scores,
                             u16* __restrict__ xf, int n) {
  int node = (blockIdx.x * blockDim.x + threadIdx.x) >> 6;
  int lane = threadIdx.x & 63;
  if (node >= n) return;
  u32 o = off[node], c = cnt[node];
  u32 end = o + c;
  float acc[6] = {0.f, 0.f, 0.f, 0.f, 0.f, 0.f};
  const float sc = 0.05103103630798288f;   // 1/sqrt(384)
  if (c > 0) {
    const u16* tp = ti + (size_t)node * TS;
    float tf[6];
#pragma unroll
    for (int q = 0; q < 3; ++q) {
      ushort2 tv = *(const ushort2*)(tp + q * 128 + lane * 2);
      tf[q * 2] = bf2f(tv.x);
      tf[q * 2 + 1] = bf2f(tv.y);
    }
    if (c <= 64) {
      // ---- fast path: per-lane register scores ----
      float sreg = -1e30f;
      u32 i = o;
      for (; i + 2 <= end; i += 2) {
        int d0 = (int)adj[i], d1 = (int)adj[i + 1];
        const u16* g0 = gi + (size_t)d0 * GS;
        const u16* g1 = gi + (size_t)d1 * GS;
        float dot0 = 0.f, dot1 = 0.f;
#pragma unroll
        for (int q = 0; q < 3; ++q) {
          ushort2 a = *(const ushort2*)(g0 + q * 128 + lane * 2);
          ushort2 b = *(const ushort2*)(g1 + q * 128 + lane * 2);
          dot0 = fmaf(tf[q * 2], bf2f(a.x), dot0);
          dot0 = fmaf(tf[q * 2 + 1], bf2f(a.y), dot0);
          dot1 = fmaf(tf[q * 2], bf2f(b.x), dot1);
          dot1 = fmaf(tf[q * 2 + 1], bf2f(b.y), dot1);
        }
#pragma unroll
        for (int s2 = 32; s2 >= 1; s2 >>= 1) {
          dot0 += __shfl_xor(dot0, s2);
          dot1 += __shfl_xor(dot1, s2);
        }
        int idx = (int)(i - o);
        if (lane == idx) sreg = dot0 * sc;
        if (lane == idx + 1) sreg = dot1 * sc;
      }
      if (i < end) {
        int d0 = (int)adj[i];
        const u16* g0 = gi + (size_t)d0 * GS;
        float dot0 = 0.f;
#pragma unroll
        for (int q = 0; q < 3; ++q) {
          ushort2 a = *(const ushort2*)(g0 + q * 128 + lane * 2);
          dot0 = fmaf(tf[q * 2], bf2f(a.x), dot0);
          dot0 = fmaf(tf[q * 2 + 1], bf2f(a.y), dot0);
        }
#pragma unroll
        for (int s2 = 32; s2 >= 1; s2 >>= 1) dot0 += __shfl_xor(dot0, s2);
        if (lane == (int)(i - o)) sreg = dot0 * sc;
      }
      float mx = sreg;
#pragma unroll
      for (int s2 = 32; s2 >= 1; s2 >>= 1) mx = fmaxf(mx, __shfl_xor(mx, s2));
      float ew = (lane < (int)c) ? expf(sreg - mx) : 0.f;
      float den = ew;
#pragma unroll
      for (int s2 = 32; s2 >= 1; s2 >>= 1) den += __shfl_xor(den, s2);
      float wreg = ew / den;
      i = o;
      for (; i + 2 <= end; i += 2) {
        int d0 = (int)adj[i], d1 = (int)adj[i + 1];
        int idx = (int)(i - o);
        float w0 = __shfl(wreg, idx);
        float w1 = __shfl(wreg, idx + 1);
        const u16* v0 = vmat + (size_t)d0 * VS;
        const u16* v1 = vmat + (size_t)d1 * VS;
#pragma unroll
        for (int q = 0; q < 3; ++q) {
          ushort2 a = *(const ushort2*)(v0 + q * 128 + lane * 2);
          ushort2 b = *(const ushort2*)(v1 + q * 128 + lane * 2);
          acc[q * 2]     = fmaf(w0, bf2f(a.x), acc[q * 2]);
          acc[q * 2 + 1] = fmaf(w0, bf2f(a.y), acc[q * 2 + 1]);
          acc[q * 2]     = fmaf(w1, bf2f(b.x), acc[q * 2]);
          acc[q * 2 + 1] = fmaf(w1, bf2f(b.y), acc[q * 2 + 1]);
        }
      }
      if (i < end) {
        int d0 = (int)adj[i];
        float w0 = __shfl(wreg, (int)(i - o));
        const u16* v0 = vmat + (size_t)d0 * VS;
#pragma unroll
        for (int q = 0; q < 3; ++q) {
          ushort2 a = *(const ushort2*)(v0 + q * 128 + lane * 2);
          acc[q * 2]     = fmaf(w0, bf2f(a.x), acc[q * 2]);
          acc[q * 2 + 1] = fmaf(w0, bf2f(a.y), acc[q * 2 + 1]);
        }
      }
    } else {
      // ---- fallback: 3-pass global scores (degree > 64) ----
      float mx = -1e30f;
      u32 i = o;
      for (; i < end; ++i) {
        int d0 = (int)adj[i];
        const u16* g0 = gi + (size_t)d0 * GS;
        float dot0 = 0.f;
#pragma unroll
        for (int q = 0; q < 3; ++q) {
          ushort2 a = *(const ushort2*)(g0 + q * 128 + lane * 2);
          dot0 = fmaf(tf[q * 2], bf2f(a.x), dot0);
          dot0 = fmaf(tf[q * 2 + 1], bf2f(a.y), dot0);
        }
#pragma unroll
        for (int s2 = 32; s2 >= 1; s2 >>= 1) dot0 += __shfl_xor(dot0, s2);
        dot0 *= sc;
        if (lane == 0) scores[i] = dot0;
        mx = fmaxf(mx, dot0);
      }
      float den = 0.f;
      for (u32 k = o + lane; k < end; k += 64) den += expf(scores[k] - mx);
#pragma unroll
      for (int s2 = 32; s2 >= 1; s2 >>= 1) den += __shfl_xor(den, s2);
      float invden = 1.0f / den;
      for (i = o; i < end; ++i) {
        int d0 = (int)adj[i];
        float w0 = expf(scores[i] - mx) * invden;
        const u16* v0 = vmat + (size_t)d0 * VS;
#pragma unroll
        for (int q = 0; q < 3; ++q) {
          ushort2 a = *(const ushort2*)(v0 + q * 128 + lane * 2);
          acc[q * 2]     = fmaf(w0, bf2f(a.x), acc[q * 2]);
          acc[q * 2 + 1] = fmaf(w0, bf2f(a.y), acc[q * 2 + 1]);
        }
      }
    }
  }
  const u16* xp = xb + (size_t)node * FIN;
  u16* op = xf + (size_t)node * FIN;
#pragma unroll
  for (int q = 0; q < 3; ++q) {
    ushort2 xv = *(const ushort2*)(xp + q * 128 + lane * 2);
    ushort2 ov;
    ov.x = f2bf(acc[q * 2] + bf2f(xv.x));
    ov.y = f2bf(acc[q * 2 + 1] + bf2f(xv.y));
    *(ushort2*)(op + q * 128 + lane * 2) = ov;
  }
}

// ---------------------------------------------------------------------------
// MFMA bf16 GEMM (2-phase 128x128), 1-D grid + XCD swizzle (T1).
// EPI 0/1/2: none / +bias / relu(+bias); split-bias at bsplit.
// EPI 4 (left): epilogue-time temp loads (r13 preload cost occupancy);
//   slice-stream bf16 ptP[ctile][row][wc*4+j].
// EPI 6 (tv+gcn1 merged, Nc=896): col<768 -> Cp; col>=768 -> Cbf2.
// ---------------------------------------------------------------------------
template <int EPI, int OUTBF>
__global__ __launch_bounds__(256)
void mgemm_k(const u16* __restrict__ Abf, int As, const u16* __restrict__ WT,
             const float* __restrict__ bias, const float* __restrict__ bias_b, int bsplit,
             void* __restrict__ Cp, u16* __restrict__ Cbf2,
             float* __restrict__ tmp, int M, int K, int Nc, int ncx) {
  __shared__ u16 Albuf[2][128 * 32];
  __shared__ u16 Blbuf[2][128 * 32];
  const int t = threadIdx.x;
  const int lane = t & 63;
  const int wave = t >> 6;
  const int wr = wave >> 1, wc = wave & 1;
  const int wgid = xcd_wgid();
  const int ctile = wgid % ncx;
  const int row0 = (wgid / ncx) * 128;
  const int col0 = ctile * 128;
  const int sr = t >> 2;
  const int sk = (t & 3) * 8;
  const int nt = K >> 5;

  f32x4 acc[4][4] = {};

  auto stage = [&](int buf, int k0) {
#pragma unroll
    for (int h = 0; h < 2; ++h) {
      int ar = row0 + h * 64 + sr;
      if (ar >= M) ar = M - 1;
      GLOAD16(Abf + (size_t)ar * As + k0 + sk, &Albuf[buf][h * 2048 + wave * 512]);
    }
#pragma unroll
    for (int h = 0; h < 2; ++h) {
      int bc = col0 + h * 64 + sr;
      if (bc >= Nc) bc = Nc - 1;
      GLOAD16(WT + (size_t)bc * K + k0 + sk, &Blbuf[buf][h * 2048 + wave * 512]);
    }
  };

  stage(0, 0);
  int buf = 0;
  for (int tk = 0; tk < nt; ++tk) {
    __syncthreads();
    if (tk + 1 < nt) stage(buf ^ 1, (tk + 1) << 5);
    const u16* Al = Albuf[buf];
    const u16* Bl = Blbuf[buf];
    s16x8 a[4], b[4];
#pragma unroll
    for (int m = 0; m < 4; ++m)
      a[m] = *(const s16x8*)(Al + (wr * 64 + m * 16 + (lane & 15)) * 32 + (lane >> 4) * 8);
#pragma unroll
    for (int j = 0; j < 4; ++j)
      b[j] = *(const s16x8*)(Bl + (wc * 64 + j * 16 + (lane & 15)) * 32 + (lane >> 4) * 8);
#pragma unroll
    for (int m = 0; m < 4; ++m)
#pragma unroll
      for (int j = 0; j < 4; ++j)
        acc[m][j] = __builtin_amdgcn_mfma_f32_16x16x32_bf16(a[m], b[j], acc[m][j], 0, 0, 0);
    buf ^= 1;
  }

  if constexpr (EPI <= 2) {
#pragma unroll
    for (int m = 0; m < 4; ++m) {
      int rbase = row0 + wr * 64 + m * 16 + (lane >> 4) * 4;
#pragma unroll
      for (int j = 0; j < 4; ++j) {
        int col = col0 + wc * 64 + j * 16 + (lane & 15);
        if (col >= Nc) continue;
        float bv = 0.f;
        if (EPI >= 1) bv = (col < bsplit) ? bias[col] : bias_b[col - bsplit];
#pragma unroll
        for (int r = 0; r < 4; ++r) {
          int row = rbase + r;
          if (row >= M) continue;
          float v = acc[m][j][r] + bv;
          if (EPI == 2) v = fmaxf(v, 0.f);
          if (OUTBF) ((u16*)Cp)[(size_t)row * Nc + col] = f2bf(v);
          else       ((float*)Cp)[(size_t)row * Nc + col] = v;
        }
      }
    }
  } else if constexpr (EPI == 6) {
#pragma unroll
    for (int m = 0; m < 4; ++m) {
      int rbase = row0 + wr * 64 + m * 16 + (lane >> 4) * 4;
#pragma unroll
      for (int j = 0; j < 4; ++j) {
        int col = col0 + wc * 64 + j * 16 + (lane & 15);
        if (col < 2 * FIN) {
          float bv = (col < bsplit) ? bias[col] : bias_b[col - bsplit];
#pragma unroll
          for (int r = 0; r < 4; ++r) {
            int row = rbase + r;
            if (row >= M) continue;
            ((u16*)Cp)[(size_t)row * (2 * FIN) + col] = f2bf(acc[m][j][r] + bv);
          }
        } else {
          int c2 = col - 2 * FIN;
#pragma unroll
          for (int r = 0; r < 4; ++r) {
            int row = rbase + r;
            if (row >= M) continue;
            Cbf2[(size_t)row * HD + c2] = f2bf(acc[m][j][r]);
          }
        }
      }
    }
  } else {  // EPI == 4: bf16 slice-stream to ptP[ctile][row][wc*4+j]
    u16* slice = (u16*)Cp + (size_t)ctile * M * 8;
#pragma unroll
    for (int m = 0; m < 4; ++m) {
#pragma unroll
      for (int r = 0; r < 4; ++r) {
        int row = row0 + wr * 64 + m * 16 + (lane >> 4) * 4 + r;
        float tv = (row < M) ? tmp[(size_t)row * RD + (lane & 15)] : 0.f;
#pragma unroll
        for (int j = 0; j < 4; ++j) {
          float s = (acc[m][j][r] + bias[col0 + wc * 64 + j * 16 + (lane & 15)]) * tv;
          s += __shfl_xor(s, 1); s += __shfl_xor(s, 2);
          s += __shfl_xor(s, 4); s += __shfl_xor(s, 8);
          if ((lane & 15) == 0 && row < M)
            slice[(size_t)row * 8 + wc * 4 + j] = f2bf(s);
        }
      }
    }
  }
}

// ---------------------------------------------------------------------------
// pt gather: pt[row][ct*8+pl] = bf2f(ptP[ct][row][pl]); coalesced full rows,
// fp32 + bf16 outputs.
// ---------------------------------------------------------------------------
__global__ void ptgather_k(const u16* __restrict__ ptP, float* __restrict__ pt,
                           u16* __restrict__ ptb, int n) {
  int g = blockIdx.x * 256 + threadIdx.x;
  if (g >= n * 16) return;
  int row = g >> 4, ct = g & 15;
  const u16* sp = ptP + ((size_t)ct * n + (size_t)row) * 8;
  ushort4 a = ((const ushort4*)sp)[0];
  ushort4 b = ((const ushort4*)sp)[1];
  float* dp = pt + (size_t)row * PD + ct * 8;
  ((float4*)dp)[0] = make_float4(bf2f(a.x), bf2f(a.y), bf2f(a.z), bf2f(a.w));
  ((float4*)dp)[1] = make_float4(bf2f(b.x), bf2f(b.y), bf2f(b.z), bf2f(b.w));
  u16* db = ptb + (size_t)row * PD + ct * 8;
  ((ushort4*)db)[0] = a;
  ((ushort4*)db)[1] = b;
}

// ---------------------------------------------------------------------------
// Y-GEMM, 8-phase 256x256/BK=64/8-wave (T3+T4+T2+T5), race-verified (r8),
// 1-D grid + XCD swizzle (ncx=12 col-groups).
// ---------------------------------------------------------------------------
#define VM6  asm volatile("s_waitcnt vmcnt(6)" ::: "memory")
#define VM0  asm volatile("s_waitcnt vmcnt(0)" ::: "memory")
#define VMNOP
#define BARR asm volatile("s_barrier" ::: "memory")

__global__ __launch_bounds__(512)
void ygemm8_k(const u16* __restrict__ X, const u16* __restrict__ QT,
              const u16* __restrict__ Ar, float* __restrict__ tmpP, int M) {
  __shared__ u16 Al[2][16384];
  __shared__ u16 Bl[2][16384];
  const int t = threadIdx.x;
  const int lane = t & 63;
  const int wave = t >> 6;
  const int wr = wave >> 2;
  const int wcn = wave & 3;
  const int wgid = xcd_wgid();
  const int ctile = wgid % 12;
  const int row0 = (wgid / 12) * 256;
  const int col0 = ctile * 256;

  const int srow = t >> 3;
  const int sgk  = (((t & 7) ^ (srow & 7)) << 3);
  const int sdst = t * 8;

  const int pc0 = (((lane >> 4)) ^ (lane & 7)) << 3;
  const int pc1 = ((((lane >> 4) + 4)) ^ (lane & 7)) << 3;
  const int arow = (wr * 128 + (lane & 15)) << 6;
  const int brow = (wcn * 64 + (lane & 15)) << 6;

  f32x4 acc[8][4] = {};
  s16x8 a[4][2], b[4][2];

#define STGA8(bf, h, kt) do {                                                  \
    int r0_ = row0 + (h) * 128 + srow;                                         \
    int r1_ = r0_ + 64;                                                        \
    if (r0_ >= M) r0_ = M - 1;                                                 \
    if (r1_ >= M) r1_ = M - 1;                                                 \
    GLOAD16(X + (size_t)r0_ * 384 + (kt) * 64 + sgk, &Al[bf][(h) * 8192 + sdst]);        \
    GLOAD16(X + (size_t)r1_ * 384 + (kt) * 64 + sgk, &Al[bf][(h) * 8192 + 4096 + sdst]); \
  } while (0)

#define STGB8(bf, h, kt) do {                                                  \
    int c0_ = col0 + (h) * 128 + srow;                                         \
    GLOAD16(QT + (size_t)c0_ * 384 + (kt) * 64 + sgk, &Bl[bf][(h) * 8192 + sdst]);       \
    GLOAD16(QT + (size_t)(c0_ + 64) * 384 + (kt) * 64 + sgk,                   \
            &Bl[bf][(h) * 8192 + 4096 + sdst]);                                \
  } while (0)

#define LDA8(bf, mh) do {                                                      \
    _Pragma("unroll") for (int m2_ = 0; m2_ < 4; ++m2_) {                      \
      const u16* p_ = &Al[bf][arow + ((mh) * 4 + m2_) * 1024];                 \
      a[m2_][0] = *(const s16x8*)(p_ + pc0);                                   \
      a[m2_][1] = *(const s16x8*)(p_ + pc1);                                   \
    }                                                                          \
  } while (0)

#define LDB8(bf, jh) do {                                                      \
    _Pragma("unroll") for (int j2_ = 0; j2_ < 2; ++j2_) {                      \
      const u16* p_ = &Bl[bf][brow + ((jh) * 2 + j2_) * 1024];                 \
      b[(jh) * 2 + j2_][0] = *(const s16x8*)(p_ + pc0);                        \
      b[(jh) * 2 + j2_][1] = *(const s16x8*)(p_ + pc1);                        \
    }                                                                          \
  } while (0)

#define MQ8(mh, jh) do {                                                       \
    __builtin_amdgcn_s_setprio(1);                                             \
    _Pragma("unroll") for (int m2_ = 0; m2_ < 4; ++m2_)                        \
      _Pragma("unroll") for (int j2_ = 0; j2_ < 2; ++j2_)                      \
        _Pragma("unroll") for (int ks_ = 0; ks_ < 2; ++ks_)                    \
          acc[(mh) * 4 + m2_][(jh) * 2 + j2_] =                                \
              __builtin_amdgcn_mfma_f32_16x16x32_bf16(                         \
                  a[m2_][ks_], b[(jh) * 2 + j2_][ks_],                         \
                  acc[(mh) * 4 + m2_][(jh) * 2 + j2_], 0, 0, 0);               \
    __builtin_amdgcn_s_setprio(0);                                             \
  } while (0)

  STGA8(0, 0, 0); STGA8(0, 1, 0); STGB8(0, 0, 0); STGB8(0, 1, 0);
  STGA8(1, 0, 1); STGB8(1, 0, 1); STGB8(1, 1, 1);
  VM6; BARR;

#define ITER8(i, VMP3, VMP7, DOSTG)                                                          \
  /*ph0*/ LDA8(0,0); LDB8(0,0); STGA8(1,1,2*(i)+1);                   BARR; MQ8(0,0); BARR;  \
  /*ph1*/ LDB8(0,1);                                                  BARR; MQ8(0,1); BARR;  \
  /*ph2*/ LDA8(0,1); if (DOSTG) STGB8(0,0,2*(i)+2);                   BARR; MQ8(1,0); BARR;  \
  /*ph3*/ if (DOSTG) { STGB8(0,1,2*(i)+2); STGA8(0,0,2*(i)+2); } VMP3; BARR; MQ8(1,1); BARR; \
  /*ph4*/ LDA8(1,0); LDB8(1,0); if (DOSTG) STGA8(0,1,2*(i)+2);        BARR; MQ8(0,0); BARR;  \
  /*ph5*/ LDB8(1,1);                                                  BARR; MQ8(0,1); BARR;  \
  /*ph6*/ LDA8(1,1); if (DOSTG) STGB8(1,0,2*(i)+3);                   BARR; MQ8(1,0); BARR;  \
  /*ph7*/ if (DOSTG) { STGB8(1,1,2*(i)+3); STGA8(1,0,2*(i)+3); } VMP7; BARR; MQ8(1,1); BARR;

  ITER8(0, VM6, VM6, 1)
  ITER8(1, VM6, VM6, 1)
  ITER8(2, VM0, VMNOP, 0)

  // fold: s[m][rr] = sum_j relu_r[row, h0+j] * acc[m][j][rr]
  const int h0 = (col0 >> 4) + wcn * 4;
  float s[8][4];
#pragma unroll
  for (int m = 0; m < 8; ++m) {
#pragma unroll
    for (int rr = 0; rr < 4; ++rr) {
      int row = row0 + wr * 128 + m * 16 + (lane >> 4) * 4 + rr;
      int rc = row < M ? row : M - 1;
      ushort4 arv = *(const ushort4*)(Ar + (size_t)rc * 384 + h0);
      s[m][rr] = bf2f(arv.x) * acc[m][0][rr] + bf2f(arv.y) * acc[m][1][rr] +
                 bf2f(arv.z) * acc[m][2][rr] + bf2f(arv.w) * acc[m][3][rr];
    }
  }

  __syncthreads();
  float* redA = (float*)&Al[0][0];
  float* redB = redA + 4096;
  const int r16 = lane & 15;
  const int rlb = wr * 128 + (lane >> 4) * 4;
  if (wcn & 1) {
    float* red = (wcn == 1) ? redA : redB;
#pragma unroll
    for (int m = 0; m < 8; ++m)
#pragma unroll
      for (int rr = 0; rr < 4; ++rr)
        red[(rlb + m * 16 + rr) * 16 + r16] = s[m][rr];
  }
  __syncthreads();
  if (!(wcn & 1)) {
    float* red = (wcn == 0) ? redA : redB;
#pragma unroll
    for (int m = 0; m < 8; ++m)
#pragma unroll
      for (int rr = 0; rr < 4; ++rr)
        s[m][rr] += red[(rlb + m * 16 + rr) * 16 + r16];
  }
  __syncthreads();
  if (wcn == 2) {
#pragma unroll
    for (int m = 0; m < 8; ++m)
#pragma unroll
      for (int rr = 0; rr < 4; ++rr)
        redA[(rlb + m * 16 + rr) * 16 + r16] = s[m][rr];
  }
  __syncthreads();
  if (wcn == 0) {
    float* slice = tmpP + (size_t)ctile * M * RD;
#pragma unroll
    for (int m = 0; m < 8; ++m)
#pragma unroll
      for (int rr = 0; rr < 4; ++rr) {
        int row = row0 + rlb + m * 16 + rr;
        if (row < M)
          slice[(size_t)row * RD + r16] =
              s[m][rr] + redA[(rlb + m * 16 + rr) * 16 + r16];
      }
  }
#undef STGA8
#undef STGB8
#undef LDA8
#undef LDB8
#undef MQ8
#undef ITER8
}

// ---------------------------------------------------------------------------
// combine: temp[i] = sum_{s=0..12} tmpP[s][i]   (slice 12 = x@Br bias term)
// ---------------------------------------------------------------------------
__global__ void combine_k(const float* __restrict__ tmpP, float* __restrict__ temp,
                          size_t sl, int tot4) {
  int i = blockIdx.x * 256 + threadIdx.x;
  if (i >= tot4) return;
  float4 s = ((const float4*)(tmpP + 12 * sl))[i];
#pragma unroll
  for (int c = 0; c < 12; ++c) {
    float4 p = ((const float4*)(tmpP + (size_t)c * sl))[i];
    s.x += p.x; s.y += p.y; s.z += p.z; s.w += p.w;
  }
  ((float4*)temp)[i] = s;
}

// ---------------------------------------------------------------------------
// Final: in-place row-normalize p_t, p_g; alignment = dot of normalized rows.
// ---------------------------------------------------------------------------
__global__ void final_k(float* __restrict__ out, int n) {
  int node = (blockIdx.x * blockDim.x + threadIdx.x) >> 6;
  int lane = threadIdx.x & 63;
  if (node >= n) return;
  float* pt = out + n + (size_t)node * PD;
  float* pg = out + n + (size_t)n * PD + (size_t)node * PD;
  float2 t = ((float2*)pt)[lane];
  float2 g = ((float2*)pg)[lane];
  float tt = t.x * t.x + t.y * t.y;
  float gg = g.x * g.x + g.y * g.y;
  float tg = t.x * g.x + t.y * g.y;
#pragma unroll
  for (int s = 32; s >= 1; s >>= 1) {
    tt += __shfl_xor(tt, s);
    gg += __shfl_xor(gg, s);
    tg += __shfl_xor(tg, s);
  }
  float invt = 1.0f / fmaxf(sqrtf(tt), 1e-12f);
  float invg = 1.0f / fmaxf(sqrtf(gg), 1e-12f);
  ((float2*)pt)[lane] = make_float2(t.x * invt, t.y * invt);
  ((float2*)pg)[lane] = make_float2(g.x * invg, g.y * invg);
  if (lane == 0) out[node] = tg * invt * invg;
}

// ---------------------------------------------------------------------------
struct MgArgs {
  const u16* A; int As; const u16* WT;
  const float* b; const float* b2; int bsplit;
  void* C; u16* C2; float* tmp;
  int M, K, Nc;
};
template <int EPI, int OUTBF>
static void mg(const MgArgs& a, hipStream_t s) {
  int ncx = (a.Nc + 127) / 128, nry = (a.M + 127) / 128;
  mgemm_k<EPI, OUTBF><<<dim3(ncx * nry), 256, 0, s>>>(
      a.A, a.As, a.WT, a.b, a.b2, a.bsplit, a.C, a.C2, a.tmp,
      a.M, a.K, a.Nc, ncx);
}

extern "C" void kernel_launch(void* const* d_in, const int* in_sizes, int n_in,
                              void* d_out, int out_size, void* d_ws, size_t ws_size,
                              hipStream_t stream) {
  const float* x      = (const float*)d_in[0];
  const int*   ei     = (const int*)d_in[1];
  const float* W_gcn1 = (const float*)d_in[2];
  const float* b_gcn1 = (const float*)d_in[3];
  const float* W_ti   = (const float*)d_in[4];
  const float* b_ti   = (const float*)d_in[5];
  const float* W_gi   = (const float*)d_in[6];
  const float* b_gi   = (const float*)d_in[7];
  const float* W_v    = (const float*)d_in[8];
  const float* b_v    = (const float*)d_in[9];
  const float* Wl1    = (const float*)d_in[10];
  const float* bl1    = (const float*)d_in[11];
  const float* Wl2    = (const float*)d_in[12];
  const float* bl2    = (const float*)d_in[13];
  const float* Wr1    = (const float*)d_in[14];
  const float* br1    = (const float*)d_in[15];
  const float* Wr2    = (const float*)d_in[16];
  const float* br2    = (const float*)d_in[17];
  const float* W_gcn2 = (const float*)d_in[18];
  const float* b_gcn2 = (const float*)d_in[19];
  const float* W_gp   = (const float*)d_in[20];
  const float* b_gp   = (const float*)d_in[21];

  const int n = in_sizes[0] / FIN;   // 50000
  const int E = in_sizes[1] / 2;     // 500000
  const int* src = ei;
  const int* dst = ei + E;

  // -------- workspace carve (tmpP/ptP overlay gibf+xfbf) --------
  char* wsp = (char*)d_ws;
  auto carve = [&](size_t bytes) -> void* {
    void* p = (void*)wsp;
    wsp += (bytes + 255) & ~(size_t)255;
    return p;
  };
  u32* cnt      = (u32*)carve((size_t)2 * n * 4);   // [src | dst]
  u32* off      = (u32*)carve((size_t)2 * n * 4);
  u32* cur      = (u32*)carve((size_t)2 * n * 4);
  u32* bsum     = (u32*)carve(512);
  u32* adj      = (u32*)carve((size_t)2 * E * 4);   // [src-CSR dsts | dst-CSR srcs]
  float* dinv   = (float*)carve((size_t)n * 4);
  float* scores = (float*)carve((size_t)E * 4);
  float* temp   = (float*)carve((size_t)n * RD * 4);

  u16* xbf    = (u16*)carve((size_t)n * FIN * 2);       // x bf16 (pristine)
  u16* tvbf   = (u16*)carve((size_t)n * 2 * FIN * 2);   // [t_info | v]; later lrbf
  u16* bufHbf = (u16*)carve((size_t)n * HD * 2);        // xw (both GCNs)
  u16* gembf  = (u16*)carve((size_t)n * HD * 2);
  u16* ptbf   = (u16*)carve((size_t)n * PD * 2);
  u16* g2bf   = (u16*)carve((size_t)n * HD * 2);

  // gibf and xfbf adjacent; tmpP (13 x n*16 fp32 = 41.6 MB) overlays them;
  // ptP (16 x n*8 bf16 = 12.8 MB) reuses the same region after combine.
  u16* gibf   = (u16*)carve((size_t)n * FIN * 2);       // g_info
  u16* xfbf   = (u16*)carve((size_t)n * FIN * 2);       // x_fused
  size_t tmpP_bytes = (size_t)13 * n * RD * 4;
  size_t overlay    = (size_t)2 * n * FIN * 2;
  carve(tmpP_bytes > overlay ? tmpP_bytes - overlay : 0);
  float* tmpP = (float*)gibf;
  u16* ptP    = (u16*)gibf;   // reused after combine_k (slices dead)

  u16* WtvT   = (u16*)carve((size_t)2 * FIN * FIN * 2); // [768][384]
  u16* WgcnT  = (u16*)carve((size_t)HD * FIN * 2);      // [128][384], contiguous
  u16* WgiT   = (u16*)carve((size_t)FIN * HD * 2);      // [384][128]
  u16* WlrT   = (u16*)carve((size_t)FIN * FIN * 2);     // [384][384]
  u16* Wl2T   = (u16*)carve((size_t)2048 * 192 * 2);
  u16* QT     = (u16*)carve((size_t)3072 * FIN * 2);    // permuted Wr2
  u16* BrT    = (u16*)carve((size_t)RD * FIN * 2);      // br2 reshaped [16][384]
  u16* Wgcn2T = (u16*)carve((size_t)HD * PD * 2);
  u16* WgpT   = (u16*)carve((size_t)PD * PD * 2);

  u16* lrbf = tvbf;   // [relu_l | relu_r], stride 384; tv dead after attn

  float* out    = (float*)d_out;
  float* pt_raw = out + n;
  float* pg_raw = out + n + (size_t)n * PD;
  float* g2     = out + n + (size_t)2 * n * PD;

  // 0) all converts in one launch
  CvtDesc dsc;
  int nent = 0, blk = 0;
  auto addent = [&](const float* s, u16* d, int K, int N, int mode) {
    dsc.e[nent] = {s, d, K, N, mode, blk};
    blk += (K * N + 255) / 256;
    ++nent;
  };
  addent(x,      xbf,    n * FIN, 1, 1);
  addent(W_ti,   WtvT,   FIN, FIN, 0);
  addent(W_v,    WtvT + (size_t)FIN * FIN, FIN, FIN, 0);
  addent(W_gcn1, WgcnT,  FIN, HD,  0);
  addent(W_gi,   WgiT,   HD,  FIN, 0);
  addent(Wl1,    WlrT,   FIN, 192, 0);
  addent(Wr1,    WlrT + (size_t)192 * FIN, FIN, 192, 0);
  addent(Wl2,    Wl2T,   192, 2048, 0);
  addent(Wr2,    QT,     FIN, 3072, 2);
  addent(br2,    BrT,    RD * FIN, 1, 1);
  addent(W_gcn2, Wgcn2T, PD, HD, 0);
  addent(W_gp,   WgpT,   PD, PD, 0);
  dsc.n = nent;
  cvt_all_k<<<blk, 256, 0, stream>>>(dsc);

  // 1) CSR build + degrees (one concatenated scan over 2n)
  hipMemsetAsync(cnt, 0, (size_t)2 * n * 4, stream);
  hist_k<<<(E + 255) / 256, 256, 0, stream>>>(src, dst, cnt, n, E);
  int n2 = 2 * n;
  int nb = (n2 + 1023) / 1024;
  scanA_k<<<nb, 1024, 0, stream>>>(cnt, off, bsum, n2);
  scanB_k<<<1, 64, 0, stream>>>(bsum, nb);
  scanC_k<<<nb, 1024, 0, stream>>>(off, cur, bsum, n2);
  fill_k<<<(E + 255) / 256, 256, 0, stream>>>(src, dst, cur, adj, n, E);
  dinv_k<<<(n + 255) / 256, 256, 0, stream>>>(cnt + n, dinv, n);

  MgArgs a{};

  // 2+3a) merged GEMM: [t_info | v | xw_gcn1], Nc=896 (EPI 6)
  a = {xbf, FIN, WtvT, b_ti, b_v, FIN, tvbf, bufHbf, nullptr, n, FIN, 896};
  mg<6, 1>(a, stream);
  gcn_agg_k<0, 1><<<(n + 3) / 4, 256, 0, stream>>>(bufHbf, dinv, off + n, cnt + n, adj,
                                                   b_gcn1, nullptr, gembf, n);

  // 3b) g_info GEMM; fused scores+softmax+aggregate+residual
  a = {gembf, HD, WgiT, b_gi, nullptr, 1 << 30, gibf, nullptr, nullptr, n, HD, FIN};
  mg<1, 1>(a, stream);
  attn_fused_k<<<(n + 3) / 4, 256, 0, stream>>>(off, cnt, adj, tvbf, 2 * FIN, gibf, FIN,
                                                tvbf + FIN, 2 * FIN, xbf, scores, xfbf, n);

  // 4) Generators: [relu_l | relu_r] in one GEMM (overwrites tv buffer)
  a = {xfbf, FIN, WlrT, bl1, br1, 192, lrbf, nullptr, nullptr, n, FIN, FIN};
  mg<2, 1>(a, stream);

  // right path: x@Br into tmpP slice 12, 8-phase Y-GEMM partials into 0..11,
  // combine -> temp. (gibf/xfbf dead from here.)
  a = {xbf, FIN, BrT, nullptr, nullptr, 1 << 30, tmpP + (size_t)12 * n * RD, nullptr,
       nullptr, n, FIN, RD};
  mg<0, 0>(a, stream);
  ygemm8_k<<<dim3(12 * ((n + 255) / 256)), 512, 0, stream>>>(xbf, QT, lrbf + 192,
                                                             tmpP, n);
  combine_k<<<(n * RD / 4 + 255) / 256, 256, 0, stream>>>(tmpP, temp, (size_t)n * RD,
                                                          n * RD / 4);

  // left path fused: bf16 slice-streamed partials -> ptP[16][n][8], gather
  a = {lrbf, FIN, Wl2T, bl2, nullptr, 1 << 30, ptP, nullptr, temp, n, 192, PD * RD};
  mg<4, 0>(a, stream);
  ptgather_k<<<(n * 16 + 255) / 256, 256, 0, stream>>>(ptP, pt_raw, ptbf, n);

  // 5) GCN2 + projection
  a = {ptbf, PD, Wgcn2T, nullptr, nullptr, 1 << 30, bufHbf, nullptr, nullptr, n, PD, HD};
  mg<0, 1>(a, stream);
  gcn_agg_k<1, 1><<<(n + 3) / 4, 256, 0, stream>>>(bufHbf, dinv, off + n, cnt + n, adj,
                                                   b_gcn2, g2, g2bf, n);
  a = {g2bf, HD, WgpT, b_gp, nullptr, 1 << 30, pg_raw, nullptr, nullptr, n, HD, PD};
  mg<1, 0>(a, stream);

  // 6) normalize + alignment
  final_k<<<(n + 3) / 4, 256, 0, stream>>>(out, n);
}

// Round 15
// 814.074 us; speedup vs baseline: 1.1515x; 1.1153x over previous
//
#include <hip/hip_runtime.h>

typedef unsigned int u32;
typedef unsigned short u16;
typedef short s16x8 __attribute__((ext_vector_type(8)));
typedef u16 u16x8 __attribute__((ext_vector_type(8)));
typedef float f32x4 __attribute__((ext_vector_type(4)));

#define FIN 384
#define HD  128
#define PD  128
#define RD  16

#define GLOAD16(g, l)                                                          \
  __builtin_amdgcn_global_load_lds(                                            \
      (const __attribute__((address_space(1))) void*)(g),                      \
      (__attribute__((address_space(3))) void*)(l), 16, 0, 0)

__device__ __forceinline__ u16 f2bf(float f) {
  u32 u = __float_as_uint(f);
  u32 r = (u + 0x7fffu + ((u >> 16) & 1u)) >> 16;   // RNE
  return (u16)r;
}
__device__ __forceinline__ float bf2f(u16 h) {
  return __uint_as_float(((u32)h) << 16);
}

// XCD-aware bijective block remap (m204): assumes dispatch XCD ~ blockIdx%8.
// Consecutive wgid -> ctile fastest, so each XCD gets complete row-panels.
__device__ __forceinline__ int xcd_wgid() {
  int nwg = gridDim.x, orig = blockIdx.x;
  int q = nwg >> 3, r = nwg & 7, xcd = orig & 7, idx = orig >> 3;
  return (xcd < r ? xcd * (q + 1) : r * (q + 1) + (xcd - r) * q) + idx;
}

// ---------------------------------------------------------------------------
// One descriptor-driven convert kernel for all weights + x.
// mode 0: transpose; mode 1: copy; mode 2: Wr2 Q-permute (q=h*16+r).
// ---------------------------------------------------------------------------
struct CvtEnt { const float* s; u16* d; int K, N, mode, blk0; };
struct CvtDesc { CvtEnt e[12]; int n; };

__global__ void cvt_all_k(CvtDesc dsc) {
  int b = blockIdx.x;
  int ei = 0;
  while (ei + 1 < dsc.n && dsc.e[ei + 1].blk0 <= b) ++ei;
  CvtEnt E = dsc.e[ei];
  int i = (b - E.blk0) * 256 + (int)threadIdx.x;
  int tot = E.K * E.N;
  if (i >= tot) return;
  float v;
  if (E.mode == 0) {
    int c = i / E.K, k = i - c * E.K;
    v = E.s[(size_t)k * E.N + c];
  } else if (E.mode == 1) {
    v = E.s[i];
  } else {
    int q = i / 384, f = i - q * 384;
    v = E.s[(size_t)(q >> 4) * 6144 + (q & 15) * 384 + f];
  }
  E.d[i] = f2bf(v);
}

// ---------------------------------------------------------------------------
// Graph preprocessing (concatenated src|dst arrays, one scan over 2n)
// ---------------------------------------------------------------------------
__global__ void hist_k(const int* __restrict__ src, const int* __restrict__ dst,
                       u32* __restrict__ cnt, int n, int E) {
  int i = blockIdx.x * 256 + threadIdx.x;
  if (i < E) {
    atomicAdd(&cnt[src[i]], 1u);
    atomicAdd(&cnt[n + dst[i]], 1u);
  }
}

__global__ __launch_bounds__(1024)
void scanA_k(const u32* __restrict__ cnt, u32* __restrict__ off,
             u32* __restrict__ bsum, int n2) {
  __shared__ u32 sh[1024];
  int i = blockIdx.x * 1024 + (int)threadIdx.x;
  u32 v = (i < n2) ? cnt[i] : 0u;
  sh[threadIdx.x] = v;
  __syncthreads();
  for (int s = 1; s < 1024; s <<= 1) {
    u32 t = (threadIdx.x >= (u32)s) ? sh[threadIdx.x - s] : 0u;
    __syncthreads();
    sh[threadIdx.x] += t;
    __syncthreads();
  }
  if (i < n2) off[i] = sh[threadIdx.x] - v;       // local exclusive
  if (threadIdx.x == 1023) bsum[blockIdx.x] = sh[1023];
}

__global__ void scanB_k(u32* __restrict__ bsum, int nb) {   // 1 wave, chunks of 64
  int l = threadIdx.x;
  u32 carry = 0u;
  for (int base = 0; base < nb; base += 64) {
    u32 v = (base + l < nb) ? bsum[base + l] : 0u;
    for (int s = 1; s < 64; s <<= 1) {
      u32 t = __shfl_up(v, s);
      if (l >= s) v += t;
    }
    if (base + l < nb) bsum[base + l] = v + carry;
    carry += __shfl(v, 63);
  }
}

__global__ __launch_bounds__(1024)
void scanC_k(u32* __restrict__ off, u32* __restrict__ cur,
             const u32* __restrict__ bsum, int n2) {
  int b = blockIdx.x;
  int i = b * 1024 + (int)threadIdx.x;
  if (i >= n2) return;
  u32 add = (b > 0) ? bsum[b - 1] : 0u;
  u32 o = off[i] + add;
  off[i] = o;
  cur[i] = o;
}

__global__ void fill_k(const int* __restrict__ src, const int* __restrict__ dst,
                       u32* __restrict__ cur, u32* __restrict__ adj, int n, int E) {
  int i = blockIdx.x * 256 + threadIdx.x;
  if (i >= E) return;
  int s = src[i], d = dst[i];
  u32 ps = atomicAdd(&cur[s], 1u);
  adj[ps] = (u32)d;
  u32 pd = atomicAdd(&cur[n + d], 1u);
  adj[pd] = (u32)s;
}

__global__ void dinv_k(const u32* __restrict__ cd, float* __restrict__ dinv, int n) {
  int i = blockIdx.x * 256 + threadIdx.x;
  if (i < n) dinv[i] = 1.0f / sqrtf((float)(cd[i] + 1u));
}

// ---------------------------------------------------------------------------
// GCN aggregation, bf16 in, fp32/bf16 out; 4-edge ILP
// ---------------------------------------------------------------------------
template <int WF32, int WBF>
__global__ void gcn_agg_k(const u16* __restrict__ xw, const float* __restrict__ dinv,
                          const u32* __restrict__ off, const u32* __restrict__ cnt,
                          const u32* __restrict__ nbr, const float* __restrict__ bias,
                          float* __restrict__ outf, u16* __restrict__ outb, int n) {
  int node = (blockIdx.x * blockDim.x + threadIdx.x) >> 6;
  int lane = threadIdx.x & 63;
  if (node >= n) return;
  float di = dinv[node];
  ushort2 v = ((const ushort2*)(xw + (size_t)node * HD))[lane];
  float ax = di * di * bf2f(v.x), ay = di * di * bf2f(v.y);
  u32 i = off[node], end = i + cnt[node];
  for (; i + 4 <= end; i += 4) {
    int s0 = (int)nbr[i],     s1 = (int)nbr[i + 1];
    int s2 = (int)nbr[i + 2], s3 = (int)nbr[i + 3];
    float w0 = di * dinv[s0], w1 = di * dinv[s1];
    float w2 = di * dinv[s2], w3 = di * dinv[s3];
    ushort2 u0 = ((const ushort2*)(xw + (size_t)s0 * HD))[lane];
    ushort2 u1 = ((const ushort2*)(xw + (size_t)s1 * HD))[lane];
    ushort2 u2 = ((const ushort2*)(xw + (size_t)s2 * HD))[lane];
    ushort2 u3 = ((const ushort2*)(xw + (size_t)s3 * HD))[lane];
    ax = fmaf(w0, bf2f(u0.x), ax); ay = fmaf(w0, bf2f(u0.y), ay);
    ax = fmaf(w1, bf2f(u1.x), ax); ay = fmaf(w1, bf2f(u1.y), ay);
    ax = fmaf(w2, bf2f(u2.x), ax); ay = fmaf(w2, bf2f(u2.y), ay);
    ax = fmaf(w3, bf2f(u3.x), ax); ay = fmaf(w3, bf2f(u3.y), ay);
  }
  for (; i < end; ++i) {
    int s0 = (int)nbr[i];
    float w0 = di * dinv[s0];
    ushort2 u0 = ((const ushort2*)(xw + (size_t)s0 * HD))[lane];
    ax = fmaf(w0, bf2f(u0.x), ax);
    ay = fmaf(w0, bf2f(u0.y), ay);
  }
  float2 b = ((const float2*)bias)[lane];
  ax += b.x; ay += b.y;
  if (WF32) ((float2*)(outf + (size_t)node * HD))[lane] = make_float2(ax, ay);
  if (WBF) {
    ushort2 ob; ob.x = f2bf(ax); ob.y = f2bf(ay);
    ((ushort2*)(outb + (size_t)node * HD))[lane] = ob;
  }
}

// ---------------------------------------------------------------------------
// Fused edge scores + scatter-softmax + aggregate + residual (one wave/node).
// Fast path (degree <= 64): scores kept in one register/lane, no global
// round-trip, exp computed once. Fallback = 3-pass global path.
// ---------------------------------------------------------------------------
__global__ void attn_fused_k(const u32* __restrict__ off, const u32* __restrict__ cnt,
                             const u32* __restrict__ adj,
                             const u16* __restrict__ ti, int TS,
                             const u16* __restrict__ gi, int GS,
                             const u16* __restrict__ vmat, int VS,
                             const u16* __restrict__ xb,
                             float* __restrict__ scores,
                             u16* __restrict__ xf, int n) {
  int node = (blockIdx.x * blockDim.x + threadIdx.x) >> 6;
  int lane = threadIdx.x & 63;
  if (node >= n) return;
  u32 o = off[node], c = cnt[node];
  u32 end = o + c;
  float acc[6] = {0.f, 0.f, 0.f, 0.f, 0.f, 0.f};
  const float sc = 0.05103103630798288f;   // 1/sqrt(384)
  if (c > 0) {
    const u16* tp = ti + (size_t)node * TS;
    float tf[6];
#pragma unroll
    for (int q = 0; q < 3; ++q) {
      ushort2 tv = *(const ushort2*)(tp + q * 128 + lane * 2);
      tf[q * 2] = bf2f(tv.x);
      tf[q * 2 + 1] = bf2f(tv.y);
    }
    if (c <= 64) {
      // ---- fast path: per-lane register scores ----
      float sreg = -1e30f;
      u32 i = o;
      for (; i + 2 <= end; i += 2) {
        int d0 = (int)adj[i], d1 = (int)adj[i + 1];
        const u16* g0 = gi + (size_t)d0 * GS;
        const u16* g1 = gi + (size_t)d1 * GS;
        float dot0 = 0.f, dot1 = 0.f;
#pragma unroll
        for (int q = 0; q < 3; ++q) {
          ushort2 a = *(const ushort2*)(g0 + q * 128 + lane * 2);
          ushort2 b = *(const ushort2*)(g1 + q * 128 + lane * 2);
          dot0 = fmaf(tf[q * 2], bf2f(a.x), dot0);
          dot0 = fmaf(tf[q * 2 + 1], bf2f(a.y), dot0);
          dot1 = fmaf(tf[q * 2], bf2f(b.x), dot1);
          dot1 = fmaf(tf[q * 2 + 1], bf2f(b.y), dot1);
        }
#pragma unroll
        for (int s2 = 32; s2 >= 1; s2 >>= 1) {
          dot0 += __shfl_xor(dot0, s2);
          dot1 += __shfl_xor(dot1, s2);
        }
        int idx = (int)(i - o);
        if (lane == idx) sreg = dot0 * sc;
        if (lane == idx + 1) sreg = dot1 * sc;
      }
      if (i < end) {
        int d0 = (int)adj[i];
        const u16* g0 = gi + (size_t)d0 * GS;
        float dot0 = 0.f;
#pragma unroll
        for (int q = 0; q < 3; ++q) {
          ushort2 a = *(const ushort2*)(g0 + q * 128 + lane * 2);
          dot0 = fmaf(tf[q * 2], bf2f(a.x), dot0);
          dot0 = fmaf(tf[q * 2 + 1], bf2f(a.y), dot0);
        }
#pragma unroll
        for (int s2 = 32; s2 >= 1; s2 >>= 1) dot0 += __shfl_xor(dot0, s2);
        if (lane == (int)(i - o)) sreg = dot0 * sc;
      }
      float mx = sreg;
#pragma unroll
      for (int s2 = 32; s2 >= 1; s2 >>= 1) mx = fmaxf(mx, __shfl_xor(mx, s2));
      float ew = (lane < (int)c) ? expf(sreg - mx) : 0.f;
      float den = ew;
#pragma unroll
      for (int s2 = 32; s2 >= 1; s2 >>= 1) den += __shfl_xor(den, s2);
      float wreg = ew / den;
      i = o;
      for (; i + 2 <= end; i += 2) {
        int d0 = (int)adj[i], d1 = (int)adj[i + 1];
        int idx = (int)(i - o);
        float w0 = __shfl(wreg, idx);
        float w1 = __shfl(wreg, idx + 1);
        const u16* v0 = vmat + (size_t)d0 * VS;
        const u16* v1 = vmat + (size_t)d1 * VS;
#pragma unroll
        for (int q = 0; q < 3; ++q) {
          ushort2 a = *(const ushort2*)(v0 + q * 128 + lane * 2);
          ushort2 b = *(const ushort2*)(v1 + q * 128 + lane * 2);
          acc[q * 2]     = fmaf(w0, bf2f(a.x), acc[q * 2]);
          acc[q * 2 + 1] = fmaf(w0, bf2f(a.y), acc[q * 2 + 1]);
          acc[q * 2]     = fmaf(w1, bf2f(b.x), acc[q * 2]);
          acc[q * 2 + 1] = fmaf(w1, bf2f(b.y), acc[q * 2 + 1]);
        }
      }
      if (i < end) {
        int d0 = (int)adj[i];
        float w0 = __shfl(wreg, (int)(i - o));
        const u16* v0 = vmat + (size_t)d0 * VS;
#pragma unroll
        for (int q = 0; q < 3; ++q) {
          ushort2 a = *(const ushort2*)(v0 + q * 128 + lane * 2);
          acc[q * 2]     = fmaf(w0, bf2f(a.x), acc[q * 2]);
          acc[q * 2 + 1] = fmaf(w0, bf2f(a.y), acc[q * 2 + 1]);
        }
      }
    } else {
      // ---- fallback: 3-pass global scores (degree > 64) ----
      float mx = -1e30f;
      u32 i = o;
      for (; i < end; ++i) {
        int d0 = (int)adj[i];
        const u16* g0 = gi + (size_t)d0 * GS;
        float dot0 = 0.f;
#pragma unroll
        for (int q = 0; q < 3; ++q) {
          ushort2 a = *(const ushort2*)(g0 + q * 128 + lane * 2);
          dot0 = fmaf(tf[q * 2], bf2f(a.x), dot0);
          dot0 = fmaf(tf[q * 2 + 1], bf2f(a.y), dot0);
        }
#pragma unroll
        for (int s2 = 32; s2 >= 1; s2 >>= 1) dot0 += __shfl_xor(dot0, s2);
        dot0 *= sc;
        if (lane == 0) scores[i] = dot0;
        mx = fmaxf(mx, dot0);
      }
      float den = 0.f;
      for (u32 k = o + lane; k < end; k += 64) den += expf(scores[k] - mx);
#pragma unroll
      for (int s2 = 32; s2 >= 1; s2 >>= 1) den += __shfl_xor(den, s2);
      float invden = 1.0f / den;
      for (i = o; i < end; ++i) {
        int d0 = (int)adj[i];
        float w0 = expf(scores[i] - mx) * invden;
        const u16* v0 = vmat + (size_t)d0 * VS;
#pragma unroll
        for (int q = 0; q < 3; ++q) {
          ushort2 a = *(const ushort2*)(v0 + q * 128 + lane * 2);
          acc[q * 2]     = fmaf(w0, bf2f(a.x), acc[q * 2]);
          acc[q * 2 + 1] = fmaf(w0, bf2f(a.y), acc[q * 2 + 1]);
        }
      }
    }
  }
  const u16* xp = xb + (size_t)node * FIN;
  u16* op = xf + (size_t)node * FIN;
#pragma unroll
  for (int q = 0; q < 3; ++q) {
    ushort2 xv = *(const ushort2*)(xp + q * 128 + lane * 2);
    ushort2 ov;
    ov.x = f2bf(acc[q * 2] + bf2f(xv.x));
    ov.y = f2bf(acc[q * 2 + 1] + bf2f(xv.y));
    *(ushort2*)(op + q * 128 + lane * 2) = ov;
  }
}

// ---------------------------------------------------------------------------
// MFMA bf16 GEMM (2-phase 128x128), 1-D grid + XCD swizzle (T1).
// EPI 0/1/2: none / +bias / relu(+bias); split-bias at bsplit.
// EPI 4 (left): TRANSPOSED fragments — mfma(b,a) computes C^T so r=(col&15)
//   lives in (lane>>4,reg): r-sum = 3 reg-adds + 2 shuffles (vs 4-shuffle
//   trees per col). bias/temp as aligned float4; 8B ushort4 slice stores.
// EPI 6 (tv+gcn1 merged, Nc=896): col<768 -> Cp; col>=768 -> Cbf2.
// ---------------------------------------------------------------------------
template <int EPI, int OUTBF>
__global__ __launch_bounds__(256)
void mgemm_k(const u16* __restrict__ Abf, int As, const u16* __restrict__ WT,
             const float* __restrict__ bias, const float* __restrict__ bias_b, int bsplit,
             void* __restrict__ Cp, u16* __restrict__ Cbf2,
             float* __restrict__ tmp, int M, int K, int Nc, int ncx) {
  __shared__ u16 Albuf[2][128 * 32];
  __shared__ u16 Blbuf[2][128 * 32];
  const int t = threadIdx.x;
  const int lane = t & 63;
  const int wave = t >> 6;
  const int wr = wave >> 1, wc = wave & 1;
  const int wgid = xcd_wgid();
  const int ctile = wgid % ncx;
  const int row0 = (wgid / ncx) * 128;
  const int col0 = ctile * 128;
  const int sr = t >> 2;
  const int sk = (t & 3) * 8;
  const int nt = K >> 5;

  f32x4 acc[4][4] = {};

  auto stage = [&](int buf, int k0) {
#pragma unroll
    for (int h = 0; h < 2; ++h) {
      int ar = row0 + h * 64 + sr;
      if (ar >= M) ar = M - 1;
      GLOAD16(Abf + (size_t)ar * As + k0 + sk, &Albuf[buf][h * 2048 + wave * 512]);
    }
#pragma unroll
    for (int h = 0; h < 2; ++h) {
      int bc = col0 + h * 64 + sr;
      if (bc >= Nc) bc = Nc - 1;
      GLOAD16(WT + (size_t)bc * K + k0 + sk, &Blbuf[buf][h * 2048 + wave * 512]);
    }
  };

  stage(0, 0);
  int buf = 0;
  for (int tk = 0; tk < nt; ++tk) {
    __syncthreads();
    if (tk + 1 < nt) stage(buf ^ 1, (tk + 1) << 5);
    const u16* Al = Albuf[buf];
    const u16* Bl = Blbuf[buf];
    s16x8 a[4], b[4];
#pragma unroll
    for (int m = 0; m < 4; ++m)
      a[m] = *(const s16x8*)(Al + (wr * 64 + m * 16 + (lane & 15)) * 32 + (lane >> 4) * 8);
#pragma unroll
    for (int j = 0; j < 4; ++j)
      b[j] = *(const s16x8*)(Bl + (wc * 64 + j * 16 + (lane & 15)) * 32 + (lane >> 4) * 8);
    if constexpr (EPI == 4) {
      // transposed: acc[mc][jr] = C^T frag for cols mc*16.., rows jr*16..
#pragma unroll
      for (int mc = 0; mc < 4; ++mc)
#pragma unroll
        for (int jr = 0; jr < 4; ++jr)
          acc[mc][jr] = __builtin_amdgcn_mfma_f32_16x16x32_bf16(b[mc], a[jr], acc[mc][jr], 0, 0, 0);
    } else {
#pragma unroll
      for (int m = 0; m < 4; ++m)
#pragma unroll
        for (int j = 0; j < 4; ++j)
          acc[m][j] = __builtin_amdgcn_mfma_f32_16x16x32_bf16(a[m], b[j], acc[m][j], 0, 0, 0);
    }
    buf ^= 1;
  }

  if constexpr (EPI <= 2) {
#pragma unroll
    for (int m = 0; m < 4; ++m) {
      int rbase = row0 + wr * 64 + m * 16 + (lane >> 4) * 4;
#pragma unroll
      for (int j = 0; j < 4; ++j) {
        int col = col0 + wc * 64 + j * 16 + (lane & 15);
        if (col >= Nc) continue;
        float bv = 0.f;
        if (EPI >= 1) bv = (col < bsplit) ? bias[col] : bias_b[col - bsplit];
#pragma unroll
        for (int r = 0; r < 4; ++r) {
          int row = rbase + r;
          if (row >= M) continue;
          float v = acc[m][j][r] + bv;
          if (EPI == 2) v = fmaxf(v, 0.f);
          if (OUTBF) ((u16*)Cp)[(size_t)row * Nc + col] = f2bf(v);
          else       ((float*)Cp)[(size_t)row * Nc + col] = v;
        }
      }
    }
  } else if constexpr (EPI == 6) {
#pragma unroll
    for (int m = 0; m < 4; ++m) {
      int rbase = row0 + wr * 64 + m * 16 + (lane >> 4) * 4;
#pragma unroll
      for (int j = 0; j < 4; ++j) {
        int col = col0 + wc * 64 + j * 16 + (lane & 15);
        if (col < 2 * FIN) {
          float bv = (col < bsplit) ? bias[col] : bias_b[col - bsplit];
#pragma unroll
          for (int r = 0; r < 4; ++r) {
            int row = rbase + r;
            if (row >= M) continue;
            ((u16*)Cp)[(size_t)row * (2 * FIN) + col] = f2bf(acc[m][j][r] + bv);
          }
        } else {
          int c2 = col - 2 * FIN;
#pragma unroll
          for (int r = 0; r < 4; ++r) {
            int row = rbase + r;
            if (row >= M) continue;
            Cbf2[(size_t)row * HD + c2] = f2bf(acc[m][j][r]);
          }
        }
      }
    }
  } else {  // EPI == 4: transposed fold + bf16 slice-stream
    // acc[mc][jr][reg]: row = row0+wr*64+jr*16+(lane&15),
    //                   col = col0+wc*64+mc*16+(lane>>4)*4+reg, r = col&15.
    u16* slice = (u16*)Cp + (size_t)ctile * M * 8;
    float4 b4[4];
#pragma unroll
    for (int mc = 0; mc < 4; ++mc)
      b4[mc] = *(const float4*)&bias[col0 + wc * 64 + mc * 16 + (lane >> 4) * 4];
#pragma unroll
    for (int jr = 0; jr < 4; ++jr) {
      int row = row0 + wr * 64 + jr * 16 + (lane & 15);
      int rc = row < M ? row : M - 1;
      float4 tv = *(const float4*)&tmp[(size_t)rc * RD + (lane >> 4) * 4];
      ushort4 outp;
#pragma unroll
      for (int mc = 0; mc < 4; ++mc) {
        float s = (acc[mc][jr][0] + b4[mc].x) * tv.x +
                  (acc[mc][jr][1] + b4[mc].y) * tv.y +
                  (acc[mc][jr][2] + b4[mc].z) * tv.z +
                  (acc[mc][jr][3] + b4[mc].w) * tv.w;
        s += __shfl_xor(s, 16);
        s += __shfl_xor(s, 32);
        ((u16*)&outp)[mc] = f2bf(s);
      }
      if (lane < 16 && row < M)
        *(ushort4*)(slice + (size_t)row * 8 + wc * 4) = outp;
    }
  }
}

// ---------------------------------------------------------------------------
// pt gather: pt[row][ct*8+pl] = bf2f(ptP[ct][row][pl]); coalesced full rows,
// fp32 + bf16 outputs.
// ---------------------------------------------------------------------------
__global__ void ptgather_k(const u16* __restrict__ ptP, float* __restrict__ pt,
                           u16* __restrict__ ptb, int n) {
  int g = blockIdx.x * 256 + threadIdx.x;
  if (g >= n * 16) return;
  int row = g >> 4, ct = g & 15;
  const u16* sp = ptP + ((size_t)ct * n + (size_t)row) * 8;
  ushort4 a = ((const ushort4*)sp)[0];
  ushort4 b = ((const ushort4*)sp)[1];
  float* dp = pt + (size_t)row * PD + ct * 8;
  ((float4*)dp)[0] = make_float4(bf2f(a.x), bf2f(a.y), bf2f(a.z), bf2f(a.w));
  ((float4*)dp)[1] = make_float4(bf2f(b.x), bf2f(b.y), bf2f(b.z), bf2f(b.w));
  u16* db = ptb + (size_t)row * PD + ct * 8;
  ((ushort4*)db)[0] = a;
  ((ushort4*)db)[1] = b;
}

// ---------------------------------------------------------------------------
// Y-GEMM, 8-phase 256x256/BK=64/8-wave (T3+T4+T2+T5), race-verified (r8),
// 1-D grid + XCD swizzle (ncx=12 col-groups).
// ---------------------------------------------------------------------------
#define VM6  asm volatile("s_waitcnt vmcnt(6)" ::: "memory")
#define VM0  asm volatile("s_waitcnt vmcnt(0)" ::: "memory")
#define VMNOP
#define BARR asm volatile("s_barrier" ::: "memory")

__global__ __launch_bounds__(512)
void ygemm8_k(const u16* __restrict__ X, const u16* __restrict__ QT,
              const u16* __restrict__ Ar, float* __restrict__ tmpP, int M) {
  __shared__ u16 Al[2][16384];
  __shared__ u16 Bl[2][16384];
  const int t = threadIdx.x;
  const int lane = t & 63;
  const int wave = t >> 6;
  const int wr = wave >> 2;
  const int wcn = wave & 3;
  const int wgid = xcd_wgid();
  const int ctile = wgid % 12;
  const int row0 = (wgid / 12) * 256;
  const int col0 = ctile * 256;

  const int srow = t >> 3;
  const int sgk  = (((t & 7) ^ (srow & 7)) << 3);
  const int sdst = t * 8;

  const int pc0 = (((lane >> 4)) ^ (lane & 7)) << 3;
  const int pc1 = ((((lane >> 4) + 4)) ^ (lane & 7)) << 3;
  const int arow = (wr * 128 + (lane & 15)) << 6;
  const int brow = (wcn * 64 + (lane & 15)) << 6;

  f32x4 acc[8][4] = {};
  s16x8 a[4][2], b[4][2];

#define STGA8(bf, h, kt) do {                                                  \
    int r0_ = row0 + (h) * 128 + srow;                                         \
    int r1_ = r0_ + 64;                                                        \
    if (r0_ >= M) r0_ = M - 1;                                                 \
    if (r1_ >= M) r1_ = M - 1;                                                 \
    GLOAD16(X + (size_t)r0_ * 384 + (kt) * 64 + sgk, &Al[bf][(h) * 8192 + sdst]);        \
    GLOAD16(X + (size_t)r1_ * 384 + (kt) * 64 + sgk, &Al[bf][(h) * 8192 + 4096 + sdst]); \
  } while (0)

#define STGB8(bf, h, kt) do {                                                  \
    int c0_ = col0 + (h) * 128 + srow;                                         \
    GLOAD16(QT + (size_t)c0_ * 384 + (kt) * 64 + sgk, &Bl[bf][(h) * 8192 + sdst]);       \
    GLOAD16(QT + (size_t)(c0_ + 64) * 384 + (kt) * 64 + sgk,                   \
            &Bl[bf][(h) * 8192 + 4096 + sdst]);                                \
  } while (0)

#define LDA8(bf, mh) do {                                                      \
    _Pragma("unroll") for (int m2_ = 0; m2_ < 4; ++m2_) {                      \
      const u16* p_ = &Al[bf][arow + ((mh) * 4 + m2_) * 1024];                 \
      a[m2_][0] = *(const s16x8*)(p_ + pc0);                                   \
      a[m2_][1] = *(const s16x8*)(p_ + pc1);                                   \
    }                                                                          \
  } while (0)

#define LDB8(bf, jh) do {                                                      \
    _Pragma("unroll") for (int j2_ = 0; j2_ < 2; ++j2_) {                      \
      const u16* p_ = &Bl[bf][brow + ((jh) * 2 + j2_) * 1024];                 \
      b[(jh) * 2 + j2_][0] = *(const s16x8*)(p_ + pc0);                        \
      b[(jh) * 2 + j2_][1] = *(const s16x8*)(p_ + pc1);                        \
    }                                                                          \
  } while (0)

#define MQ8(mh, jh) do {                                                       \
    __builtin_amdgcn_s_setprio(1);                                             \
    _Pragma("unroll") for (int m2_ = 0; m2_ < 4; ++m2_)                        \
      _Pragma("unroll") for (int j2_ = 0; j2_ < 2; ++j2_)                      \
        _Pragma("unroll") for (int ks_ = 0; ks_ < 2; ++ks_)                    \
          acc[(mh) * 4 + m2_][(jh) * 2 + j2_] =                                \
              __builtin_amdgcn_mfma_f32_16x16x32_bf16(                         \
                  a[m2_][ks_], b[(jh) * 2 + j2_][ks_],                         \
                  acc[(mh) * 4 + m2_][(jh) * 2 + j2_], 0, 0, 0);               \
    __builtin_amdgcn_s_setprio(0);                                             \
  } while (0)

  STGA8(0, 0, 0); STGA8(0, 1, 0); STGB8(0, 0, 0); STGB8(0, 1, 0);
  STGA8(1, 0, 1); STGB8(1, 0, 1); STGB8(1, 1, 1);
  VM6; BARR;

#define ITER8(i, VMP3, VMP7, DOSTG)                                                          \
  /*ph0*/ LDA8(0,0); LDB8(0,0); STGA8(1,1,2*(i)+1);                   BARR; MQ8(0,0); BARR;  \
  /*ph1*/ LDB8(0,1);                                                  BARR; MQ8(0,1); BARR;  \
  /*ph2*/ LDA8(0,1); if (DOSTG) STGB8(0,0,2*(i)+2);                   BARR; MQ8(1,0); BARR;  \
  /*ph3*/ if (DOSTG) { STGB8(0,1,2*(i)+2); STGA8(0,0,2*(i)+2); } VMP3; BARR; MQ8(1,1); BARR; \
  /*ph4*/ LDA8(1,0); LDB8(1,0); if (DOSTG) STGA8(0,1,2*(i)+2);        BARR; MQ8(0,0); BARR;  \
  /*ph5*/ LDB8(1,1);                                                  BARR; MQ8(0,1); BARR;  \
  /*ph6*/ LDA8(1,1); if (DOSTG) STGB8(1,0,2*(i)+3);                   BARR; MQ8(1,0); BARR;  \
  /*ph7*/ if (DOSTG) { STGB8(1,1,2*(i)+3); STGA8(1,0,2*(i)+3); } VMP7; BARR; MQ8(1,1); BARR;

  ITER8(0, VM6, VM6, 1)
  ITER8(1, VM6, VM6, 1)
  ITER8(2, VM0, VMNOP, 0)

  // fold: s[m][rr] = sum_j relu_r[row, h0+j] * acc[m][j][rr]
  const int h0 = (col0 >> 4) + wcn * 4;
  float s[8][4];
#pragma unroll
  for (int m = 0; m < 8; ++m) {
#pragma unroll
    for (int rr = 0; rr < 4; ++rr) {
      int row = row0 + wr * 128 + m * 16 + (lane >> 4) * 4 + rr;
      int rc = row < M ? row : M - 1;
      ushort4 arv = *(const ushort4*)(Ar + (size_t)rc * 384 + h0);
      s[m][rr] = bf2f(arv.x) * acc[m][0][rr] + bf2f(arv.y) * acc[m][1][rr] +
                 bf2f(arv.z) * acc[m][2][rr] + bf2f(arv.w) * acc[m][3][rr];
    }
  }

  __syncthreads();
  float* redA = (float*)&Al[0][0];
  float* redB = redA + 4096;
  const int r16 = lane & 15;
  const int rlb = wr * 128 + (lane >> 4) * 4;
  if (wcn & 1) {
    float* red = (wcn == 1) ? redA : redB;
#pragma unroll
    for (int m = 0; m < 8; ++m)
#pragma unroll
      for (int rr = 0; rr < 4; ++rr)
        red[(rlb + m * 16 + rr) * 16 + r16] = s[m][rr];
  }
  __syncthreads();
  if (!(wcn & 1)) {
    float* red = (wcn == 0) ? redA : redB;
#pragma unroll
    for (int m = 0; m < 8; ++m)
#pragma unroll
      for (int rr = 0; rr < 4; ++rr)
        s[m][rr] += red[(rlb + m * 16 + rr) * 16 + r16];
  }
  __syncthreads();
  if (wcn == 2) {
#pragma unroll
    for (int m = 0; m < 8; ++m)
#pragma unroll
      for (int rr = 0; rr < 4; ++rr)
        redA[(rlb + m * 16 + rr) * 16 + r16] = s[m][rr];
  }
  __syncthreads();
  if (wcn == 0) {
    float* slice = tmpP + (size_t)ctile * M * RD;
#pragma unroll
    for (int m = 0; m < 8; ++m)
#pragma unroll
      for (int rr = 0; rr < 4; ++rr) {
        int row = row0 + rlb + m * 16 + rr;
        if (row < M)
          slice[(size_t)row * RD + r16] =
              s[m][rr] + redA[(rlb + m * 16 + rr) * 16 + r16];
      }
  }
#undef STGA8
#undef STGB8
#undef LDA8
#undef LDB8
#undef MQ8
#undef ITER8
}

// ---------------------------------------------------------------------------
// combine: temp[i] = sum_{s=0..12} tmpP[s][i]   (slice 12 = x@Br bias term)
// ---------------------------------------------------------------------------
__global__ void combine_k(const float* __restrict__ tmpP, float* __restrict__ temp,
                          size_t sl, int tot4) {
  int i = blockIdx.x * 256 + threadIdx.x;
  if (i >= tot4) return;
  float4 s = ((const float4*)(tmpP + 12 * sl))[i];
#pragma unroll
  for (int c = 0; c < 12; ++c) {
    float4 p = ((const float4*)(tmpP + (size_t)c * sl))[i];
    s.x += p.x; s.y += p.y; s.z += p.z; s.w += p.w;
  }
  ((float4*)temp)[i] = s;
}

// ---------------------------------------------------------------------------
// Final: in-place row-normalize p_t, p_g; alignment = dot of normalized rows.
// ---------------------------------------------------------------------------
__global__ void final_k(float* __restrict__ out, int n) {
  int node = (blockIdx.x * blockDim.x + threadIdx.x) >> 6;
  int lane = threadIdx.x & 63;
  if (node >= n) return;
  float* pt = out + n + (size_t)node * PD;
  float* pg = out + n + (size_t)n * PD + (size_t)node * PD;
  float2 t = ((float2*)pt)[lane];
  float2 g = ((float2*)pg)[lane];
  float tt = t.x * t.x + t.y * t.y;
  float gg = g.x * g.x + g.y * g.y;
  float tg = t.x * g.x + t.y * g.y;
#pragma unroll
  for (int s = 32; s >= 1; s >>= 1) {
    tt += __shfl_xor(tt, s);
    gg += __shfl_xor(gg, s);
    tg += __shfl_xor(tg, s);
  }
  float invt = 1.0f / fmaxf(sqrtf(tt), 1e-12f);
  float invg = 1.0f / fmaxf(sqrtf(gg), 1e-12f);
  ((float2*)pt)[lane] = make_float2(t.x * invt, t.y * invt);
  ((float2*)pg)[lane] = make_float2(g.x * invg, g.y * invg);
  if (lane == 0) out[node] = tg * invt * invg;
}

// ---------------------------------------------------------------------------
struct MgArgs {
  const u16* A; int As; const u16* WT;
  const float* b; const float* b2; int bsplit;
  void* C; u16* C2; float* tmp;
  int M, K, Nc;
};
template <int EPI, int OUTBF>
static void mg(const MgArgs& a, hipStream_t s) {
  int ncx = (a.Nc + 127) / 128, nry = (a.M + 127) / 128;
  mgemm_k<EPI, OUTBF><<<dim3(ncx * nry), 256, 0, s>>>(
      a.A, a.As, a.WT, a.b, a.b2, a.bsplit, a.C, a.C2, a.tmp,
      a.M, a.K, a.Nc, ncx);
}

extern "C" void kernel_launch(void* const* d_in, const int* in_sizes, int n_in,
                              void* d_out, int out_size, void* d_ws, size_t ws_size,
                              hipStream_t stream) {
  const float* x      = (const float*)d_in[0];
  const int*   ei     = (const int*)d_in[1];
  const float* W_gcn1 = (const float*)d_in[2];
  const float* b_gcn1 = (const float*)d_in[3];
  const float* W_ti   = (const float*)d_in[4];
  const float* b_ti   = (const float*)d_in[5];
  const float* W_gi   = (const float*)d_in[6];
  const float* b_gi   = (const float*)d_in[7];
  const float* W_v    = (const float*)d_in[8];
  const float* b_v    = (const float*)d_in[9];
  const float* Wl1    = (const float*)d_in[10];
  const float* bl1    = (const float*)d_in[11];
  const float* Wl2    = (const float*)d_in[12];
  const float* bl2    = (const float*)d_in[13];
  const float* Wr1    = (const float*)d_in[14];
  const float* br1    = (const float*)d_in[15];
  const float* Wr2    = (const float*)d_in[16];
  const float* br2    = (const float*)d_in[17];
  const float* W_gcn2 = (const float*)d_in[18];
  const float* b_gcn2 = (const float*)d_in[19];
  const float* W_gp   = (const float*)d_in[20];
  const float* b_gp   = (const float*)d_in[21];

  const int n = in_sizes[0] / FIN;   // 50000
  const int E = in_sizes[1] / 2;     // 500000
  const int* src = ei;
  const int* dst = ei + E;

  // -------- workspace carve (tmpP/ptP overlay gibf+xfbf) --------
  char* wsp = (char*)d_ws;
  auto carve = [&](size_t bytes) -> void* {
    void* p = (void*)wsp;
    wsp += (bytes + 255) & ~(size_t)255;
    return p;
  };
  u32* cnt      = (u32*)carve((size_t)2 * n * 4);   // [src | dst]
  u32* off      = (u32*)carve((size_t)2 * n * 4);
  u32* cur      = (u32*)carve((size_t)2 * n * 4);
  u32* bsum     = (u32*)carve(512);
  u32* adj      = (u32*)carve((size_t)2 * E * 4);   // [src-CSR dsts | dst-CSR srcs]
  float* dinv   = (float*)carve((size_t)n * 4);
  float* scores = (float*)carve((size_t)E * 4);
  float* temp   = (float*)carve((size_t)n * RD * 4);

  u16* xbf    = (u16*)carve((size_t)n * FIN * 2);       // x bf16 (pristine)
  u16* tvbf   = (u16*)carve((size_t)n * 2 * FIN * 2);   // [t_info | v]; later lrbf
  u16* bufHbf = (u16*)carve((size_t)n * HD * 2);        // xw (both GCNs)
  u16* gembf  = (u16*)carve((size_t)n * HD * 2);
  u16* ptbf   = (u16*)carve((size_t)n * PD * 2);
  u16* g2bf   = (u16*)carve((size_t)n * HD * 2);

  // gibf and xfbf adjacent; tmpP (13 x n*16 fp32 = 41.6 MB) overlays them;
  // ptP (16 x n*8 bf16 = 12.8 MB) reuses the same region after combine.
  u16* gibf   = (u16*)carve((size_t)n * FIN * 2);       // g_info
  u16* xfbf   = (u16*)carve((size_t)n * FIN * 2);       // x_fused
  size_t tmpP_bytes = (size_t)13 * n * RD * 4;
  size_t overlay    = (size_t)2 * n * FIN * 2;
  carve(tmpP_bytes > overlay ? tmpP_bytes - overlay : 0);
  float* tmpP = (float*)gibf;
  u16* ptP    = (u16*)gibf;   // reused after combine_k (slices dead)

  u16* WtvT   = (u16*)carve((size_t)2 * FIN * FIN * 2); // [768][384]
  u16* WgcnT  = (u16*)carve((size_t)HD * FIN * 2);      // [128][384], contiguous
  u16* WgiT   = (u16*)carve((size_t)FIN * HD * 2);      // [384][128]
  u16* WlrT   = (u16*)carve((size_t)FIN * FIN * 2);     // [384][384]
  u16* Wl2T   = (u16*)carve((size_t)2048 * 192 * 2);
  u16* QT     = (u16*)carve((size_t)3072 * FIN * 2);    // permuted Wr2
  u16* BrT    = (u16*)carve((size_t)RD * FIN * 2);      // br2 reshaped [16][384]
  u16* Wgcn2T = (u16*)carve((size_t)HD * PD * 2);
  u16* WgpT   = (u16*)carve((size_t)PD * PD * 2);

  u16* lrbf = tvbf;   // [relu_l | relu_r], stride 384; tv dead after attn

  float* out    = (float*)d_out;
  float* pt_raw = out + n;
  float* pg_raw = out + n + (size_t)n * PD;
  float* g2     = out + n + (size_t)2 * n * PD;

  // 0) all converts in one launch
  CvtDesc dsc;
  int nent = 0, blk = 0;
  auto addent = [&](const float* s, u16* d, int K, int N, int mode) {
    dsc.e[nent] = {s, d, K, N, mode, blk};
    blk += (K * N + 255) / 256;
    ++nent;
  };
  addent(x,      xbf,    n * FIN, 1, 1);
  addent(W_ti,   WtvT,   FIN, FIN, 0);
  addent(W_v,    WtvT + (size_t)FIN * FIN, FIN, FIN, 0);
  addent(W_gcn1, WgcnT,  FIN, HD,  0);
  addent(W_gi,   WgiT,   HD,  FIN, 0);
  addent(Wl1,    WlrT,   FIN, 192, 0);
  addent(Wr1,    WlrT + (size_t)192 * FIN, FIN, 192, 0);
  addent(Wl2,    Wl2T,   192, 2048, 0);
  addent(Wr2,    QT,     FIN, 3072, 2);
  addent(br2,    BrT,    RD * FIN, 1, 1);
  addent(W_gcn2, Wgcn2T, PD, HD, 0);
  addent(W_gp,   WgpT,   PD, PD, 0);
  dsc.n = nent;
  cvt_all_k<<<blk, 256, 0, stream>>>(dsc);

  // 1) CSR build + degrees (one concatenated scan over 2n)
  hipMemsetAsync(cnt, 0, (size_t)2 * n * 4, stream);
  hist_k<<<(E + 255) / 256, 256, 0, stream>>>(src, dst, cnt, n, E);
  int n2 = 2 * n;
  int nb = (n2 + 1023) / 1024;
  scanA_k<<<nb, 1024, 0, stream>>>(cnt, off, bsum, n2);
  scanB_k<<<1, 64, 0, stream>>>(bsum, nb);
  scanC_k<<<nb, 1024, 0, stream>>>(off, cur, bsum, n2);
  fill_k<<<(E + 255) / 256, 256, 0, stream>>>(src, dst, cur, adj, n, E);
  dinv_k<<<(n + 255) / 256, 256, 0, stream>>>(cnt + n, dinv, n);

  MgArgs a{};

  // 2+3a) merged GEMM: [t_info | v | xw_gcn1], Nc=896 (EPI 6)
  a = {xbf, FIN, WtvT, b_ti, b_v, FIN, tvbf, bufHbf, nullptr, n, FIN, 896};
  mg<6, 1>(a, stream);
  gcn_agg_k<0, 1><<<(n + 3) / 4, 256, 0, stream>>>(bufHbf, dinv, off + n, cnt + n, adj,
                                                   b_gcn1, nullptr, gembf, n);

  // 3b) g_info GEMM; fused scores+softmax+aggregate+residual
  a = {gembf, HD, WgiT, b_gi, nullptr, 1 << 30, gibf, nullptr, nullptr, n, HD, FIN};
  mg<1, 1>(a, stream);
  attn_fused_k<<<(n + 3) / 4, 256, 0, stream>>>(off, cnt, adj, tvbf, 2 * FIN, gibf, FIN,
                                                tvbf + FIN, 2 * FIN, xbf, scores, xfbf, n);

  // 4) Generators: [relu_l | relu_r] in one GEMM (overwrites tv buffer)
  a = {xfbf, FIN, WlrT, bl1, br1, 192, lrbf, nullptr, nullptr, n, FIN, FIN};
  mg<2, 1>(a, stream);

  // right path: x@Br into tmpP slice 12, 8-phase Y-GEMM partials into 0..11,
  // combine -> temp. (gibf/xfbf dead from here.)
  a = {xbf, FIN, BrT, nullptr, nullptr, 1 << 30, tmpP + (size_t)12 * n * RD, nullptr,
       nullptr, n, FIN, RD};
  mg<0, 0>(a, stream);
  ygemm8_k<<<dim3(12 * ((n + 255) / 256)), 512, 0, stream>>>(xbf, QT, lrbf + 192,
                                                             tmpP, n);
  combine_k<<<(n * RD / 4 + 255) / 256, 256, 0, stream>>>(tmpP, temp, (size_t)n * RD,
                                                          n * RD / 4);

  // left path fused (transposed-fragment fold): ptP[16][n][8], then gather
  a = {lrbf, FIN, Wl2T, bl2, nullptr, 1 << 30, ptP, nullptr, temp, n, 192, PD * RD};
  mg<4, 0>(a, stream);
  ptgather_k<<<(n * 16 + 255) / 256, 256, 0, stream>>>(ptP, pt_raw, ptbf, n);

  // 5) GCN2 + projection
  a = {ptbf, PD, Wgcn2T, nullptr, nullptr, 1 << 30, bufHbf, nullptr, nullptr, n, PD, HD};
  mg<0, 1>(a, stream);
  gcn_agg_k<1, 1><<<(n + 3) / 4, 256, 0, stream>>>(bufHbf, dinv, off + n, cnt + n, adj,
                                                   b_gcn2, g2, g2bf, n);
  a = {g2bf, HD, WgpT, b_gp, nullptr, 1 << 30, pg_raw, nullptr, nullptr, n, HD, PD};
  mg<1, 0>(a, stream);

  // 6) normalize + alignment
  final_k<<<(n + 3) / 4, 256, 0, stream>>>(out, n);
}

// Round 16
// 789.584 us; speedup vs baseline: 1.1872x; 1.0310x over previous
//
#include <hip/hip_runtime.h>

typedef unsigned int u32;
typedef unsigned short u16;
typedef short s16x8 __attribute__((ext_vector_type(8)));
typedef u16 u16x8 __attribute__((ext_vector_type(8)));
typedef float f32x4 __attribute__((ext_vector_type(4)));

#define FIN 384
#define HD  128
#define PD  128
#define RD  16

#define GLOAD16(g, l)                                                          \
  __builtin_amdgcn_global_load_lds(                                            \
      (const __attribute__((address_space(1))) void*)(g),                      \
      (__attribute__((address_space(3))) void*)(l), 16, 0, 0)

__device__ __forceinline__ u16 f2bf(float f) {
  u32 u = __float_as_uint(f);
  u32 r = (u + 0x7fffu + ((u >> 16) & 1u)) >> 16;   // RNE
  return (u16)r;
}
__device__ __forceinline__ float bf2f(u16 h) {
  return __uint_as_float(((u32)h) << 16);
}

// XCD-aware bijective block remap (m204): assumes dispatch XCD ~ blockIdx%8.
__device__ __forceinline__ int xcd_wgid() {
  int nwg = gridDim.x, orig = blockIdx.x;
  int q = nwg >> 3, r = nwg & 7, xcd = orig & 7, idx = orig >> 3;
  return (xcd < r ? xcd * (q + 1) : r * (q + 1) + (xcd - r) * q) + idx;
}

// ---------------------------------------------------------------------------
// One descriptor-driven convert kernel for all weights + x.
// mode 0: transpose; mode 1: copy; mode 2: Wr2 Q-permute (q=h*16+r).
// ---------------------------------------------------------------------------
struct CvtEnt { const float* s; u16* d; int K, N, mode, blk0; };
struct CvtDesc { CvtEnt e[12]; int n; };

__global__ void cvt_all_k(CvtDesc dsc) {
  int b = blockIdx.x;
  int ei = 0;
  while (ei + 1 < dsc.n && dsc.e[ei + 1].blk0 <= b) ++ei;
  CvtEnt E = dsc.e[ei];
  int i = (b - E.blk0) * 256 + (int)threadIdx.x;
  int tot = E.K * E.N;
  if (i >= tot) return;
  float v;
  if (E.mode == 0) {
    int c = i / E.K, k = i - c * E.K;
    v = E.s[(size_t)k * E.N + c];
  } else if (E.mode == 1) {
    v = E.s[i];
  } else {
    int q = i / 384, f = i - q * 384;
    v = E.s[(size_t)(q >> 4) * 6144 + (q & 15) * 384 + f];
  }
  E.d[i] = f2bf(v);
}

// ---------------------------------------------------------------------------
// Graph preprocessing (concatenated src|dst arrays, one scan over 2n)
// ---------------------------------------------------------------------------
__global__ void hist_k(const int* __restrict__ src, const int* __restrict__ dst,
                       u32* __restrict__ cnt, int n, int E) {
  int i = blockIdx.x * 256 + threadIdx.x;
  if (i < E) {
    atomicAdd(&cnt[src[i]], 1u);
    atomicAdd(&cnt[n + dst[i]], 1u);
  }
}

__global__ __launch_bounds__(1024)
void scanA_k(const u32* __restrict__ cnt, u32* __restrict__ off,
             u32* __restrict__ bsum, int n2) {
  __shared__ u32 sh[1024];
  int i = blockIdx.x * 1024 + (int)threadIdx.x;
  u32 v = (i < n2) ? cnt[i] : 0u;
  sh[threadIdx.x] = v;
  __syncthreads();
  for (int s = 1; s < 1024; s <<= 1) {
    u32 t = (threadIdx.x >= (u32)s) ? sh[threadIdx.x - s] : 0u;
    __syncthreads();
    sh[threadIdx.x] += t;
    __syncthreads();
  }
  if (i < n2) off[i] = sh[threadIdx.x] - v;       // local exclusive
  if (threadIdx.x == 1023) bsum[blockIdx.x] = sh[1023];
}

__global__ void scanB_k(u32* __restrict__ bsum, int nb) {   // 1 wave, chunks of 64
  int l = threadIdx.x;
  u32 carry = 0u;
  for (int base = 0; base < nb; base += 64) {
    u32 v = (base + l < nb) ? bsum[base + l] : 0u;
    for (int s = 1; s < 64; s <<= 1) {
      u32 t = __shfl_up(v, s);
      if (l >= s) v += t;
    }
    if (base + l < nb) bsum[base + l] = v + carry;
    carry += __shfl(v, 63);
  }
}

__global__ __launch_bounds__(1024)
void scanC_k(u32* __restrict__ off, u32* __restrict__ cur,
             const u32* __restrict__ bsum, int n2) {
  int b = blockIdx.x;
  int i = b * 1024 + (int)threadIdx.x;
  if (i >= n2) return;
  u32 add = (b > 0) ? bsum[b - 1] : 0u;
  u32 o = off[i] + add;
  off[i] = o;
  cur[i] = o;
}

__global__ void fill_k(const int* __restrict__ src, const int* __restrict__ dst,
                       u32* __restrict__ cur, u32* __restrict__ adj, int n, int E) {
  int i = blockIdx.x * 256 + threadIdx.x;
  if (i >= E) return;
  int s = src[i], d = dst[i];
  u32 ps = atomicAdd(&cur[s], 1u);
  adj[ps] = (u32)d;
  u32 pd = atomicAdd(&cur[n + d], 1u);
  adj[pd] = (u32)s;
}

__global__ void dinv_k(const u32* __restrict__ cd, float* __restrict__ dinv, int n) {
  int i = blockIdx.x * 256 + threadIdx.x;
  if (i < n) dinv[i] = 1.0f / sqrtf((float)(cd[i] + 1u));
}

// ---------------------------------------------------------------------------
// GCN aggregation, bf16 in, fp32/bf16 out; 4-edge ILP
// ---------------------------------------------------------------------------
template <int WF32, int WBF>
__global__ void gcn_agg_k(const u16* __restrict__ xw, const float* __restrict__ dinv,
                          const u32* __restrict__ off, const u32* __restrict__ cnt,
                          const u32* __restrict__ nbr, const float* __restrict__ bias,
                          float* __restrict__ outf, u16* __restrict__ outb, int n) {
  int node = (blockIdx.x * blockDim.x + threadIdx.x) >> 6;
  int lane = threadIdx.x & 63;
  if (node >= n) return;
  float di = dinv[node];
  ushort2 v = ((const ushort2*)(xw + (size_t)node * HD))[lane];
  float ax = di * di * bf2f(v.x), ay = di * di * bf2f(v.y);
  u32 i = off[node], end = i + cnt[node];
  for (; i + 4 <= end; i += 4) {
    int s0 = (int)nbr[i],     s1 = (int)nbr[i + 1];
    int s2 = (int)nbr[i + 2], s3 = (int)nbr[i + 3];
    float w0 = di * dinv[s0], w1 = di * dinv[s1];
    float w2 = di * dinv[s2], w3 = di * dinv[s3];
    ushort2 u0 = ((const ushort2*)(xw + (size_t)s0 * HD))[lane];
    ushort2 u1 = ((const ushort2*)(xw + (size_t)s1 * HD))[lane];
    ushort2 u2 = ((const ushort2*)(xw + (size_t)s2 * HD))[lane];
    ushort2 u3 = ((const ushort2*)(xw + (size_t)s3 * HD))[lane];
    ax = fmaf(w0, bf2f(u0.x), ax); ay = fmaf(w0, bf2f(u0.y), ay);
    ax = fmaf(w1, bf2f(u1.x), ax); ay = fmaf(w1, bf2f(u1.y), ay);
    ax = fmaf(w2, bf2f(u2.x), ax); ay = fmaf(w2, bf2f(u2.y), ay);
    ax = fmaf(w3, bf2f(u3.x), ax); ay = fmaf(w3, bf2f(u3.y), ay);
  }
  for (; i < end; ++i) {
    int s0 = (int)nbr[i];
    float w0 = di * dinv[s0];
    ushort2 u0 = ((const ushort2*)(xw + (size_t)s0 * HD))[lane];
    ax = fmaf(w0, bf2f(u0.x), ax);
    ay = fmaf(w0, bf2f(u0.y), ay);
  }
  float2 b = ((const float2*)bias)[lane];
  ax += b.x; ay += b.y;
  if (WF32) ((float2*)(outf + (size_t)node * HD))[lane] = make_float2(ax, ay);
  if (WBF) {
    ushort2 ob; ob.x = f2bf(ax); ob.y = f2bf(ay);
    ((ushort2*)(outb + (size_t)node * HD))[lane] = ob;
  }
}

// ---------------------------------------------------------------------------
// Fused edge scores + scatter-softmax + aggregate + residual (one wave/node).
// Fast path (degree <= 64): per-lane register scores. Fallback: 3-pass global.
// ---------------------------------------------------------------------------
__global__ void attn_fused_k(const u32* __restrict__ off, const u32* __restrict__ cnt,
                             const u32* __restrict__ adj,
                             const u16* __restrict__ ti, int TS,
                             const u16* __restrict__ gi, int GS,
                             const u16* __restrict__ vmat, int VS,
                             const u16* __restrict__ xb,
                             float* __restrict__ scores,
                             u16* __restrict__ xf, int n) {
  int node = (blockIdx.x * blockDim.x + threadIdx.x) >> 6;
  int lane = threadIdx.x & 63;
  if (node >= n) return;
  u32 o = off[node], c = cnt[node];
  u32 end = o + c;
  float acc[6] = {0.f, 0.f, 0.f, 0.f, 0.f, 0.f};
  const float sc = 0.05103103630798288f;   // 1/sqrt(384)
  if (c > 0) {
    const u16* tp = ti + (size_t)node * TS;
    float tf[6];
#pragma unroll
    for (int q = 0; q < 3; ++q) {
      ushort2 tv = *(const ushort2*)(tp + q * 128 + lane * 2);
      tf[q * 2] = bf2f(tv.x);
      tf[q * 2 + 1] = bf2f(tv.y);
    }
    if (c <= 64) {
      float sreg = -1e30f;
      u32 i = o;
      for (; i + 2 <= end; i += 2) {
        int d0 = (int)adj[i], d1 = (int)adj[i + 1];
        const u16* g0 = gi + (size_t)d0 * GS;
        const u16* g1 = gi + (size_t)d1 * GS;
        float dot0 = 0.f, dot1 = 0.f;
#pragma unroll
        for (int q = 0; q < 3; ++q) {
          ushort2 a = *(const ushort2*)(g0 + q * 128 + lane * 2);
          ushort2 b = *(const ushort2*)(g1 + q * 128 + lane * 2);
          dot0 = fmaf(tf[q * 2], bf2f(a.x), dot0);
          dot0 = fmaf(tf[q * 2 + 1], bf2f(a.y), dot0);
          dot1 = fmaf(tf[q * 2], bf2f(b.x), dot1);
          dot1 = fmaf(tf[q * 2 + 1], bf2f(b.y), dot1);
        }
#pragma unroll
        for (int s2 = 32; s2 >= 1; s2 >>= 1) {
          dot0 += __shfl_xor(dot0, s2);
          dot1 += __shfl_xor(dot1, s2);
        }
        int idx = (int)(i - o);
        if (lane == idx) sreg = dot0 * sc;
        if (lane == idx + 1) sreg = dot1 * sc;
      }
      if (i < end) {
        int d0 = (int)adj[i];
        const u16* g0 = gi + (size_t)d0 * GS;
        float dot0 = 0.f;
#pragma unroll
        for (int q = 0; q < 3; ++q) {
          ushort2 a = *(const ushort2*)(g0 + q * 128 + lane * 2);
          dot0 = fmaf(tf[q * 2], bf2f(a.x), dot0);
          dot0 = fmaf(tf[q * 2 + 1], bf2f(a.y), dot0);
        }
#pragma unroll
        for (int s2 = 32; s2 >= 1; s2 >>= 1) dot0 += __shfl_xor(dot0, s2);
        if (lane == (int)(i - o)) sreg = dot0 * sc;
      }
      float mx = sreg;
#pragma unroll
      for (int s2 = 32; s2 >= 1; s2 >>= 1) mx = fmaxf(mx, __shfl_xor(mx, s2));
      float ew = (lane < (int)c) ? expf(sreg - mx) : 0.f;
      float den = ew;
#pragma unroll
      for (int s2 = 32; s2 >= 1; s2 >>= 1) den += __shfl_xor(den, s2);
      float wreg = ew / den;
      i = o;
      for (; i + 2 <= end; i += 2) {
        int d0 = (int)adj[i], d1 = (int)adj[i + 1];
        int idx = (int)(i - o);
        float w0 = __shfl(wreg, idx);
        float w1 = __shfl(wreg, idx + 1);
        const u16* v0 = vmat + (size_t)d0 * VS;
        const u16* v1 = vmat + (size_t)d1 * VS;
#pragma unroll
        for (int q = 0; q < 3; ++q) {
          ushort2 a = *(const ushort2*)(v0 + q * 128 + lane * 2);
          ushort2 b = *(const ushort2*)(v1 + q * 128 + lane * 2);
          acc[q * 2]     = fmaf(w0, bf2f(a.x), acc[q * 2]);
          acc[q * 2 + 1] = fmaf(w0, bf2f(a.y), acc[q * 2 + 1]);
          acc[q * 2]     = fmaf(w1, bf2f(b.x), acc[q * 2]);
          acc[q * 2 + 1] = fmaf(w1, bf2f(b.y), acc[q * 2 + 1]);
        }
      }
      if (i < end) {
        int d0 = (int)adj[i];
        float w0 = __shfl(wreg, (int)(i - o));
        const u16* v0 = vmat + (size_t)d0 * VS;
#pragma unroll
        for (int q = 0; q < 3; ++q) {
          ushort2 a = *(const ushort2*)(v0 + q * 128 + lane * 2);
          acc[q * 2]     = fmaf(w0, bf2f(a.x), acc[q * 2]);
          acc[q * 2 + 1] = fmaf(w0, bf2f(a.y), acc[q * 2 + 1]);
        }
      }
    } else {
      float mx = -1e30f;
      u32 i = o;
      for (; i < end; ++i) {
        int d0 = (int)adj[i];
        const u16* g0 = gi + (size_t)d0 * GS;
        float dot0 = 0.f;
#pragma unroll
        for (int q = 0; q < 3; ++q) {
          ushort2 a = *(const ushort2*)(g0 + q * 128 + lane * 2);
          dot0 = fmaf(tf[q * 2], bf2f(a.x), dot0);
          dot0 = fmaf(tf[q * 2 + 1], bf2f(a.y), dot0);
        }
#pragma unroll
        for (int s2 = 32; s2 >= 1; s2 >>= 1) dot0 += __shfl_xor(dot0, s2);
        dot0 *= sc;
        if (lane == 0) scores[i] = dot0;
        mx = fmaxf(mx, dot0);
      }
      float den = 0.f;
      for (u32 k = o + lane; k < end; k += 64) den += expf(scores[k] - mx);
#pragma unroll
      for (int s2 = 32; s2 >= 1; s2 >>= 1) den += __shfl_xor(den, s2);
      float invden = 1.0f / den;
      for (i = o; i < end; ++i) {
        int d0 = (int)adj[i];
        float w0 = expf(scores[i] - mx) * invden;
        const u16* v0 = vmat + (size_t)d0 * VS;
#pragma unroll
        for (int q = 0; q < 3; ++q) {
          ushort2 a = *(const ushort2*)(v0 + q * 128 + lane * 2);
          acc[q * 2]     = fmaf(w0, bf2f(a.x), acc[q * 2]);
          acc[q * 2 + 1] = fmaf(w0, bf2f(a.y), acc[q * 2 + 1]);
        }
      }
    }
  }
  const u16* xp = xb + (size_t)node * FIN;
  u16* op = xf + (size_t)node * FIN;
#pragma unroll
  for (int q = 0; q < 3; ++q) {
    ushort2 xv = *(const ushort2*)(xp + q * 128 + lane * 2);
    ushort2 ov;
    ov.x = f2bf(acc[q * 2] + bf2f(xv.x));
    ov.y = f2bf(acc[q * 2 + 1] + bf2f(xv.y));
    *(ushort2*)(op + q * 128 + lane * 2) = ov;
  }
}

// ---------------------------------------------------------------------------
// MFMA bf16 GEMM (2-phase 128x128), 1-D grid + XCD swizzle (T1).
// ALL epilogues use transposed fragments (mfma(b,a) -> C^T): per frag,
//   row = row0+wr*64+jr*16+(lane&15), col = col0+wc*64+mc*16+(lane>>4)*4+reg.
// -> 4 consecutive cols per lane/frag: float4 bias loads, ushort4/float4
//    stores (4x fewer store instrs than scalar r-loops).  [r15-verified map]
// EPI 0/1/2: none / +bias / relu(+bias); split-bias at bsplit (16-aligned).
// EPI 4 (left): transposed fold (r in regs) + bf16 slice-stream (r15).
// EPI 6 (tv+gcn1 merged, Nc=896): col<768 -> Cp (stride 768); else Cbf2.
// ---------------------------------------------------------------------------
template <int EPI, int OUTBF>
__global__ __launch_bounds__(256)
void mgemm_k(const u16* __restrict__ Abf, int As, const u16* __restrict__ WT,
             const float* __restrict__ bias, const float* __restrict__ bias_b, int bsplit,
             void* __restrict__ Cp, u16* __restrict__ Cbf2,
             float* __restrict__ tmp, int M, int K, int Nc, int ncx) {
  __shared__ u16 Albuf[2][128 * 32];
  __shared__ u16 Blbuf[2][128 * 32];
  const int t = threadIdx.x;
  const int lane = t & 63;
  const int wave = t >> 6;
  const int wr = wave >> 1, wc = wave & 1;
  const int wgid = xcd_wgid();
  const int ctile = wgid % ncx;
  const int row0 = (wgid / ncx) * 128;
  const int col0 = ctile * 128;
  const int sr = t >> 2;
  const int sk = (t & 3) * 8;
  const int nt = K >> 5;

  f32x4 acc[4][4] = {};

  auto stage = [&](int buf, int k0) {
#pragma unroll
    for (int h = 0; h < 2; ++h) {
      int ar = row0 + h * 64 + sr;
      if (ar >= M) ar = M - 1;
      GLOAD16(Abf + (size_t)ar * As + k0 + sk, &Albuf[buf][h * 2048 + wave * 512]);
    }
#pragma unroll
    for (int h = 0; h < 2; ++h) {
      int bc = col0 + h * 64 + sr;
      if (bc >= Nc) bc = Nc - 1;
      GLOAD16(WT + (size_t)bc * K + k0 + sk, &Blbuf[buf][h * 2048 + wave * 512]);
    }
  };

  stage(0, 0);
  int buf = 0;
  for (int tk = 0; tk < nt; ++tk) {
    __syncthreads();
    if (tk + 1 < nt) stage(buf ^ 1, (tk + 1) << 5);
    const u16* Al = Albuf[buf];
    const u16* Bl = Blbuf[buf];
    s16x8 a[4], b[4];
#pragma unroll
    for (int m = 0; m < 4; ++m)
      a[m] = *(const s16x8*)(Al + (wr * 64 + m * 16 + (lane & 15)) * 32 + (lane >> 4) * 8);
#pragma unroll
    for (int j = 0; j < 4; ++j)
      b[j] = *(const s16x8*)(Bl + (wc * 64 + j * 16 + (lane & 15)) * 32 + (lane >> 4) * 8);
    // transposed everywhere: acc[mc][jr] = C^T frag (cols mc*16.., rows jr*16..)
#pragma unroll
    for (int mc = 0; mc < 4; ++mc)
#pragma unroll
      for (int jr = 0; jr < 4; ++jr)
        acc[mc][jr] = __builtin_amdgcn_mfma_f32_16x16x32_bf16(b[mc], a[jr], acc[mc][jr], 0, 0, 0);
    buf ^= 1;
  }

  if constexpr (EPI <= 2) {
#pragma unroll
    for (int jr = 0; jr < 4; ++jr) {
      int row = row0 + wr * 64 + jr * 16 + (lane & 15);
      if (row >= M) continue;
#pragma unroll
      for (int mc = 0; mc < 4; ++mc) {
        int colb = col0 + wc * 64 + mc * 16 + (lane >> 4) * 4;
        if (colb >= Nc) continue;
        float4 bv = make_float4(0.f, 0.f, 0.f, 0.f);
        if (EPI >= 1) {
          const float* bp = (colb < bsplit) ? bias + colb : bias_b + (colb - bsplit);
          bv = *(const float4*)bp;
        }
        float v0 = acc[mc][jr][0] + bv.x;
        float v1 = acc[mc][jr][1] + bv.y;
        float v2 = acc[mc][jr][2] + bv.z;
        float v3 = acc[mc][jr][3] + bv.w;
        if (EPI == 2) {
          v0 = fmaxf(v0, 0.f); v1 = fmaxf(v1, 0.f);
          v2 = fmaxf(v2, 0.f); v3 = fmaxf(v3, 0.f);
        }
        if (OUTBF) {
          ushort4 ov;
          ov.x = f2bf(v0); ov.y = f2bf(v1); ov.z = f2bf(v2); ov.w = f2bf(v3);
          *(ushort4*)((u16*)Cp + (size_t)row * Nc + colb) = ov;
        } else {
          *(float4*)((float*)Cp + (size_t)row * Nc + colb) = make_float4(v0, v1, v2, v3);
        }
      }
    }
  } else if constexpr (EPI == 6) {
#pragma unroll
    for (int jr = 0; jr < 4; ++jr) {
      int row = row0 + wr * 64 + jr * 16 + (lane & 15);
      if (row >= M) continue;
#pragma unroll
      for (int mc = 0; mc < 4; ++mc) {
        int colb = col0 + wc * 64 + mc * 16 + (lane >> 4) * 4;
        if (colb < 2 * FIN) {
          const float* bp = (colb < bsplit) ? bias + colb : bias_b + (colb - bsplit);
          float4 bv = *(const float4*)bp;
          ushort4 ov;
          ov.x = f2bf(acc[mc][jr][0] + bv.x);
          ov.y = f2bf(acc[mc][jr][1] + bv.y);
          ov.z = f2bf(acc[mc][jr][2] + bv.z);
          ov.w = f2bf(acc[mc][jr][3] + bv.w);
          *(ushort4*)((u16*)Cp + (size_t)row * (2 * FIN) + colb) = ov;
        } else {
          int c2 = colb - 2 * FIN;
          ushort4 ov;
          ov.x = f2bf(acc[mc][jr][0]);
          ov.y = f2bf(acc[mc][jr][1]);
          ov.z = f2bf(acc[mc][jr][2]);
          ov.w = f2bf(acc[mc][jr][3]);
          *(ushort4*)(Cbf2 + (size_t)row * HD + c2) = ov;
        }
      }
    }
  } else {  // EPI == 4: transposed fold + bf16 slice-stream (r15-verified)
    u16* slice = (u16*)Cp + (size_t)ctile * M * 8;
    float4 b4[4];
#pragma unroll
    for (int mc = 0; mc < 4; ++mc)
      b4[mc] = *(const float4*)&bias[col0 + wc * 64 + mc * 16 + (lane >> 4) * 4];
#pragma unroll
    for (int jr = 0; jr < 4; ++jr) {
      int row = row0 + wr * 64 + jr * 16 + (lane & 15);
      int rc = row < M ? row : M - 1;
      float4 tv = *(const float4*)&tmp[(size_t)rc * RD + (lane >> 4) * 4];
      ushort4 outp;
#pragma unroll
      for (int mc = 0; mc < 4; ++mc) {
        float s = (acc[mc][jr][0] + b4[mc].x) * tv.x +
                  (acc[mc][jr][1] + b4[mc].y) * tv.y +
                  (acc[mc][jr][2] + b4[mc].z) * tv.z +
                  (acc[mc][jr][3] + b4[mc].w) * tv.w;
        s += __shfl_xor(s, 16);
        s += __shfl_xor(s, 32);
        ((u16*)&outp)[mc] = f2bf(s);
      }
      if (lane < 16 && row < M)
        *(ushort4*)(slice + (size_t)row * 8 + wc * 4) = outp;
    }
  }
}

// ---------------------------------------------------------------------------
// pt gather: pt[row][ct*8+pl] = bf2f(ptP[ct][row][pl]); fp32 + bf16 outputs.
// ---------------------------------------------------------------------------
__global__ void ptgather_k(const u16* __restrict__ ptP, float* __restrict__ pt,
                           u16* __restrict__ ptb, int n) {
  int g = blockIdx.x * 256 + threadIdx.x;
  if (g >= n * 16) return;
  int row = g >> 4, ct = g & 15;
  const u16* sp = ptP + ((size_t)ct * n + (size_t)row) * 8;
  ushort4 a = ((const ushort4*)sp)[0];
  ushort4 b = ((const ushort4*)sp)[1];
  float* dp = pt + (size_t)row * PD + ct * 8;
  ((float4*)dp)[0] = make_float4(bf2f(a.x), bf2f(a.y), bf2f(a.z), bf2f(a.w));
  ((float4*)dp)[1] = make_float4(bf2f(b.x), bf2f(b.y), bf2f(b.z), bf2f(b.w));
  u16* db = ptb + (size_t)row * PD + ct * 8;
  ((ushort4*)db)[0] = a;
  ((ushort4*)db)[1] = b;
}

// ---------------------------------------------------------------------------
// Y-GEMM, 8-phase 256x256/BK=64/8-wave (T3+T4+T2+T5), race-verified (r8),
// 1-D grid + XCD swizzle (ncx=12 col-groups).
// ---------------------------------------------------------------------------
#define VM6  asm volatile("s_waitcnt vmcnt(6)" ::: "memory")
#define VM0  asm volatile("s_waitcnt vmcnt(0)" ::: "memory")
#define VMNOP
#define BARR asm volatile("s_barrier" ::: "memory")

__global__ __launch_bounds__(512)
void ygemm8_k(const u16* __restrict__ X, const u16* __restrict__ QT,
              const u16* __restrict__ Ar, float* __restrict__ tmpP, int M) {
  __shared__ u16 Al[2][16384];
  __shared__ u16 Bl[2][16384];
  const int t = threadIdx.x;
  const int lane = t & 63;
  const int wave = t >> 6;
  const int wr = wave >> 2;
  const int wcn = wave & 3;
  const int wgid = xcd_wgid();
  const int ctile = wgid % 12;
  const int row0 = (wgid / 12) * 256;
  const int col0 = ctile * 256;

  const int srow = t >> 3;
  const int sgk  = (((t & 7) ^ (srow & 7)) << 3);
  const int sdst = t * 8;

  const int pc0 = (((lane >> 4)) ^ (lane & 7)) << 3;
  const int pc1 = ((((lane >> 4) + 4)) ^ (lane & 7)) << 3;
  const int arow = (wr * 128 + (lane & 15)) << 6;
  const int brow = (wcn * 64 + (lane & 15)) << 6;

  f32x4 acc[8][4] = {};
  s16x8 a[4][2], b[4][2];

#define STGA8(bf, h, kt) do {                                                  \
    int r0_ = row0 + (h) * 128 + srow;                                         \
    int r1_ = r0_ + 64;                                                        \
    if (r0_ >= M) r0_ = M - 1;                                                 \
    if (r1_ >= M) r1_ = M - 1;                                                 \
    GLOAD16(X + (size_t)r0_ * 384 + (kt) * 64 + sgk, &Al[bf][(h) * 8192 + sdst]);        \
    GLOAD16(X + (size_t)r1_ * 384 + (kt) * 64 + sgk, &Al[bf][(h) * 8192 + 4096 + sdst]); \
  } while (0)

#define STGB8(bf, h, kt) do {                                                  \
    int c0_ = col0 + (h) * 128 + srow;                                         \
    GLOAD16(QT + (size_t)c0_ * 384 + (kt) * 64 + sgk, &Bl[bf][(h) * 8192 + sdst]);       \
    GLOAD16(QT + (size_t)(c0_ + 64) * 384 + (kt) * 64 + sgk,                   \
            &Bl[bf][(h) * 8192 + 4096 + sdst]);                                \
  } while (0)

#define LDA8(bf, mh) do {                                                      \
    _Pragma("unroll") for (int m2_ = 0; m2_ < 4; ++m2_) {                      \
      const u16* p_ = &Al[bf][arow + ((mh) * 4 + m2_) * 1024];                 \
      a[m2_][0] = *(const s16x8*)(p_ + pc0);                                   \
      a[m2_][1] = *(const s16x8*)(p_ + pc1);                                   \
    }                                                                          \
  } while (0)

#define LDB8(bf, jh) do {                                                      \
    _Pragma("unroll") for (int j2_ = 0; j2_ < 2; ++j2_) {                      \
      const u16* p_ = &Bl[bf][brow + ((jh) * 2 + j2_) * 1024];                 \
      b[(jh) * 2 + j2_][0] = *(const s16x8*)(p_ + pc0);                        \
      b[(jh) * 2 + j2_][1] = *(const s16x8*)(p_ + pc1);                        \
    }                                                                          \
  } while (0)

#define MQ8(mh, jh) do {                                                       \
    __builtin_amdgcn_s_setprio(1);                                             \
    _Pragma("unroll") for (int m2_ = 0; m2_ < 4; ++m2_)                        \
      _Pragma("unroll") for (int j2_ = 0; j2_ < 2; ++j2_)                      \
        _Pragma("unroll") for (int ks_ = 0; ks_ < 2; ++ks_)                    \
          acc[(mh) * 4 + m2_][(jh) * 2 + j2_] =                                \
              __builtin_amdgcn_mfma_f32_16x16x32_bf16(                         \
                  a[m2_][ks_], b[(jh) * 2 + j2_][ks_],                         \
                  acc[(mh) * 4 + m2_][(jh) * 2 + j2_], 0, 0, 0);               \
    __builtin_amdgcn_s_setprio(0);                                             \
  } while (0)

  STGA8(0, 0, 0); STGA8(0, 1, 0); STGB8(0, 0, 0); STGB8(0, 1, 0);
  STGA8(1, 0, 1); STGB8(1, 0, 1); STGB8(1, 1, 1);
  VM6; BARR;

#define ITER8(i, VMP3, VMP7, DOSTG)                                                          \
  /*ph0*/ LDA8(0,0); LDB8(0,0); STGA8(1,1,2*(i)+1);                   BARR; MQ8(0,0); BARR;  \
  /*ph1*/ LDB8(0,1);                                                  BARR; MQ8(0,1); BARR;  \
  /*ph2*/ LDA8(0,1); if (DOSTG) STGB8(0,0,2*(i)+2);                   BARR; MQ8(1,0); BARR;  \
  /*ph3*/ if (DOSTG) { STGB8(0,1,2*(i)+2); STGA8(0,0,2*(i)+2); } VMP3; BARR; MQ8(1,1); BARR; \
  /*ph4*/ LDA8(1,0); LDB8(1,0); if (DOSTG) STGA8(0,1,2*(i)+2);        BARR; MQ8(0,0); BARR;  \
  /*ph5*/ LDB8(1,1);                                                  BARR; MQ8(0,1); BARR;  \
  /*ph6*/ LDA8(1,1); if (DOSTG) STGB8(1,0,2*(i)+3);                   BARR; MQ8(1,0); BARR;  \
  /*ph7*/ if (DOSTG) { STGB8(1,1,2*(i)+3); STGA8(1,0,2*(i)+3); } VMP7; BARR; MQ8(1,1); BARR;

  ITER8(0, VM6, VM6, 1)
  ITER8(1, VM6, VM6, 1)
  ITER8(2, VM0, VMNOP, 0)

  // fold: s[m][rr] = sum_j relu_r[row, h0+j] * acc[m][j][rr]
  const int h0 = (col0 >> 4) + wcn * 4;
  float s[8][4];
#pragma unroll
  for (int m = 0; m < 8; ++m) {
#pragma unroll
    for (int rr = 0; rr < 4; ++rr) {
      int row = row0 + wr * 128 + m * 16 + (lane >> 4) * 4 + rr;
      int rc = row < M ? row : M - 1;
      ushort4 arv = *(const ushort4*)(Ar + (size_t)rc * 384 + h0);
      s[m][rr] = bf2f(arv.x) * acc[m][0][rr] + bf2f(arv.y) * acc[m][1][rr] +
                 bf2f(arv.z) * acc[m][2][rr] + bf2f(arv.w) * acc[m][3][rr];
    }
  }

  __syncthreads();
  float* redA = (float*)&Al[0][0];
  float* redB = redA + 4096;
  const int r16 = lane & 15;
  const int rlb = wr * 128 + (lane >> 4) * 4;
  if (wcn & 1) {
    float* red = (wcn == 1) ? redA : redB;
#pragma unroll
    for (int m = 0; m < 8; ++m)
#pragma unroll
      for (int rr = 0; rr < 4; ++rr)
        red[(rlb + m * 16 + rr) * 16 + r16] = s[m][rr];
  }
  __syncthreads();
  if (!(wcn & 1)) {
    float* red = (wcn == 0) ? redA : redB;
#pragma unroll
    for (int m = 0; m < 8; ++m)
#pragma unroll
      for (int rr = 0; rr < 4; ++rr)
        s[m][rr] += red[(rlb + m * 16 + rr) * 16 + r16];
  }
  __syncthreads();
  if (wcn == 2) {
#pragma unroll
    for (int m = 0; m < 8; ++m)
#pragma unroll
      for (int rr = 0; rr < 4; ++rr)
        redA[(rlb + m * 16 + rr) * 16 + r16] = s[m][rr];
  }
  __syncthreads();
  if (wcn == 0) {
    float* slice = tmpP + (size_t)ctile * M * RD;
#pragma unroll
    for (int m = 0; m < 8; ++m)
#pragma unroll
      for (int rr = 0; rr < 4; ++rr) {
        int row = row0 + rlb + m * 16 + rr;
        if (row < M)
          slice[(size_t)row * RD + r16] =
              s[m][rr] + redA[(rlb + m * 16 + rr) * 16 + r16];
      }
  }
#undef STGA8
#undef STGB8
#undef LDA8
#undef LDB8
#undef MQ8
#undef ITER8
}

// ---------------------------------------------------------------------------
// combine: temp[i] = sum_{s=0..12} tmpP[s][i]   (slice 12 = x@Br bias term)
// ---------------------------------------------------------------------------
__global__ void combine_k(const float* __restrict__ tmpP, float* __restrict__ temp,
                          size_t sl, int tot4) {
  int i = blockIdx.x * 256 + threadIdx.x;
  if (i >= tot4) return;
  float4 s = ((const float4*)(tmpP + 12 * sl))[i];
#pragma unroll
  for (int c = 0; c < 12; ++c) {
    float4 p = ((const float4*)(tmpP + (size_t)c * sl))[i];
    s.x += p.x; s.y += p.y; s.z += p.z; s.w += p.w;
  }
  ((float4*)temp)[i] = s;
}

// ---------------------------------------------------------------------------
// Final: in-place row-normalize p_t, p_g; alignment = dot of normalized rows.
// ---------------------------------------------------------------------------
__global__ void final_k(float* __restrict__ out, int n) {
  int node = (blockIdx.x * blockDim.x + threadIdx.x) >> 6;
  int lane = threadIdx.x & 63;
  if (node >= n) return;
  float* pt = out + n + (size_t)node * PD;
  float* pg = out + n + (size_t)n * PD + (size_t)node * PD;
  float2 t = ((float2*)pt)[lane];
  float2 g = ((float2*)pg)[lane];
  float tt = t.x * t.x + t.y * t.y;
  float gg = g.x * g.x + g.y * g.y;
  float tg = t.x * g.x + t.y * g.y;
#pragma unroll
  for (int s = 32; s >= 1; s >>= 1) {
    tt += __shfl_xor(tt, s);
    gg += __shfl_xor(gg, s);
    tg += __shfl_xor(tg, s);
  }
  float invt = 1.0f / fmaxf(sqrtf(tt), 1e-12f);
  float invg = 1.0f / fmaxf(sqrtf(gg), 1e-12f);
  ((float2*)pt)[lane] = make_float2(t.x * invt, t.y * invt);
  ((float2*)pg)[lane] = make_float2(g.x * invg, g.y * invg);
  if (lane == 0) out[node] = tg * invt * invg;
}

// ---------------------------------------------------------------------------
struct MgArgs {
  const u16* A; int As; const u16* WT;
  const float* b; const float* b2; int bsplit;
  void* C; u16* C2; float* tmp;
  int M, K, Nc;
};
template <int EPI, int OUTBF>
static void mg(const MgArgs& a, hipStream_t s) {
  int ncx = (a.Nc + 127) / 128, nry = (a.M + 127) / 128;
  mgemm_k<EPI, OUTBF><<<dim3(ncx * nry), 256, 0, s>>>(
      a.A, a.As, a.WT, a.b, a.b2, a.bsplit, a.C, a.C2, a.tmp,
      a.M, a.K, a.Nc, ncx);
}

extern "C" void kernel_launch(void* const* d_in, const int* in_sizes, int n_in,
                              void* d_out, int out_size, void* d_ws, size_t ws_size,
                              hipStream_t stream) {
  const float* x      = (const float*)d_in[0];
  const int*   ei     = (const int*)d_in[1];
  const float* W_gcn1 = (const float*)d_in[2];
  const float* b_gcn1 = (const float*)d_in[3];
  const float* W_ti   = (const float*)d_in[4];
  const float* b_ti   = (const float*)d_in[5];
  const float* W_gi   = (const float*)d_in[6];
  const float* b_gi   = (const float*)d_in[7];
  const float* W_v    = (const float*)d_in[8];
  const float* b_v    = (const float*)d_in[9];
  const float* Wl1    = (const float*)d_in[10];
  const float* bl1    = (const float*)d_in[11];
  const float* Wl2    = (const float*)d_in[12];
  const float* bl2    = (const float*)d_in[13];
  const float* Wr1    = (const float*)d_in[14];
  const float* br1    = (const float*)d_in[15];
  const float* Wr2    = (const float*)d_in[16];
  const float* br2    = (const float*)d_in[17];
  const float* W_gcn2 = (const float*)d_in[18];
  const float* b_gcn2 = (const float*)d_in[19];
  const float* W_gp   = (const float*)d_in[20];
  const float* b_gp   = (const float*)d_in[21];

  const int n = in_sizes[0] / FIN;   // 50000
  const int E = in_sizes[1] / 2;     // 500000
  const int* src = ei;
  const int* dst = ei + E;

  // -------- workspace carve (tmpP/ptP overlay gibf+xfbf) --------
  char* wsp = (char*)d_ws;
  auto carve = [&](size_t bytes) -> void* {
    void* p = (void*)wsp;
    wsp += (bytes + 255) & ~(size_t)255;
    return p;
  };
  u32* cnt      = (u32*)carve((size_t)2 * n * 4);   // [src | dst]
  u32* off      = (u32*)carve((size_t)2 * n * 4);
  u32* cur      = (u32*)carve((size_t)2 * n * 4);
  u32* bsum     = (u32*)carve(512);
  u32* adj      = (u32*)carve((size_t)2 * E * 4);   // [src-CSR dsts | dst-CSR srcs]
  float* dinv   = (float*)carve((size_t)n * 4);
  float* scores = (float*)carve((size_t)E * 4);
  float* temp   = (float*)carve((size_t)n * RD * 4);

  u16* xbf    = (u16*)carve((size_t)n * FIN * 2);       // x bf16 (pristine)
  u16* tvbf   = (u16*)carve((size_t)n * 2 * FIN * 2);   // [t_info | v]; later lrbf
  u16* bufHbf = (u16*)carve((size_t)n * HD * 2);        // xw (both GCNs)
  u16* gembf  = (u16*)carve((size_t)n * HD * 2);
  u16* ptbf   = (u16*)carve((size_t)n * PD * 2);
  u16* g2bf   = (u16*)carve((size_t)n * HD * 2);

  // gibf and xfbf adjacent; tmpP (13 x n*16 fp32 = 41.6 MB) overlays them;
  // ptP (16 x n*8 bf16 = 12.8 MB) reuses the same region after combine.
  u16* gibf   = (u16*)carve((size_t)n * FIN * 2);       // g_info
  u16* xfbf   = (u16*)carve((size_t)n * FIN * 2);       // x_fused
  size_t tmpP_bytes = (size_t)13 * n * RD * 4;
  size_t overlay    = (size_t)2 * n * FIN * 2;
  carve(tmpP_bytes > overlay ? tmpP_bytes - overlay : 0);
  float* tmpP = (float*)gibf;
  u16* ptP    = (u16*)gibf;   // reused after combine_k (slices dead)

  u16* WtvT   = (u16*)carve((size_t)2 * FIN * FIN * 2); // [768][384]
  u16* WgcnT  = (u16*)carve((size_t)HD * FIN * 2);      // [128][384], contiguous
  u16* WgiT   = (u16*)carve((size_t)FIN * HD * 2);      // [384][128]
  u16* WlrT   = (u16*)carve((size_t)FIN * FIN * 2);     // [384][384]
  u16* Wl2T   = (u16*)carve((size_t)2048 * 192 * 2);
  u16* QT     = (u16*)carve((size_t)3072 * FIN * 2);    // permuted Wr2
  u16* BrT    = (u16*)carve((size_t)RD * FIN * 2);      // br2 reshaped [16][384]
  u16* Wgcn2T = (u16*)carve((size_t)HD * PD * 2);
  u16* WgpT   = (u16*)carve((size_t)PD * PD * 2);

  u16* lrbf = tvbf;   // [relu_l | relu_r], stride 384; tv dead after attn

  float* out    = (float*)d_out;
  float* pt_raw = out + n;
  float* pg_raw = out + n + (size_t)n * PD;
  float* g2     = out + n + (size_t)2 * n * PD;

  // 0) all converts in one launch
  CvtDesc dsc;
  int nent = 0, blk = 0;
  auto addent = [&](const float* s, u16* d, int K, int N, int mode) {
    dsc.e[nent] = {s, d, K, N, mode, blk};
    blk += (K * N + 255) / 256;
    ++nent;
  };
  addent(x,      xbf,    n * FIN, 1, 1);
  addent(W_ti,   WtvT,   FIN, FIN, 0);
  addent(W_v,    WtvT + (size_t)FIN * FIN, FIN, FIN, 0);
  addent(W_gcn1, WgcnT,  FIN, HD,  0);
  addent(W_gi,   WgiT,   HD,  FIN, 0);
  addent(Wl1,    WlrT,   FIN, 192, 0);
  addent(Wr1,    WlrT + (size_t)192 * FIN, FIN, 192, 0);
  addent(Wl2,    Wl2T,   192, 2048, 0);
  addent(Wr2,    QT,     FIN, 3072, 2);
  addent(br2,    BrT,    RD * FIN, 1, 1);
  addent(W_gcn2, Wgcn2T, PD, HD, 0);
  addent(W_gp,   WgpT,   PD, PD, 0);
  dsc.n = nent;
  cvt_all_k<<<blk, 256, 0, stream>>>(dsc);

  // 1) CSR build + degrees (one concatenated scan over 2n)
  hipMemsetAsync(cnt, 0, (size_t)2 * n * 4, stream);
  hist_k<<<(E + 255) / 256, 256, 0, stream>>>(src, dst, cnt, n, E);
  int n2 = 2 * n;
  int nb = (n2 + 1023) / 1024;
  scanA_k<<<nb, 1024, 0, stream>>>(cnt, off, bsum, n2);
  scanB_k<<<1, 64, 0, stream>>>(bsum, nb);
  scanC_k<<<nb, 1024, 0, stream>>>(off, cur, bsum, n2);
  fill_k<<<(E + 255) / 256, 256, 0, stream>>>(src, dst, cur, adj, n, E);
  dinv_k<<<(n + 255) / 256, 256, 0, stream>>>(cnt + n, dinv, n);

  MgArgs a{};

  // 2+3a) merged GEMM: [t_info | v | xw_gcn1], Nc=896 (EPI 6)
  a = {xbf, FIN, WtvT, b_ti, b_v, FIN, tvbf, bufHbf, nullptr, n, FIN, 896};
  mg<6, 1>(a, stream);
  gcn_agg_k<0, 1><<<(n + 3) / 4, 256, 0, stream>>>(bufHbf, dinv, off + n, cnt + n, adj,
                                                   b_gcn1, nullptr, gembf, n);

  // 3b) g_info GEMM; fused scores+softmax+aggregate+residual
  a = {gembf, HD, WgiT, b_gi, nullptr, 1 << 30, gibf, nullptr, nullptr, n, HD, FIN};
  mg<1, 1>(a, stream);
  attn_fused_k<<<(n + 3) / 4, 256, 0, stream>>>(off, cnt, adj, tvbf, 2 * FIN, gibf, FIN,
                                                tvbf + FIN, 2 * FIN, xbf, scores, xfbf, n);

  // 4) Generators: [relu_l | relu_r] in one GEMM (overwrites tv buffer)
  a = {xfbf, FIN, WlrT, bl1, br1, 192, lrbf, nullptr, nullptr, n, FIN, FIN};
  mg<2, 1>(a, stream);

  // right path: x@Br into tmpP slice 12, 8-phase Y-GEMM partials into 0..11,
  // combine -> temp. (gibf/xfbf dead from here.)
  a = {xbf, FIN, BrT, nullptr, nullptr, 1 << 30, tmpP + (size_t)12 * n * RD, nullptr,
       nullptr, n, FIN, RD};
  mg<0, 0>(a, stream);
  ygemm8_k<<<dim3(12 * ((n + 255) / 256)), 512, 0, stream>>>(xbf, QT, lrbf + 192,
                                                             tmpP, n);
  combine_k<<<(n * RD / 4 + 255) / 256, 256, 0, stream>>>(tmpP, temp, (size_t)n * RD,
                                                          n * RD / 4);

  // left path fused (transposed-fragment fold): ptP[16][n][8], then gather
  a = {lrbf, FIN, Wl2T, bl2, nullptr, 1 << 30, ptP, nullptr, temp, n, 192, PD * RD};
  mg<4, 0>(a, stream);
  ptgather_k<<<(n * 16 + 255) / 256, 256, 0, stream>>>(ptP, pt_raw, ptbf, n);

  // 5) GCN2 + projection
  a = {ptbf, PD, Wgcn2T, nullptr, nullptr, 1 << 30, bufHbf, nullptr, nullptr, n, PD, HD};
  mg<0, 1>(a, stream);
  gcn_agg_k<1, 1><<<(n + 3) / 4, 256, 0, stream>>>(bufHbf, dinv, off + n, cnt + n, adj,
                                                   b_gcn2, g2, g2bf, n);
  a = {g2bf, HD, WgpT, b_gp, nullptr, 1 << 30, pg_raw, nullptr, nullptr, n, HD, PD};
  mg<1, 0>(a, stream);

  // 6) normalize + alignment
  final_k<<<(n + 3) / 4, 256, 0, stream>>>(out, n);
}

// Round 17
// 784.753 us; speedup vs baseline: 1.1945x; 1.0062x over previous
//
#include <hip/hip_runtime.h>

typedef unsigned int u32;
typedef unsigned short u16;
typedef short s16x8 __attribute__((ext_vector_type(8)));
typedef u16 u16x8 __attribute__((ext_vector_type(8)));
typedef float f32x4 __attribute__((ext_vector_type(4)));

#define FIN 384
#define HD  128
#define PD  128
#define RD  16

#define GLOAD16(g, l)                                                          \
  __builtin_amdgcn_global_load_lds(                                            \
      (const __attribute__((address_space(1))) void*)(g),                      \
      (__attribute__((address_space(3))) void*)(l), 16, 0, 0)

__device__ __forceinline__ u16 f2bf(float f) {
  u32 u = __float_as_uint(f);
  u32 r = (u + 0x7fffu + ((u >> 16) & 1u)) >> 16;   // RNE
  return (u16)r;
}
__device__ __forceinline__ float bf2f(u16 h) {
  return __uint_as_float(((u32)h) << 16);
}

// XCD-aware bijective block remap (m204): assumes dispatch XCD ~ blockIdx%8.
__device__ __forceinline__ int xcd_wgid() {
  int nwg = gridDim.x, orig = blockIdx.x;
  int q = nwg >> 3, r = nwg & 7, xcd = orig & 7, idx = orig >> 3;
  return (xcd < r ? xcd * (q + 1) : r * (q + 1) + (xcd - r) * q) + idx;
}

// ---------------------------------------------------------------------------
// One descriptor-driven convert kernel for all weights + x.
// mode 0: transpose; mode 1: copy; mode 2: Wr2 Q-permute (q=h*16+r).
// ---------------------------------------------------------------------------
struct CvtEnt { const float* s; u16* d; int K, N, mode, blk0; };
struct CvtDesc { CvtEnt e[12]; int n; };

__global__ void cvt_all_k(CvtDesc dsc) {
  int b = blockIdx.x;
  int ei = 0;
  while (ei + 1 < dsc.n && dsc.e[ei + 1].blk0 <= b) ++ei;
  CvtEnt E = dsc.e[ei];
  int i = (b - E.blk0) * 256 + (int)threadIdx.x;
  int tot = E.K * E.N;
  if (i >= tot) return;
  float v;
  if (E.mode == 0) {
    int c = i / E.K, k = i - c * E.K;
    v = E.s[(size_t)k * E.N + c];
  } else if (E.mode == 1) {
    v = E.s[i];
  } else {
    int q = i / 384, f = i - q * 384;
    v = E.s[(size_t)(q >> 4) * 6144 + (q & 15) * 384 + f];
  }
  E.d[i] = f2bf(v);
}

// ---------------------------------------------------------------------------
// Graph preprocessing (concatenated src|dst arrays, one scan over 2n)
// ---------------------------------------------------------------------------
__global__ void hist_k(const int* __restrict__ src, const int* __restrict__ dst,
                       u32* __restrict__ cnt, int n, int E) {
  int i = blockIdx.x * 256 + threadIdx.x;
  if (i < E) {
    atomicAdd(&cnt[src[i]], 1u);
    atomicAdd(&cnt[n + dst[i]], 1u);
  }
}

__global__ __launch_bounds__(1024)
void scanA_k(const u32* __restrict__ cnt, u32* __restrict__ off,
             u32* __restrict__ bsum, int n2) {
  __shared__ u32 sh[1024];
  int i = blockIdx.x * 1024 + (int)threadIdx.x;
  u32 v = (i < n2) ? cnt[i] : 0u;
  sh[threadIdx.x] = v;
  __syncthreads();
  for (int s = 1; s < 1024; s <<= 1) {
    u32 t = (threadIdx.x >= (u32)s) ? sh[threadIdx.x - s] : 0u;
    __syncthreads();
    sh[threadIdx.x] += t;
    __syncthreads();
  }
  if (i < n2) off[i] = sh[threadIdx.x] - v;       // local exclusive
  if (threadIdx.x == 1023) bsum[blockIdx.x] = sh[1023];
}

__global__ void scanB_k(u32* __restrict__ bsum, int nb) {   // 1 wave, chunks of 64
  int l = threadIdx.x;
  u32 carry = 0u;
  for (int base = 0; base < nb; base += 64) {
    u32 v = (base + l < nb) ? bsum[base + l] : 0u;
    for (int s = 1; s < 64; s <<= 1) {
      u32 t = __shfl_up(v, s);
      if (l >= s) v += t;
    }
    if (base + l < nb) bsum[base + l] = v + carry;
    carry += __shfl(v, 63);
  }
}

__global__ __launch_bounds__(1024)
void scanC_k(u32* __restrict__ off, u32* __restrict__ cur,
             const u32* __restrict__ bsum, int n2) {
  int b = blockIdx.x;
  int i = b * 1024 + (int)threadIdx.x;
  if (i >= n2) return;
  u32 add = (b > 0) ? bsum[b - 1] : 0u;
  u32 o = off[i] + add;
  off[i] = o;
  cur[i] = o;
}

__global__ void fill_k(const int* __restrict__ src, const int* __restrict__ dst,
                       u32* __restrict__ cur, u32* __restrict__ adj, int n, int E) {
  int i = blockIdx.x * 256 + threadIdx.x;
  if (i >= E) return;
  int s = src[i], d = dst[i];
  u32 ps = atomicAdd(&cur[s], 1u);
  adj[ps] = (u32)d;
  u32 pd = atomicAdd(&cur[n + d], 1u);
  adj[pd] = (u32)s;
}

__global__ void dinv_k(const u32* __restrict__ cd, float* __restrict__ dinv, int n) {
  int i = blockIdx.x * 256 + threadIdx.x;
  if (i < n) dinv[i] = 1.0f / sqrtf((float)(cd[i] + 1u));
}

// ---------------------------------------------------------------------------
// GCN aggregation, bf16 in, fp32/bf16 out; 4-edge ILP
// ---------------------------------------------------------------------------
template <int WF32, int WBF>
__global__ void gcn_agg_k(const u16* __restrict__ xw, const float* __restrict__ dinv,
                          const u32* __restrict__ off, const u32* __restrict__ cnt,
                          const u32* __restrict__ nbr, const float* __restrict__ bias,
                          float* __restrict__ outf, u16* __restrict__ outb, int n) {
  int node = (blockIdx.x * blockDim.x + threadIdx.x) >> 6;
  int lane = threadIdx.x & 63;
  if (node >= n) return;
  float di = dinv[node];
  ushort2 v = ((const ushort2*)(xw + (size_t)node * HD))[lane];
  float ax = di * di * bf2f(v.x), ay = di * di * bf2f(v.y);
  u32 i = off[node], end = i + cnt[node];
  for (; i + 4 <= end; i += 4) {
    int s0 = (int)nbr[i],     s1 = (int)nbr[i + 1];
    int s2 = (int)nbr[i + 2], s3 = (int)nbr[i + 3];
    float w0 = di * dinv[s0], w1 = di * dinv[s1];
    float w2 = di * dinv[s2], w3 = di * dinv[s3];
    ushort2 u0 = ((const ushort2*)(xw + (size_t)s0 * HD))[lane];
    ushort2 u1 = ((const ushort2*)(xw + (size_t)s1 * HD))[lane];
    ushort2 u2 = ((const ushort2*)(xw + (size_t)s2 * HD))[lane];
    ushort2 u3 = ((const ushort2*)(xw + (size_t)s3 * HD))[lane];
    ax = fmaf(w0, bf2f(u0.x), ax); ay = fmaf(w0, bf2f(u0.y), ay);
    ax = fmaf(w1, bf2f(u1.x), ax); ay = fmaf(w1, bf2f(u1.y), ay);
    ax = fmaf(w2, bf2f(u2.x), ax); ay = fmaf(w2, bf2f(u2.y), ay);
    ax = fmaf(w3, bf2f(u3.x), ax); ay = fmaf(w3, bf2f(u3.y), ay);
  }
  for (; i < end; ++i) {
    int s0 = (int)nbr[i];
    float w0 = di * dinv[s0];
    ushort2 u0 = ((const ushort2*)(xw + (size_t)s0 * HD))[lane];
    ax = fmaf(w0, bf2f(u0.x), ax);
    ay = fmaf(w0, bf2f(u0.y), ay);
  }
  float2 b = ((const float2*)bias)[lane];
  ax += b.x; ay += b.y;
  if (WF32) ((float2*)(outf + (size_t)node * HD))[lane] = make_float2(ax, ay);
  if (WBF) {
    ushort2 ob; ob.x = f2bf(ax); ob.y = f2bf(ay);
    ((ushort2*)(outb + (size_t)node * HD))[lane] = ob;
  }
}

// ---------------------------------------------------------------------------
// Fused attention, SINGLE-PASS online softmax (flash-style, exact):
// per edge gather g AND v together (4 rows in flight per 2-edge iter),
// maintain running (m, den, acc) — all wave-uniform after the dot reduce,
// so no broadcasts, no register-score bookkeeping, no scores buffer,
// no degree<=64 special case.
// ---------------------------------------------------------------------------
__global__ void attn_fused_k(const u32* __restrict__ off, const u32* __restrict__ cnt,
                             const u32* __restrict__ adj,
                             const u16* __restrict__ ti, int TS,
                             const u16* __restrict__ gi, int GS,
                             const u16* __restrict__ vmat, int VS,
                             const u16* __restrict__ xb,
                             u16* __restrict__ xf, int n) {
  int node = (blockIdx.x * blockDim.x + threadIdx.x) >> 6;
  int lane = threadIdx.x & 63;
  if (node >= n) return;
  u32 o = off[node], c = cnt[node];
  u32 end = o + c;
  float acc[6] = {0.f, 0.f, 0.f, 0.f, 0.f, 0.f};
  const float sc = 0.05103103630798288f;   // 1/sqrt(384)
  if (c > 0) {
    const u16* tp = ti + (size_t)node * TS;
    float tf[6];
#pragma unroll
    for (int q = 0; q < 3; ++q) {
      ushort2 tv = *(const ushort2*)(tp + q * 128 + lane * 2);
      tf[q * 2] = bf2f(tv.x);
      tf[q * 2 + 1] = bf2f(tv.y);
    }
    float m = -1e30f, den = 0.f;
    u32 i = o;
    for (; i + 2 <= end; i += 2) {
      int d0 = (int)adj[i], d1 = (int)adj[i + 1];
      const u16* g0 = gi + (size_t)d0 * GS;
      const u16* g1 = gi + (size_t)d1 * GS;
      const u16* v0 = vmat + (size_t)d0 * VS;
      const u16* v1 = vmat + (size_t)d1 * VS;
      // issue all four row gathers up front
      ushort2 ga[3], gb[3], va[3], vb[3];
#pragma unroll
      for (int q = 0; q < 3; ++q) {
        ga[q] = *(const ushort2*)(g0 + q * 128 + lane * 2);
        gb[q] = *(const ushort2*)(g1 + q * 128 + lane * 2);
        va[q] = *(const ushort2*)(v0 + q * 128 + lane * 2);
        vb[q] = *(const ushort2*)(v1 + q * 128 + lane * 2);
      }
      float dot0 = 0.f, dot1 = 0.f;
#pragma unroll
      for (int q = 0; q < 3; ++q) {
        dot0 = fmaf(tf[q * 2], bf2f(ga[q].x), dot0);
        dot0 = fmaf(tf[q * 2 + 1], bf2f(ga[q].y), dot0);
        dot1 = fmaf(tf[q * 2], bf2f(gb[q].x), dot1);
        dot1 = fmaf(tf[q * 2 + 1], bf2f(gb[q].y), dot1);
      }
#pragma unroll
      for (int s2 = 32; s2 >= 1; s2 >>= 1) {
        dot0 += __shfl_xor(dot0, s2);
        dot1 += __shfl_xor(dot1, s2);
      }
      dot0 *= sc; dot1 *= sc;
      // online update, edge 0
      {
        float m1 = fmaxf(m, dot0);
        float sc0 = expf(m - m1);
        float e0 = expf(dot0 - m1);
        den = den * sc0 + e0;
#pragma unroll
        for (int q = 0; q < 3; ++q) {
          acc[q * 2]     = acc[q * 2]     * sc0 + e0 * bf2f(va[q].x);
          acc[q * 2 + 1] = acc[q * 2 + 1] * sc0 + e0 * bf2f(va[q].y);
        }
        m = m1;
      }
      // online update, edge 1
      {
        float m1 = fmaxf(m, dot1);
        float sc1 = expf(m - m1);
        float e1 = expf(dot1 - m1);
        den = den * sc1 + e1;
#pragma unroll
        for (int q = 0; q < 3; ++q) {
          acc[q * 2]     = acc[q * 2]     * sc1 + e1 * bf2f(vb[q].x);
          acc[q * 2 + 1] = acc[q * 2 + 1] * sc1 + e1 * bf2f(vb[q].y);
        }
        m = m1;
      }
    }
    if (i < end) {
      int d0 = (int)adj[i];
      const u16* g0 = gi + (size_t)d0 * GS;
      const u16* v0 = vmat + (size_t)d0 * VS;
      ushort2 ga[3], va[3];
#pragma unroll
      for (int q = 0; q < 3; ++q) {
        ga[q] = *(const ushort2*)(g0 + q * 128 + lane * 2);
        va[q] = *(const ushort2*)(v0 + q * 128 + lane * 2);
      }
      float dot0 = 0.f;
#pragma unroll
      for (int q = 0; q < 3; ++q) {
        dot0 = fmaf(tf[q * 2], bf2f(ga[q].x), dot0);
        dot0 = fmaf(tf[q * 2 + 1], bf2f(ga[q].y), dot0);
      }
#pragma unroll
      for (int s2 = 32; s2 >= 1; s2 >>= 1) dot0 += __shfl_xor(dot0, s2);
      dot0 *= sc;
      float m1 = fmaxf(m, dot0);
      float sc0 = expf(m - m1);
      float e0 = expf(dot0 - m1);
      den = den * sc0 + e0;
#pragma unroll
      for (int q = 0; q < 3; ++q) {
        acc[q * 2]     = acc[q * 2]     * sc0 + e0 * bf2f(va[q].x);
        acc[q * 2 + 1] = acc[q * 2 + 1] * sc0 + e0 * bf2f(va[q].y);
      }
      m = m1;
    }
    float invden = 1.0f / den;
#pragma unroll
    for (int k = 0; k < 6; ++k) acc[k] *= invden;
  }
  const u16* xp = xb + (size_t)node * FIN;
  u16* op = xf + (size_t)node * FIN;
#pragma unroll
  for (int q = 0; q < 3; ++q) {
    ushort2 xv = *(const ushort2*)(xp + q * 128 + lane * 2);
    ushort2 ov;
    ov.x = f2bf(acc[q * 2] + bf2f(xv.x));
    ov.y = f2bf(acc[q * 2 + 1] + bf2f(xv.y));
    *(ushort2*)(op + q * 128 + lane * 2) = ov;
  }
}

// ---------------------------------------------------------------------------
// MFMA bf16 GEMM (2-phase 128x128), 1-D grid + XCD swizzle (T1).
// ALL epilogues use transposed fragments (mfma(b,a) -> C^T): per frag,
//   row = row0+wr*64+jr*16+(lane&15), col = col0+wc*64+mc*16+(lane>>4)*4+reg.
// EPI 0/1/2: none / +bias / relu(+bias); split-bias at bsplit (16-aligned).
// EPI 4 (left): transposed fold (r in regs) + bf16 slice-stream (r15).
// EPI 6 (tv+gcn1 merged, Nc=896): col<768 -> Cp (stride 768); else Cbf2.
// ---------------------------------------------------------------------------
template <int EPI, int OUTBF>
__global__ __launch_bounds__(256)
void mgemm_k(const u16* __restrict__ Abf, int As, const u16* __restrict__ WT,
             const float* __restrict__ bias, const float* __restrict__ bias_b, int bsplit,
             void* __restrict__ Cp, u16* __restrict__ Cbf2,
             float* __restrict__ tmp, int M, int K, int Nc, int ncx) {
  __shared__ u16 Albuf[2][128 * 32];
  __shared__ u16 Blbuf[2][128 * 32];
  const int t = threadIdx.x;
  const int lane = t & 63;
  const int wave = t >> 6;
  const int wr = wave >> 1, wc = wave & 1;
  const int wgid = xcd_wgid();
  const int ctile = wgid % ncx;
  const int row0 = (wgid / ncx) * 128;
  const int col0 = ctile * 128;
  const int sr = t >> 2;
  const int sk = (t & 3) * 8;
  const int nt = K >> 5;

  f32x4 acc[4][4] = {};

  auto stage = [&](int buf, int k0) {
#pragma unroll
    for (int h = 0; h < 2; ++h) {
      int ar = row0 + h * 64 + sr;
      if (ar >= M) ar = M - 1;
      GLOAD16(Abf + (size_t)ar * As + k0 + sk, &Albuf[buf][h * 2048 + wave * 512]);
    }
#pragma unroll
    for (int h = 0; h < 2; ++h) {
      int bc = col0 + h * 64 + sr;
      if (bc >= Nc) bc = Nc - 1;
      GLOAD16(WT + (size_t)bc * K + k0 + sk, &Blbuf[buf][h * 2048 + wave * 512]);
    }
  };

  stage(0, 0);
  int buf = 0;
  for (int tk = 0; tk < nt; ++tk) {
    __syncthreads();
    if (tk + 1 < nt) stage(buf ^ 1, (tk + 1) << 5);
    const u16* Al = Albuf[buf];
    const u16* Bl = Blbuf[buf];
    s16x8 a[4], b[4];
#pragma unroll
    for (int m = 0; m < 4; ++m)
      a[m] = *(const s16x8*)(Al + (wr * 64 + m * 16 + (lane & 15)) * 32 + (lane >> 4) * 8);
#pragma unroll
    for (int j = 0; j < 4; ++j)
      b[j] = *(const s16x8*)(Bl + (wc * 64 + j * 16 + (lane & 15)) * 32 + (lane >> 4) * 8);
    // transposed everywhere: acc[mc][jr] = C^T frag (cols mc*16.., rows jr*16..)
#pragma unroll
    for (int mc = 0; mc < 4; ++mc)
#pragma unroll
      for (int jr = 0; jr < 4; ++jr)
        acc[mc][jr] = __builtin_amdgcn_mfma_f32_16x16x32_bf16(b[mc], a[jr], acc[mc][jr], 0, 0, 0);
    buf ^= 1;
  }

  if constexpr (EPI <= 2) {
#pragma unroll
    for (int jr = 0; jr < 4; ++jr) {
      int row = row0 + wr * 64 + jr * 16 + (lane & 15);
      if (row >= M) continue;
#pragma unroll
      for (int mc = 0; mc < 4; ++mc) {
        int colb = col0 + wc * 64 + mc * 16 + (lane >> 4) * 4;
        if (colb >= Nc) continue;
        float4 bv = make_float4(0.f, 0.f, 0.f, 0.f);
        if (EPI >= 1) {
          const float* bp = (colb < bsplit) ? bias + colb : bias_b + (colb - bsplit);
          bv = *(const float4*)bp;
        }
        float v0 = acc[mc][jr][0] + bv.x;
        float v1 = acc[mc][jr][1] + bv.y;
        float v2 = acc[mc][jr][2] + bv.z;
        float v3 = acc[mc][jr][3] + bv.w;
        if (EPI == 2) {
          v0 = fmaxf(v0, 0.f); v1 = fmaxf(v1, 0.f);
          v2 = fmaxf(v2, 0.f); v3 = fmaxf(v3, 0.f);
        }
        if (OUTBF) {
          ushort4 ov;
          ov.x = f2bf(v0); ov.y = f2bf(v1); ov.z = f2bf(v2); ov.w = f2bf(v3);
          *(ushort4*)((u16*)Cp + (size_t)row * Nc + colb) = ov;
        } else {
          *(float4*)((float*)Cp + (size_t)row * Nc + colb) = make_float4(v0, v1, v2, v3);
        }
      }
    }
  } else if constexpr (EPI == 6) {
#pragma unroll
    for (int jr = 0; jr < 4; ++jr) {
      int row = row0 + wr * 64 + jr * 16 + (lane & 15);
      if (row >= M) continue;
#pragma unroll
      for (int mc = 0; mc < 4; ++mc) {
        int colb = col0 + wc * 64 + mc * 16 + (lane >> 4) * 4;
        if (colb < 2 * FIN) {
          const float* bp = (colb < bsplit) ? bias + colb : bias_b + (colb - bsplit);
          float4 bv = *(const float4*)bp;
          ushort4 ov;
          ov.x = f2bf(acc[mc][jr][0] + bv.x);
          ov.y = f2bf(acc[mc][jr][1] + bv.y);
          ov.z = f2bf(acc[mc][jr][2] + bv.z);
          ov.w = f2bf(acc[mc][jr][3] + bv.w);
          *(ushort4*)((u16*)Cp + (size_t)row * (2 * FIN) + colb) = ov;
        } else {
          int c2 = colb - 2 * FIN;
          ushort4 ov;
          ov.x = f2bf(acc[mc][jr][0]);
          ov.y = f2bf(acc[mc][jr][1]);
          ov.z = f2bf(acc[mc][jr][2]);
          ov.w = f2bf(acc[mc][jr][3]);
          *(ushort4*)(Cbf2 + (size_t)row * HD + c2) = ov;
        }
      }
    }
  } else {  // EPI == 4: transposed fold + bf16 slice-stream (r15-verified)
    u16* slice = (u16*)Cp + (size_t)ctile * M * 8;
    float4 b4[4];
#pragma unroll
    for (int mc = 0; mc < 4; ++mc)
      b4[mc] = *(const float4*)&bias[col0 + wc * 64 + mc * 16 + (lane >> 4) * 4];
#pragma unroll
    for (int jr = 0; jr < 4; ++jr) {
      int row = row0 + wr * 64 + jr * 16 + (lane & 15);
      int rc = row < M ? row : M - 1;
      float4 tv = *(const float4*)&tmp[(size_t)rc * RD + (lane >> 4) * 4];
      ushort4 outp;
#pragma unroll
      for (int mc = 0; mc < 4; ++mc) {
        float s = (acc[mc][jr][0] + b4[mc].x) * tv.x +
                  (acc[mc][jr][1] + b4[mc].y) * tv.y +
                  (acc[mc][jr][2] + b4[mc].z) * tv.z +
                  (acc[mc][jr][3] + b4[mc].w) * tv.w;
        s += __shfl_xor(s, 16);
        s += __shfl_xor(s, 32);
        ((u16*)&outp)[mc] = f2bf(s);
      }
      if (lane < 16 && row < M)
        *(ushort4*)(slice + (size_t)row * 8 + wc * 4) = outp;
    }
  }
}

// ---------------------------------------------------------------------------
// pt gather: pt[row][ct*8+pl] = bf2f(ptP[ct][row][pl]); fp32 + bf16 outputs.
// ---------------------------------------------------------------------------
__global__ void ptgather_k(const u16* __restrict__ ptP, float* __restrict__ pt,
                           u16* __restrict__ ptb, int n) {
  int g = blockIdx.x * 256 + threadIdx.x;
  if (g >= n * 16) return;
  int row = g >> 4, ct = g & 15;
  const u16* sp = ptP + ((size_t)ct * n + (size_t)row) * 8;
  ushort4 a = ((const ushort4*)sp)[0];
  ushort4 b = ((const ushort4*)sp)[1];
  float* dp = pt + (size_t)row * PD + ct * 8;
  ((float4*)dp)[0] = make_float4(bf2f(a.x), bf2f(a.y), bf2f(a.z), bf2f(a.w));
  ((float4*)dp)[1] = make_float4(bf2f(b.x), bf2f(b.y), bf2f(b.z), bf2f(b.w));
  u16* db = ptb + (size_t)row * PD + ct * 8;
  ((ushort4*)db)[0] = a;
  ((ushort4*)db)[1] = b;
}

// ---------------------------------------------------------------------------
// Y-GEMM, 8-phase 256x256/BK=64/8-wave (T3+T4+T2+T5), race-verified (r8),
// 1-D grid + XCD swizzle (ncx=12 col-groups).
// ---------------------------------------------------------------------------
#define VM6  asm volatile("s_waitcnt vmcnt(6)" ::: "memory")
#define VM0  asm volatile("s_waitcnt vmcnt(0)" ::: "memory")
#define VMNOP
#define BARR asm volatile("s_barrier" ::: "memory")

__global__ __launch_bounds__(512)
void ygemm8_k(const u16* __restrict__ X, const u16* __restrict__ QT,
              const u16* __restrict__ Ar, float* __restrict__ tmpP, int M) {
  __shared__ u16 Al[2][16384];
  __shared__ u16 Bl[2][16384];
  const int t = threadIdx.x;
  const int lane = t & 63;
  const int wave = t >> 6;
  const int wr = wave >> 2;
  const int wcn = wave & 3;
  const int wgid = xcd_wgid();
  const int ctile = wgid % 12;
  const int row0 = (wgid / 12) * 256;
  const int col0 = ctile * 256;

  const int srow = t >> 3;
  const int sgk  = (((t & 7) ^ (srow & 7)) << 3);
  const int sdst = t * 8;

  const int pc0 = (((lane >> 4)) ^ (lane & 7)) << 3;
  const int pc1 = ((((lane >> 4) + 4)) ^ (lane & 7)) << 3;
  const int arow = (wr * 128 + (lane & 15)) << 6;
  const int brow = (wcn * 64 + (lane & 15)) << 6;

  f32x4 acc[8][4] = {};
  s16x8 a[4][2], b[4][2];

#define STGA8(bf, h, kt) do {                                                  \
    int r0_ = row0 + (h) * 128 + srow;                                         \
    int r1_ = r0_ + 64;                                                        \
    if (r0_ >= M) r0_ = M - 1;                                                 \
    if (r1_ >= M) r1_ = M - 1;                                                 \
    GLOAD16(X + (size_t)r0_ * 384 + (kt) * 64 + sgk, &Al[bf][(h) * 8192 + sdst]);        \
    GLOAD16(X + (size_t)r1_ * 384 + (kt) * 64 + sgk, &Al[bf][(h) * 8192 + 4096 + sdst]); \
  } while (0)

#define STGB8(bf, h, kt) do {                                                  \
    int c0_ = col0 + (h) * 128 + srow;                                         \
    GLOAD16(QT + (size_t)c0_ * 384 + (kt) * 64 + sgk, &Bl[bf][(h) * 8192 + sdst]);       \
    GLOAD16(QT + (size_t)(c0_ + 64) * 384 + (kt) * 64 + sgk,                   \
            &Bl[bf][(h) * 8192 + 4096 + sdst]);                                \
  } while (0)

#define LDA8(bf, mh) do {                                                      \
    _Pragma("unroll") for (int m2_ = 0; m2_ < 4; ++m2_) {                      \
      const u16* p_ = &Al[bf][arow + ((mh) * 4 + m2_) * 1024];                 \
      a[m2_][0] = *(const s16x8*)(p_ + pc0);                                   \
      a[m2_][1] = *(const s16x8*)(p_ + pc1);                                   \
    }                                                                          \
  } while (0)

#define LDB8(bf, jh) do {                                                      \
    _Pragma("unroll") for (int j2_ = 0; j2_ < 2; ++j2_) {                      \
      const u16* p_ = &Bl[bf][brow + ((jh) * 2 + j2_) * 1024];                 \
      b[(jh) * 2 + j2_][0] = *(const s16x8*)(p_ + pc0);                        \
      b[(jh) * 2 + j2_][1] = *(const s16x8*)(p_ + pc1);                        \
    }                                                                          \
  } while (0)

#define MQ8(mh, jh) do {                                                       \
    __builtin_amdgcn_s_setprio(1);                                             \
    _Pragma("unroll") for (int m2_ = 0; m2_ < 4; ++m2_)                        \
      _Pragma("unroll") for (int j2_ = 0; j2_ < 2; ++j2_)                      \
        _Pragma("unroll") for (int ks_ = 0; ks_ < 2; ++ks_)                    \
          acc[(mh) * 4 + m2_][(jh) * 2 + j2_] =                                \
              __builtin_amdgcn_mfma_f32_16x16x32_bf16(                         \
                  a[m2_][ks_], b[(jh) * 2 + j2_][ks_],                         \
                  acc[(mh) * 4 + m2_][(jh) * 2 + j2_], 0, 0, 0);               \
    __builtin_amdgcn_s_setprio(0);                                             \
  } while (0)

  STGA8(0, 0, 0); STGA8(0, 1, 0); STGB8(0, 0, 0); STGB8(0, 1, 0);
  STGA8(1, 0, 1); STGB8(1, 0, 1); STGB8(1, 1, 1);
  VM6; BARR;

#define ITER8(i, VMP3, VMP7, DOSTG)                                                          \
  /*ph0*/ LDA8(0,0); LDB8(0,0); STGA8(1,1,2*(i)+1);                   BARR; MQ8(0,0); BARR;  \
  /*ph1*/ LDB8(0,1);                                                  BARR; MQ8(0,1); BARR;  \
  /*ph2*/ LDA8(0,1); if (DOSTG) STGB8(0,0,2*(i)+2);                   BARR; MQ8(1,0); BARR;  \
  /*ph3*/ if (DOSTG) { STGB8(0,1,2*(i)+2); STGA8(0,0,2*(i)+2); } VMP3; BARR; MQ8(1,1); BARR; \
  /*ph4*/ LDA8(1,0); LDB8(1,0); if (DOSTG) STGA8(0,1,2*(i)+2);        BARR; MQ8(0,0); BARR;  \
  /*ph5*/ LDB8(1,1);                                                  BARR; MQ8(0,1); BARR;  \
  /*ph6*/ LDA8(1,1); if (DOSTG) STGB8(1,0,2*(i)+3);                   BARR; MQ8(1,0); BARR;  \
  /*ph7*/ if (DOSTG) { STGB8(1,1,2*(i)+3); STGA8(1,0,2*(i)+3); } VMP7; BARR; MQ8(1,1); BARR;

  ITER8(0, VM6, VM6, 1)
  ITER8(1, VM6, VM6, 1)
  ITER8(2, VM0, VMNOP, 0)

  // fold: s[m][rr] = sum_j relu_r[row, h0+j] * acc[m][j][rr]
  const int h0 = (col0 >> 4) + wcn * 4;
  float s[8][4];
#pragma unroll
  for (int m = 0; m < 8; ++m) {
#pragma unroll
    for (int rr = 0; rr < 4; ++rr) {
      int row = row0 + wr * 128 + m * 16 + (lane >> 4) * 4 + rr;
      int rc = row < M ? row : M - 1;
      ushort4 arv = *(const ushort4*)(Ar + (size_t)rc * 384 + h0);
      s[m][rr] = bf2f(arv.x) * acc[m][0][rr] + bf2f(arv.y) * acc[m][1][rr] +
                 bf2f(arv.z) * acc[m][2][rr] + bf2f(arv.w) * acc[m][3][rr];
    }
  }

  __syncthreads();
  float* redA = (float*)&Al[0][0];
  float* redB = redA + 4096;
  const int r16 = lane & 15;
  const int rlb = wr * 128 + (lane >> 4) * 4;
  if (wcn & 1) {
    float* red = (wcn == 1) ? redA : redB;
#pragma unroll
    for (int m = 0; m < 8; ++m)
#pragma unroll
      for (int rr = 0; rr < 4; ++rr)
        red[(rlb + m * 16 + rr) * 16 + r16] = s[m][rr];
  }
  __syncthreads();
  if (!(wcn & 1)) {
    float* red = (wcn == 0) ? redA : redB;
#pragma unroll
    for (int m = 0; m < 8; ++m)
#pragma unroll
      for (int rr = 0; rr < 4; ++rr)
        s[m][rr] += red[(rlb + m * 16 + rr) * 16 + r16];
  }
  __syncthreads();
  if (wcn == 2) {
#pragma unroll
    for (int m = 0; m < 8; ++m)
#pragma unroll
      for (int rr = 0; rr < 4; ++rr)
        redA[(rlb + m * 16 + rr) * 16 + r16] = s[m][rr];
  }
  __syncthreads();
  if (wcn == 0) {
    float* slice = tmpP + (size_t)ctile * M * RD;
#pragma unroll
    for (int m = 0; m < 8; ++m)
#pragma unroll
      for (int rr = 0; rr < 4; ++rr) {
        int row = row0 + rlb + m * 16 + rr;
        if (row < M)
          slice[(size_t)row * RD + r16] =
              s[m][rr] + redA[(rlb + m * 16 + rr) * 16 + r16];
      }
  }
#undef STGA8
#undef STGB8
#undef LDA8
#undef LDB8
#undef MQ8
#undef ITER8
}

// ---------------------------------------------------------------------------
// combine: temp[i] = sum_{s=0..12} tmpP[s][i]   (slice 12 = x@Br bias term)
// ---------------------------------------------------------------------------
__global__ void combine_k(const float* __restrict__ tmpP, float* __restrict__ temp,
                          size_t sl, int tot4) {
  int i = blockIdx.x * 256 + threadIdx.x;
  if (i >= tot4) return;
  float4 s = ((const float4*)(tmpP + 12 * sl))[i];
#pragma unroll
  for (int c = 0; c < 12; ++c) {
    float4 p = ((const float4*)(tmpP + (size_t)c * sl))[i];
    s.x += p.x; s.y += p.y; s.z += p.z; s.w += p.w;
  }
  ((float4*)temp)[i] = s;
}

// ---------------------------------------------------------------------------
// Final: in-place row-normalize p_t, p_g; alignment = dot of normalized rows.
// ---------------------------------------------------------------------------
__global__ void final_k(float* __restrict__ out, int n) {
  int node = (blockIdx.x * blockDim.x + threadIdx.x) >> 6;
  int lane = threadIdx.x & 63;
  if (node >= n) return;
  float* pt = out + n + (size_t)node * PD;
  float* pg = out + n + (size_t)n * PD + (size_t)node * PD;
  float2 t = ((float2*)pt)[lane];
  float2 g = ((float2*)pg)[lane];
  float tt = t.x * t.x + t.y * t.y;
  float gg = g.x * g.x + g.y * g.y;
  float tg = t.x * g.x + t.y * g.y;
#pragma unroll
  for (int s = 32; s >= 1; s >>= 1) {
    tt += __shfl_xor(tt, s);
    gg += __shfl_xor(gg, s);
    tg += __shfl_xor(tg, s);
  }
  float invt = 1.0f / fmaxf(sqrtf(tt), 1e-12f);
  float invg = 1.0f / fmaxf(sqrtf(gg), 1e-12f);
  ((float2*)pt)[lane] = make_float2(t.x * invt, t.y * invt);
  ((float2*)pg)[lane] = make_float2(g.x * invg, g.y * invg);
  if (lane == 0) out[node] = tg * invt * invg;
}

// ---------------------------------------------------------------------------
struct MgArgs {
  const u16* A; int As; const u16* WT;
  const float* b; const float* b2; int bsplit;
  void* C; u16* C2; float* tmp;
  int M, K, Nc;
};
template <int EPI, int OUTBF>
static void mg(const MgArgs& a, hipStream_t s) {
  int ncx = (a.Nc + 127) / 128, nry = (a.M + 127) / 128;
  mgemm_k<EPI, OUTBF><<<dim3(ncx * nry), 256, 0, s>>>(
      a.A, a.As, a.WT, a.b, a.b2, a.bsplit, a.C, a.C2, a.tmp,
      a.M, a.K, a.Nc, ncx);
}

extern "C" void kernel_launch(void* const* d_in, const int* in_sizes, int n_in,
                              void* d_out, int out_size, void* d_ws, size_t ws_size,
                              hipStream_t stream) {
  const float* x      = (const float*)d_in[0];
  const int*   ei     = (const int*)d_in[1];
  const float* W_gcn1 = (const float*)d_in[2];
  const float* b_gcn1 = (const float*)d_in[3];
  const float* W_ti   = (const float*)d_in[4];
  const float* b_ti   = (const float*)d_in[5];
  const float* W_gi   = (const float*)d_in[6];
  const float* b_gi   = (const float*)d_in[7];
  const float* W_v    = (const float*)d_in[8];
  const float* b_v    = (const float*)d_in[9];
  const float* Wl1    = (const float*)d_in[10];
  const float* bl1    = (const float*)d_in[11];
  const float* Wl2    = (const float*)d_in[12];
  const float* bl2    = (const float*)d_in[13];
  const float* Wr1    = (const float*)d_in[14];
  const float* br1    = (const float*)d_in[15];
  const float* Wr2    = (const float*)d_in[16];
  const float* br2    = (const float*)d_in[17];
  const float* W_gcn2 = (const float*)d_in[18];
  const float* b_gcn2 = (const float*)d_in[19];
  const float* W_gp   = (const float*)d_in[20];
  const float* b_gp   = (const float*)d_in[21];

  const int n = in_sizes[0] / FIN;   // 50000
  const int E = in_sizes[1] / 2;     // 500000
  const int* src = ei;
  const int* dst = ei + E;

  // -------- workspace carve (tmpP/ptP overlay gibf+xfbf) --------
  char* wsp = (char*)d_ws;
  auto carve = [&](size_t bytes) -> void* {
    void* p = (void*)wsp;
    wsp += (bytes + 255) & ~(size_t)255;
    return p;
  };
  u32* cnt      = (u32*)carve((size_t)2 * n * 4);   // [src | dst]
  u32* off      = (u32*)carve((size_t)2 * n * 4);
  u32* cur      = (u32*)carve((size_t)2 * n * 4);
  u32* bsum     = (u32*)carve(512);
  u32* adj      = (u32*)carve((size_t)2 * E * 4);   // [src-CSR dsts | dst-CSR srcs]
  float* dinv   = (float*)carve((size_t)n * 4);
  float* temp   = (float*)carve((size_t)n * RD * 4);

  u16* xbf    = (u16*)carve((size_t)n * FIN * 2);       // x bf16 (pristine)
  u16* tvbf   = (u16*)carve((size_t)n * 2 * FIN * 2);   // [t_info | v]; later lrbf
  u16* bufHbf = (u16*)carve((size_t)n * HD * 2);        // xw (both GCNs)
  u16* gembf  = (u16*)carve((size_t)n * HD * 2);
  u16* ptbf   = (u16*)carve((size_t)n * PD * 2);
  u16* g2bf   = (u16*)carve((size_t)n * HD * 2);

  // gibf and xfbf adjacent; tmpP (13 x n*16 fp32 = 41.6 MB) overlays them;
  // ptP (16 x n*8 bf16 = 12.8 MB) reuses the same region after combine.
  u16* gibf   = (u16*)carve((size_t)n * FIN * 2);       // g_info
  u16* xfbf   = (u16*)carve((size_t)n * FIN * 2);       // x_fused
  size_t tmpP_bytes = (size_t)13 * n * RD * 4;
  size_t overlay    = (size_t)2 * n * FIN * 2;
  carve(tmpP_bytes > overlay ? tmpP_bytes - overlay : 0);
  float* tmpP = (float*)gibf;
  u16* ptP    = (u16*)gibf;   // reused after combine_k (slices dead)

  u16* WtvT   = (u16*)carve((size_t)2 * FIN * FIN * 2); // [768][384]
  u16* WgcnT  = (u16*)carve((size_t)HD * FIN * 2);      // [128][384], contiguous
  u16* WgiT   = (u16*)carve((size_t)FIN * HD * 2);      // [384][128]
  u16* WlrT   = (u16*)carve((size_t)FIN * FIN * 2);     // [384][384]
  u16* Wl2T   = (u16*)carve((size_t)2048 * 192 * 2);
  u16* QT     = (u16*)carve((size_t)3072 * FIN * 2);    // permuted Wr2
  u16* BrT    = (u16*)carve((size_t)RD * FIN * 2);      // br2 reshaped [16][384]
  u16* Wgcn2T = (u16*)carve((size_t)HD * PD * 2);
  u16* WgpT   = (u16*)carve((size_t)PD * PD * 2);

  u16* lrbf = tvbf;   // [relu_l | relu_r], stride 384; tv dead after attn

  float* out    = (float*)d_out;
  float* pt_raw = out + n;
  float* pg_raw = out + n + (size_t)n * PD;
  float* g2     = out + n + (size_t)2 * n * PD;

  // 0) all converts in one launch
  CvtDesc dsc;
  int nent = 0, blk = 0;
  auto addent = [&](const float* s, u16* d, int K, int N, int mode) {
    dsc.e[nent] = {s, d, K, N, mode, blk};
    blk += (K * N + 255) / 256;
    ++nent;
  };
  addent(x,      xbf,    n * FIN, 1, 1);
  addent(W_ti,   WtvT,   FIN, FIN, 0);
  addent(W_v,    WtvT + (size_t)FIN * FIN, FIN, FIN, 0);
  addent(W_gcn1, WgcnT,  FIN, HD,  0);
  addent(W_gi,   WgiT,   HD,  FIN, 0);
  addent(Wl1,    WlrT,   FIN, 192, 0);
  addent(Wr1,    WlrT + (size_t)192 * FIN, FIN, 192, 0);
  addent(Wl2,    Wl2T,   192, 2048, 0);
  addent(Wr2,    QT,     FIN, 3072, 2);
  addent(br2,    BrT,    RD * FIN, 1, 1);
  addent(W_gcn2, Wgcn2T, PD, HD, 0);
  addent(W_gp,   WgpT,   PD, PD, 0);
  dsc.n = nent;
  cvt_all_k<<<blk, 256, 0, stream>>>(dsc);

  // 1) CSR build + degrees (one concatenated scan over 2n)
  hipMemsetAsync(cnt, 0, (size_t)2 * n * 4, stream);
  hist_k<<<(E + 255) / 256, 256, 0, stream>>>(src, dst, cnt, n, E);
  int n2 = 2 * n;
  int nb = (n2 + 1023) / 1024;
  scanA_k<<<nb, 1024, 0, stream>>>(cnt, off, bsum, n2);
  scanB_k<<<1, 64, 0, stream>>>(bsum, nb);
  scanC_k<<<nb, 1024, 0, stream>>>(off, cur, bsum, n2);
  fill_k<<<(E + 255) / 256, 256, 0, stream>>>(src, dst, cur, adj, n, E);
  dinv_k<<<(n + 255) / 256, 256, 0, stream>>>(cnt + n, dinv, n);

  MgArgs a{};

  // 2+3a) merged GEMM: [t_info | v | xw_gcn1], Nc=896 (EPI 6)
  a = {xbf, FIN, WtvT, b_ti, b_v, FIN, tvbf, bufHbf, nullptr, n, FIN, 896};
  mg<6, 1>(a, stream);
  gcn_agg_k<0, 1><<<(n + 3) / 4, 256, 0, stream>>>(bufHbf, dinv, off + n, cnt + n, adj,
                                                   b_gcn1, nullptr, gembf, n);

  // 3b) g_info GEMM; fused single-pass online-softmax attention
  a = {gembf, HD, WgiT, b_gi, nullptr, 1 << 30, gibf, nullptr, nullptr, n, HD, FIN};
  mg<1, 1>(a, stream);
  attn_fused_k<<<(n + 3) / 4, 256, 0, stream>>>(off, cnt, adj, tvbf, 2 * FIN, gibf, FIN,
                                                tvbf + FIN, 2 * FIN, xbf, xfbf, n);

  // 4) Generators: [relu_l | relu_r] in one GEMM (overwrites tv buffer)
  a = {xfbf, FIN, WlrT, bl1, br1, 192, lrbf, nullptr, nullptr, n, FIN, FIN};
  mg<2, 1>(a, stream);

  // right path: x@Br into tmpP slice 12, 8-phase Y-GEMM partials into 0..11,
  // combine -> temp. (gibf/xfbf dead from here.)
  a = {xbf, FIN, BrT, nullptr, nullptr, 1 << 30, tmpP + (size_t)12 * n * RD, nullptr,
       nullptr, n, FIN, RD};
  mg<0, 0>(a, stream);
  ygemm8_k<<<dim3(12 * ((n + 255) / 256)), 512, 0, stream>>>(xbf, QT, lrbf + 192,
                                                             tmpP, n);
  combine_k<<<(n * RD / 4 + 255) / 256, 256, 0, stream>>>(tmpP, temp, (size_t)n * RD,
                                                          n * RD / 4);

  // left path fused (transposed-fragment fold): ptP[16][n][8], then gather
  a = {lrbf, FIN, Wl2T, bl2, nullptr, 1 << 30, ptP, nullptr, temp, n, 192, PD * RD};
  mg<4, 0>(a, stream);
  ptgather_k<<<(n * 16 + 255) / 256, 256, 0, stream>>>(ptP, pt_raw, ptbf, n);

  // 5) GCN2 + projection
  a = {ptbf, PD, Wgcn2T, nullptr, nullptr, 1 << 30, bufHbf, nullptr, nullptr, n, PD, HD};
  mg<0, 1>(a, stream);
  gcn_agg_k<1, 1><<<(n + 3) / 4, 256, 0, stream>>>(bufHbf, dinv, off + n, cnt + n, adj,
                                                   b_gcn2, g2, g2bf, n);
  a = {g2bf, HD, WgpT, b_gp, nullptr, 1 << 30, pg_raw, nullptr, nullptr, n, HD, PD};
  mg<1, 0>(a, stream);

  // 6) normalize + alignment
  final_k<<<(n + 3) / 4, 256, 0, stream>>>(out, n);
}

// Round 18
// 775.391 us; speedup vs baseline: 1.2089x; 1.0121x over previous
//
#include <hip/hip_runtime.h>

typedef unsigned int u32;
typedef unsigned short u16;
typedef short s16x8 __attribute__((ext_vector_type(8)));
typedef u16 u16x8 __attribute__((ext_vector_type(8)));
typedef float f32x4 __attribute__((ext_vector_type(4)));

#define FIN 384
#define HD  128
#define PD  128
#define RD  16

#define GLOAD16(g, l)                                                          \
  __builtin_amdgcn_global_load_lds(                                            \
      (const __attribute__((address_space(1))) void*)(g),                      \
      (__attribute__((address_space(3))) void*)(l), 16, 0, 0)

__device__ __forceinline__ u16 f2bf(float f) {
  u32 u = __float_as_uint(f);
  u32 r = (u + 0x7fffu + ((u >> 16) & 1u)) >> 16;   // RNE
  return (u16)r;
}
__device__ __forceinline__ float bf2f(u16 h) {
  return __uint_as_float(((u32)h) << 16);
}

// XCD-aware bijective block remap (m204): assumes dispatch XCD ~ blockIdx%8.
__device__ __forceinline__ int xcd_wgid() {
  int nwg = gridDim.x, orig = blockIdx.x;
  int q = nwg >> 3, r = nwg & 7, xcd = orig & 7, idx = orig >> 3;
  return (xcd < r ? xcd * (q + 1) : r * (q + 1) + (xcd - r) * q) + idx;
}

// ---------------------------------------------------------------------------
// Coalesced converts (x copy, QT permute, Br copy) — no strided access.
// mode 1: copy; mode 2: Wr2 Q-permute (q=h*16+r), reads consecutive in f.
// ---------------------------------------------------------------------------
struct CvtEnt { const float* s; u16* d; int K, N, mode, blk0; };
struct CvtDesc { CvtEnt e[4]; int n; };

__global__ void cvt_all_k(CvtDesc dsc) {
  int b = blockIdx.x;
  int ei = 0;
  while (ei + 1 < dsc.n && dsc.e[ei + 1].blk0 <= b) ++ei;
  CvtEnt E = dsc.e[ei];
  int i = (b - E.blk0) * 256 + (int)threadIdx.x;
  int tot = E.K * E.N;
  if (i >= tot) return;
  float v;
  if (E.mode == 1) {
    v = E.s[i];
  } else {  // mode 2
    int q = i / 384, f = i - q * 384;
    v = E.s[(size_t)(q >> 4) * 6144 + (q & 15) * 384 + f];
  }
  E.d[i] = f2bf(v);
}

// ---------------------------------------------------------------------------
// Tiled weight transpose: dst[c*K+k] = bf16(src[k*N+c]), 32x32 LDS tiles,
// coalesced reads AND writes (r18 fix: mode-0 strided reads were ~16x
// read-amplified). All K,N are multiples of 32.
// ---------------------------------------------------------------------------
struct TrEnt { const float* s; u16* d; int K, N, blk0; };
struct TrDesc { TrEnt e[9]; int n; };

__global__ void wtr_k(TrDesc dsc) {
  __shared__ float tile[32][33];
  int b = blockIdx.x;
  int ei = 0;
  while (ei + 1 < dsc.n && dsc.e[ei + 1].blk0 <= b) ++ei;
  TrEnt E = dsc.e[ei];
  int t = b - E.blk0;
  int ktiles = E.K >> 5;
  int tk = t % ktiles, tc = t / ktiles;
  int k0 = tk * 32, c0 = tc * 32;
  int i = threadIdx.x >> 5, j = threadIdx.x & 31;
#pragma unroll
  for (int s = 0; s < 4; ++s) {
    int kk = i + s * 8;
    tile[kk][j] = E.s[(size_t)(k0 + kk) * E.N + (c0 + j)];
  }
  __syncthreads();
#pragma unroll
  for (int s = 0; s < 4; ++s) {
    int cc = i + s * 8;
    E.d[(size_t)(c0 + cc) * E.K + (k0 + j)] = f2bf(tile[j][cc]);
  }
}

// ---------------------------------------------------------------------------
// Graph preprocessing (concatenated src|dst arrays, one scan over 2n)
// ---------------------------------------------------------------------------
__global__ void hist_k(const int* __restrict__ src, const int* __restrict__ dst,
                       u32* __restrict__ cnt, int n, int E) {
  int i = blockIdx.x * 256 + threadIdx.x;
  if (i < E) {
    atomicAdd(&cnt[src[i]], 1u);
    atomicAdd(&cnt[n + dst[i]], 1u);
  }
}

__global__ __launch_bounds__(1024)
void scanA_k(const u32* __restrict__ cnt, u32* __restrict__ off,
             u32* __restrict__ bsum, int n2) {
  __shared__ u32 sh[1024];
  int i = blockIdx.x * 1024 + (int)threadIdx.x;
  u32 v = (i < n2) ? cnt[i] : 0u;
  sh[threadIdx.x] = v;
  __syncthreads();
  for (int s = 1; s < 1024; s <<= 1) {
    u32 t = (threadIdx.x >= (u32)s) ? sh[threadIdx.x - s] : 0u;
    __syncthreads();
    sh[threadIdx.x] += t;
    __syncthreads();
  }
  if (i < n2) off[i] = sh[threadIdx.x] - v;       // local exclusive
  if (threadIdx.x == 1023) bsum[blockIdx.x] = sh[1023];
}

__global__ void scanB_k(u32* __restrict__ bsum, int nb) {   // 1 wave, chunks of 64
  int l = threadIdx.x;
  u32 carry = 0u;
  for (int base = 0; base < nb; base += 64) {
    u32 v = (base + l < nb) ? bsum[base + l] : 0u;
    for (int s = 1; s < 64; s <<= 1) {
      u32 t = __shfl_up(v, s);
      if (l >= s) v += t;
    }
    if (base + l < nb) bsum[base + l] = v + carry;
    carry += __shfl(v, 63);
  }
}

__global__ __launch_bounds__(1024)
void scanC_k(u32* __restrict__ off, u32* __restrict__ cur,
             const u32* __restrict__ bsum, int n2) {
  int b = blockIdx.x;
  int i = b * 1024 + (int)threadIdx.x;
  if (i >= n2) return;
  u32 add = (b > 0) ? bsum[b - 1] : 0u;
  u32 o = off[i] + add;
  off[i] = o;
  cur[i] = o;
}

__global__ void fill_k(const int* __restrict__ src, const int* __restrict__ dst,
                       u32* __restrict__ cur, u32* __restrict__ adj, int n, int E) {
  int i = blockIdx.x * 256 + threadIdx.x;
  if (i >= E) return;
  int s = src[i], d = dst[i];
  u32 ps = atomicAdd(&cur[s], 1u);
  adj[ps] = (u32)d;
  u32 pd = atomicAdd(&cur[n + d], 1u);
  adj[pd] = (u32)s;
}

__global__ void dinv_k(const u32* __restrict__ cd, float* __restrict__ dinv, int n) {
  int i = blockIdx.x * 256 + threadIdx.x;
  if (i < n) dinv[i] = 1.0f / sqrtf((float)(cd[i] + 1u));
}

// ---------------------------------------------------------------------------
// GCN aggregation, bf16 in, fp32/bf16 out; 4-edge ILP
// ---------------------------------------------------------------------------
template <int WF32, int WBF>
__global__ void gcn_agg_k(const u16* __restrict__ xw, const float* __restrict__ dinv,
                          const u32* __restrict__ off, const u32* __restrict__ cnt,
                          const u32* __restrict__ nbr, const float* __restrict__ bias,
                          float* __restrict__ outf, u16* __restrict__ outb, int n) {
  int node = (blockIdx.x * blockDim.x + threadIdx.x) >> 6;
  int lane = threadIdx.x & 63;
  if (node >= n) return;
  float di = dinv[node];
  ushort2 v = ((const ushort2*)(xw + (size_t)node * HD))[lane];
  float ax = di * di * bf2f(v.x), ay = di * di * bf2f(v.y);
  u32 i = off[node], end = i + cnt[node];
  for (; i + 4 <= end; i += 4) {
    int s0 = (int)nbr[i],     s1 = (int)nbr[i + 1];
    int s2 = (int)nbr[i + 2], s3 = (int)nbr[i + 3];
    float w0 = di * dinv[s0], w1 = di * dinv[s1];
    float w2 = di * dinv[s2], w3 = di * dinv[s3];
    ushort2 u0 = ((const ushort2*)(xw + (size_t)s0 * HD))[lane];
    ushort2 u1 = ((const ushort2*)(xw + (size_t)s1 * HD))[lane];
    ushort2 u2 = ((const ushort2*)(xw + (size_t)s2 * HD))[lane];
    ushort2 u3 = ((const ushort2*)(xw + (size_t)s3 * HD))[lane];
    ax = fmaf(w0, bf2f(u0.x), ax); ay = fmaf(w0, bf2f(u0.y), ay);
    ax = fmaf(w1, bf2f(u1.x), ax); ay = fmaf(w1, bf2f(u1.y), ay);
    ax = fmaf(w2, bf2f(u2.x), ax); ay = fmaf(w2, bf2f(u2.y), ay);
    ax = fmaf(w3, bf2f(u3.x), ax); ay = fmaf(w3, bf2f(u3.y), ay);
  }
  for (; i < end; ++i) {
    int s0 = (int)nbr[i];
    float w0 = di * dinv[s0];
    ushort2 u0 = ((const ushort2*)(xw + (size_t)s0 * HD))[lane];
    ax = fmaf(w0, bf2f(u0.x), ax);
    ay = fmaf(w0, bf2f(u0.y), ay);
  }
  float2 b = ((const float2*)bias)[lane];
  ax += b.x; ay += b.y;
  if (WF32) ((float2*)(outf + (size_t)node * HD))[lane] = make_float2(ax, ay);
  if (WBF) {
    ushort2 ob; ob.x = f2bf(ax); ob.y = f2bf(ay);
    ((ushort2*)(outb + (size_t)node * HD))[lane] = ob;
  }
}

// ---------------------------------------------------------------------------
// Fused attention, single-pass online softmax (flash-style, exact).
// ---------------------------------------------------------------------------
__global__ void attn_fused_k(const u32* __restrict__ off, const u32* __restrict__ cnt,
                             const u32* __restrict__ adj,
                             const u16* __restrict__ ti, int TS,
                             const u16* __restrict__ gi, int GS,
                             const u16* __restrict__ vmat, int VS,
                             const u16* __restrict__ xb,
                             u16* __restrict__ xf, int n) {
  int node = (blockIdx.x * blockDim.x + threadIdx.x) >> 6;
  int lane = threadIdx.x & 63;
  if (node >= n) return;
  u32 o = off[node], c = cnt[node];
  u32 end = o + c;
  float acc[6] = {0.f, 0.f, 0.f, 0.f, 0.f, 0.f};
  const float sc = 0.05103103630798288f;   // 1/sqrt(384)
  if (c > 0) {
    const u16* tp = ti + (size_t)node * TS;
    float tf[6];
#pragma unroll
    for (int q = 0; q < 3; ++q) {
      ushort2 tv = *(const ushort2*)(tp + q * 128 + lane * 2);
      tf[q * 2] = bf2f(tv.x);
      tf[q * 2 + 1] = bf2f(tv.y);
    }
    float m = -1e30f, den = 0.f;
    u32 i = o;
    for (; i + 2 <= end; i += 2) {
      int d0 = (int)adj[i], d1 = (int)adj[i + 1];
      const u16* g0 = gi + (size_t)d0 * GS;
      const u16* g1 = gi + (size_t)d1 * GS;
      const u16* v0 = vmat + (size_t)d0 * VS;
      const u16* v1 = vmat + (size_t)d1 * VS;
      ushort2 ga[3], gb[3], va[3], vb[3];
#pragma unroll
      for (int q = 0; q < 3; ++q) {
        ga[q] = *(const ushort2*)(g0 + q * 128 + lane * 2);
        gb[q] = *(const ushort2*)(g1 + q * 128 + lane * 2);
        va[q] = *(const ushort2*)(v0 + q * 128 + lane * 2);
        vb[q] = *(const ushort2*)(v1 + q * 128 + lane * 2);
      }
      float dot0 = 0.f, dot1 = 0.f;
#pragma unroll
      for (int q = 0; q < 3; ++q) {
        dot0 = fmaf(tf[q * 2], bf2f(ga[q].x), dot0);
        dot0 = fmaf(tf[q * 2 + 1], bf2f(ga[q].y), dot0);
        dot1 = fmaf(tf[q * 2], bf2f(gb[q].x), dot1);
        dot1 = fmaf(tf[q * 2 + 1], bf2f(gb[q].y), dot1);
      }
#pragma unroll
      for (int s2 = 32; s2 >= 1; s2 >>= 1) {
        dot0 += __shfl_xor(dot0, s2);
        dot1 += __shfl_xor(dot1, s2);
      }
      dot0 *= sc; dot1 *= sc;
      {
        float m1 = fmaxf(m, dot0);
        float sc0 = expf(m - m1);
        float e0 = expf(dot0 - m1);
        den = den * sc0 + e0;
#pragma unroll
        for (int q = 0; q < 3; ++q) {
          acc[q * 2]     = acc[q * 2]     * sc0 + e0 * bf2f(va[q].x);
          acc[q * 2 + 1] = acc[q * 2 + 1] * sc0 + e0 * bf2f(va[q].y);
        }
        m = m1;
      }
      {
        float m1 = fmaxf(m, dot1);
        float sc1 = expf(m - m1);
        float e1 = expf(dot1 - m1);
        den = den * sc1 + e1;
#pragma unroll
        for (int q = 0; q < 3; ++q) {
          acc[q * 2]     = acc[q * 2]     * sc1 + e1 * bf2f(vb[q].x);
          acc[q * 2 + 1] = acc[q * 2 + 1] * sc1 + e1 * bf2f(vb[q].y);
        }
        m = m1;
      }
    }
    if (i < end) {
      int d0 = (int)adj[i];
      const u16* g0 = gi + (size_t)d0 * GS;
      const u16* v0 = vmat + (size_t)d0 * VS;
      ushort2 ga[3], va[3];
#pragma unroll
      for (int q = 0; q < 3; ++q) {
        ga[q] = *(const ushort2*)(g0 + q * 128 + lane * 2);
        va[q] = *(const ushort2*)(v0 + q * 128 + lane * 2);
      }
      float dot0 = 0.f;
#pragma unroll
      for (int q = 0; q < 3; ++q) {
        dot0 = fmaf(tf[q * 2], bf2f(ga[q].x), dot0);
        dot0 = fmaf(tf[q * 2 + 1], bf2f(ga[q].y), dot0);
      }
#pragma unroll
      for (int s2 = 32; s2 >= 1; s2 >>= 1) dot0 += __shfl_xor(dot0, s2);
      dot0 *= sc;
      float m1 = fmaxf(m, dot0);
      float sc0 = expf(m - m1);
      float e0 = expf(dot0 - m1);
      den = den * sc0 + e0;
#pragma unroll
      for (int q = 0; q < 3; ++q) {
        acc[q * 2]     = acc[q * 2]     * sc0 + e0 * bf2f(va[q].x);
        acc[q * 2 + 1] = acc[q * 2 + 1] * sc0 + e0 * bf2f(va[q].y);
      }
      m = m1;
    }
    float invden = 1.0f / den;
#pragma unroll
    for (int k = 0; k < 6; ++k) acc[k] *= invden;
  }
  const u16* xp = xb + (size_t)node * FIN;
  u16* op = xf + (size_t)node * FIN;
#pragma unroll
  for (int q = 0; q < 3; ++q) {
    ushort2 xv = *(const ushort2*)(xp + q * 128 + lane * 2);
    ushort2 ov;
    ov.x = f2bf(acc[q * 2] + bf2f(xv.x));
    ov.y = f2bf(acc[q * 2 + 1] + bf2f(xv.y));
    *(ushort2*)(op + q * 128 + lane * 2) = ov;
  }
}

// ---------------------------------------------------------------------------
// MFMA bf16 GEMM (2-phase 128x128), 1-D grid + XCD swizzle (T1).
// ALL epilogues use transposed fragments (mfma(b,a) -> C^T): per frag,
//   row = row0+wr*64+jr*16+(lane&15), col = col0+wc*64+mc*16+(lane>>4)*4+reg.
// EPI 0/1/2: none / +bias / relu(+bias); split-bias at bsplit (16-aligned).
// EPI 4 (left): transposed fold (r in regs) + bf16 slice-stream (r15).
// EPI 6 (tv+gcn1 merged, Nc=896): col<768 -> Cp (stride 768); else Cbf2.
// ---------------------------------------------------------------------------
template <int EPI, int OUTBF>
__global__ __launch_bounds__(256)
void mgemm_k(const u16* __restrict__ Abf, int As, const u16* __restrict__ WT,
             const float* __restrict__ bias, const float* __restrict__ bias_b, int bsplit,
             void* __restrict__ Cp, u16* __restrict__ Cbf2,
             float* __restrict__ tmp, int M, int K, int Nc, int ncx) {
  __shared__ u16 Albuf[2][128 * 32];
  __shared__ u16 Blbuf[2][128 * 32];
  const int t = threadIdx.x;
  const int lane = t & 63;
  const int wave = t >> 6;
  const int wr = wave >> 1, wc = wave & 1;
  const int wgid = xcd_wgid();
  const int ctile = wgid % ncx;
  const int row0 = (wgid / ncx) * 128;
  const int col0 = ctile * 128;
  const int sr = t >> 2;
  const int sk = (t & 3) * 8;
  const int nt = K >> 5;

  f32x4 acc[4][4] = {};

  auto stage = [&](int buf, int k0) {
#pragma unroll
    for (int h = 0; h < 2; ++h) {
      int ar = row0 + h * 64 + sr;
      if (ar >= M) ar = M - 1;
      GLOAD16(Abf + (size_t)ar * As + k0 + sk, &Albuf[buf][h * 2048 + wave * 512]);
    }
#pragma unroll
    for (int h = 0; h < 2; ++h) {
      int bc = col0 + h * 64 + sr;
      if (bc >= Nc) bc = Nc - 1;
      GLOAD16(WT + (size_t)bc * K + k0 + sk, &Blbuf[buf][h * 2048 + wave * 512]);
    }
  };

  stage(0, 0);
  int buf = 0;
  for (int tk = 0; tk < nt; ++tk) {
    __syncthreads();
    if (tk + 1 < nt) stage(buf ^ 1, (tk + 1) << 5);
    const u16* Al = Albuf[buf];
    const u16* Bl = Blbuf[buf];
    s16x8 a[4], b[4];
#pragma unroll
    for (int m = 0; m < 4; ++m)
      a[m] = *(const s16x8*)(Al + (wr * 64 + m * 16 + (lane & 15)) * 32 + (lane >> 4) * 8);
#pragma unroll
    for (int j = 0; j < 4; ++j)
      b[j] = *(const s16x8*)(Bl + (wc * 64 + j * 16 + (lane & 15)) * 32 + (lane >> 4) * 8);
    // transposed everywhere: acc[mc][jr] = C^T frag (cols mc*16.., rows jr*16..)
#pragma unroll
    for (int mc = 0; mc < 4; ++mc)
#pragma unroll
      for (int jr = 0; jr < 4; ++jr)
        acc[mc][jr] = __builtin_amdgcn_mfma_f32_16x16x32_bf16(b[mc], a[jr], acc[mc][jr], 0, 0, 0);
    buf ^= 1;
  }

  if constexpr (EPI <= 2) {
#pragma unroll
    for (int jr = 0; jr < 4; ++jr) {
      int row = row0 + wr * 64 + jr * 16 + (lane & 15);
      if (row >= M) continue;
#pragma unroll
      for (int mc = 0; mc < 4; ++mc) {
        int colb = col0 + wc * 64 + mc * 16 + (lane >> 4) * 4;
        if (colb >= Nc) continue;
        float4 bv = make_float4(0.f, 0.f, 0.f, 0.f);
        if (EPI >= 1) {
          const float* bp = (colb < bsplit) ? bias + colb : bias_b + (colb - bsplit);
          bv = *(const float4*)bp;
        }
        float v0 = acc[mc][jr][0] + bv.x;
        float v1 = acc[mc][jr][1] + bv.y;
        float v2 = acc[mc][jr][2] + bv.z;
        float v3 = acc[mc][jr][3] + bv.w;
        if (EPI == 2) {
          v0 = fmaxf(v0, 0.f); v1 = fmaxf(v1, 0.f);
          v2 = fmaxf(v2, 0.f); v3 = fmaxf(v3, 0.f);
        }
        if (OUTBF) {
          ushort4 ov;
          ov.x = f2bf(v0); ov.y = f2bf(v1); ov.z = f2bf(v2); ov.w = f2bf(v3);
          *(ushort4*)((u16*)Cp + (size_t)row * Nc + colb) = ov;
        } else {
          *(float4*)((float*)Cp + (size_t)row * Nc + colb) = make_float4(v0, v1, v2, v3);
        }
      }
    }
  } else if constexpr (EPI == 6) {
#pragma unroll
    for (int jr = 0; jr < 4; ++jr) {
      int row = row0 + wr * 64 + jr * 16 + (lane & 15);
      if (row >= M) continue;
#pragma unroll
      for (int mc = 0; mc < 4; ++mc) {
        int colb = col0 + wc * 64 + mc * 16 + (lane >> 4) * 4;
        if (colb < 2 * FIN) {
          const float* bp = (colb < bsplit) ? bias + colb : bias_b + (colb - bsplit);
          float4 bv = *(const float4*)bp;
          ushort4 ov;
          ov.x = f2bf(acc[mc][jr][0] + bv.x);
          ov.y = f2bf(acc[mc][jr][1] + bv.y);
          ov.z = f2bf(acc[mc][jr][2] + bv.z);
          ov.w = f2bf(acc[mc][jr][3] + bv.w);
          *(ushort4*)((u16*)Cp + (size_t)row * (2 * FIN) + colb) = ov;
        } else {
          int c2 = colb - 2 * FIN;
          ushort4 ov;
          ov.x = f2bf(acc[mc][jr][0]);
          ov.y = f2bf(acc[mc][jr][1]);
          ov.z = f2bf(acc[mc][jr][2]);
          ov.w = f2bf(acc[mc][jr][3]);
          *(ushort4*)(Cbf2 + (size_t)row * HD + c2) = ov;
        }
      }
    }
  } else {  // EPI == 4: transposed fold + bf16 slice-stream (r15-verified)
    u16* slice = (u16*)Cp + (size_t)ctile * M * 8;
    float4 b4[4];
#pragma unroll
    for (int mc = 0; mc < 4; ++mc)
      b4[mc] = *(const float4*)&bias[col0 + wc * 64 + mc * 16 + (lane >> 4) * 4];
#pragma unroll
    for (int jr = 0; jr < 4; ++jr) {
      int row = row0 + wr * 64 + jr * 16 + (lane & 15);
      int rc = row < M ? row : M - 1;
      float4 tv = *(const float4*)&tmp[(size_t)rc * RD + (lane >> 4) * 4];
      ushort4 outp;
#pragma unroll
      for (int mc = 0; mc < 4; ++mc) {
        float s = (acc[mc][jr][0] + b4[mc].x) * tv.x +
                  (acc[mc][jr][1] + b4[mc].y) * tv.y +
                  (acc[mc][jr][2] + b4[mc].z) * tv.z +
                  (acc[mc][jr][3] + b4[mc].w) * tv.w;
        s += __shfl_xor(s, 16);
        s += __shfl_xor(s, 32);
        ((u16*)&outp)[mc] = f2bf(s);
      }
      if (lane < 16 && row < M)
        *(ushort4*)(slice + (size_t)row * 8 + wc * 4) = outp;
    }
  }
}

// ---------------------------------------------------------------------------
// pt gather: pt[row][ct*8+pl] = bf2f(ptP[ct][row][pl]); fp32 + bf16 outputs.
// ---------------------------------------------------------------------------
__global__ void ptgather_k(const u16* __restrict__ ptP, float* __restrict__ pt,
                           u16* __restrict__ ptb, int n) {
  int g = blockIdx.x * 256 + threadIdx.x;
  if (g >= n * 16) return;
  int row = g >> 4, ct = g & 15;
  const u16* sp = ptP + ((size_t)ct * n + (size_t)row) * 8;
  ushort4 a = ((const ushort4*)sp)[0];
  ushort4 b = ((const ushort4*)sp)[1];
  float* dp = pt + (size_t)row * PD + ct * 8;
  ((float4*)dp)[0] = make_float4(bf2f(a.x), bf2f(a.y), bf2f(a.z), bf2f(a.w));
  ((float4*)dp)[1] = make_float4(bf2f(b.x), bf2f(b.y), bf2f(b.z), bf2f(b.w));
  u16* db = ptb + (size_t)row * PD + ct * 8;
  ((ushort4*)db)[0] = a;
  ((ushort4*)db)[1] = b;
}

// ---------------------------------------------------------------------------
// Y-GEMM, 8-phase 256x256/BK=64/8-wave (T3+T4+T2+T5), race-verified (r8),
// 1-D grid + XCD swizzle (ncx=12 col-groups).
// ---------------------------------------------------------------------------
#define VM6  asm volatile("s_waitcnt vmcnt(6)" ::: "memory")
#define VM0  asm volatile("s_waitcnt vmcnt(0)" ::: "memory")
#define VMNOP
#define BARR asm volatile("s_barrier" ::: "memory")

__global__ __launch_bounds__(512)
void ygemm8_k(const u16* __restrict__ X, const u16* __restrict__ QT,
              const u16* __restrict__ Ar, float* __restrict__ tmpP, int M) {
  __shared__ u16 Al[2][16384];
  __shared__ u16 Bl[2][16384];
  const int t = threadIdx.x;
  const int lane = t & 63;
  const int wave = t >> 6;
  const int wr = wave >> 2;
  const int wcn = wave & 3;
  const int wgid = xcd_wgid();
  const int ctile = wgid % 12;
  const int row0 = (wgid / 12) * 256;
  const int col0 = ctile * 256;

  const int srow = t >> 3;
  const int sgk  = (((t & 7) ^ (srow & 7)) << 3);
  const int sdst = t * 8;

  const int pc0 = (((lane >> 4)) ^ (lane & 7)) << 3;
  const int pc1 = ((((lane >> 4) + 4)) ^ (lane & 7)) << 3;
  const int arow = (wr * 128 + (lane & 15)) << 6;
  const int brow = (wcn * 64 + (lane & 15)) << 6;

  f32x4 acc[8][4] = {};
  s16x8 a[4][2], b[4][2];

#define STGA8(bf, h, kt) do {                                                  \
    int r0_ = row0 + (h) * 128 + srow;                                         \
    int r1_ = r0_ + 64;                                                        \
    if (r0_ >= M) r0_ = M - 1;                                                 \
    if (r1_ >= M) r1_ = M - 1;                                                 \
    GLOAD16(X + (size_t)r0_ * 384 + (kt) * 64 + sgk, &Al[bf][(h) * 8192 + sdst]);        \
    GLOAD16(X + (size_t)r1_ * 384 + (kt) * 64 + sgk, &Al[bf][(h) * 8192 + 4096 + sdst]); \
  } while (0)

#define STGB8(bf, h, kt) do {                                                  \
    int c0_ = col0 + (h) * 128 + srow;                                         \
    GLOAD16(QT + (size_t)c0_ * 384 + (kt) * 64 + sgk, &Bl[bf][(h) * 8192 + sdst]);       \
    GLOAD16(QT + (size_t)(c0_ + 64) * 384 + (kt) * 64 + sgk,                   \
            &Bl[bf][(h) * 8192 + 4096 + sdst]);                                \
  } while (0)

#define LDA8(bf, mh) do {                                                      \
    _Pragma("unroll") for (int m2_ = 0; m2_ < 4; ++m2_) {                      \
      const u16* p_ = &Al[bf][arow + ((mh) * 4 + m2_) * 1024];                 \
      a[m2_][0] = *(const s16x8*)(p_ + pc0);                                   \
      a[m2_][1] = *(const s16x8*)(p_ + pc1);                                   \
    }                                                                          \
  } while (0)

#define LDB8(bf, jh) do {                                                      \
    _Pragma("unroll") for (int j2_ = 0; j2_ < 2; ++j2_) {                      \
      const u16* p_ = &Bl[bf][brow + ((jh) * 2 + j2_) * 1024];                 \
      b[(jh) * 2 + j2_][0] = *(const s16x8*)(p_ + pc0);                        \
      b[(jh) * 2 + j2_][1] = *(const s16x8*)(p_ + pc1);                        \
    }                                                                          \
  } while (0)

#define MQ8(mh, jh) do {                                                       \
    __builtin_amdgcn_s_setprio(1);                                             \
    _Pragma("unroll") for (int m2_ = 0; m2_ < 4; ++m2_)                        \
      _Pragma("unroll") for (int j2_ = 0; j2_ < 2; ++j2_)                      \
        _Pragma("unroll") for (int ks_ = 0; ks_ < 2; ++ks_)                    \
          acc[(mh) * 4 + m2_][(jh) * 2 + j2_] =                                \
              __builtin_amdgcn_mfma_f32_16x16x32_bf16(                         \
                  a[m2_][ks_], b[(jh) * 2 + j2_][ks_],                         \
                  acc[(mh) * 4 + m2_][(jh) * 2 + j2_], 0, 0, 0);               \
    __builtin_amdgcn_s_setprio(0);                                             \
  } while (0)

  STGA8(0, 0, 0); STGA8(0, 1, 0); STGB8(0, 0, 0); STGB8(0, 1, 0);
  STGA8(1, 0, 1); STGB8(1, 0, 1); STGB8(1, 1, 1);
  VM6; BARR;

#define ITER8(i, VMP3, VMP7, DOSTG)                                                          \
  /*ph0*/ LDA8(0,0); LDB8(0,0); STGA8(1,1,2*(i)+1);                   BARR; MQ8(0,0); BARR;  \
  /*ph1*/ LDB8(0,1);                                                  BARR; MQ8(0,1); BARR;  \
  /*ph2*/ LDA8(0,1); if (DOSTG) STGB8(0,0,2*(i)+2);                   BARR; MQ8(1,0); BARR;  \
  /*ph3*/ if (DOSTG) { STGB8(0,1,2*(i)+2); STGA8(0,0,2*(i)+2); } VMP3; BARR; MQ8(1,1); BARR; \
  /*ph4*/ LDA8(1,0); LDB8(1,0); if (DOSTG) STGA8(0,1,2*(i)+2);        BARR; MQ8(0,0); BARR;  \
  /*ph5*/ LDB8(1,1);                                                  BARR; MQ8(0,1); BARR;  \
  /*ph6*/ LDA8(1,1); if (DOSTG) STGB8(1,0,2*(i)+3);                   BARR; MQ8(1,0); BARR;  \
  /*ph7*/ if (DOSTG) { STGB8(1,1,2*(i)+3); STGA8(1,0,2*(i)+3); } VMP7; BARR; MQ8(1,1); BARR;

  ITER8(0, VM6, VM6, 1)
  ITER8(1, VM6, VM6, 1)
  ITER8(2, VM0, VMNOP, 0)

  // fold: s[m][rr] = sum_j relu_r[row, h0+j] * acc[m][j][rr]
  const int h0 = (col0 >> 4) + wcn * 4;
  float s[8][4];
#pragma unroll
  for (int m = 0; m < 8; ++m) {
#pragma unroll
    for (int rr = 0; rr < 4; ++rr) {
      int row = row0 + wr * 128 + m * 16 + (lane >> 4) * 4 + rr;
      int rc = row < M ? row : M - 1;
      ushort4 arv = *(const ushort4*)(Ar + (size_t)rc * 384 + h0);
      s[m][rr] = bf2f(arv.x) * acc[m][0][rr] + bf2f(arv.y) * acc[m][1][rr] +
                 bf2f(arv.z) * acc[m][2][rr] + bf2f(arv.w) * acc[m][3][rr];
    }
  }

  __syncthreads();
  float* redA = (float*)&Al[0][0];
  float* redB = redA + 4096;
  const int r16 = lane & 15;
  const int rlb = wr * 128 + (lane >> 4) * 4;
  if (wcn & 1) {
    float* red = (wcn == 1) ? redA : redB;
#pragma unroll
    for (int m = 0; m < 8; ++m)
#pragma unroll
      for (int rr = 0; rr < 4; ++rr)
        red[(rlb + m * 16 + rr) * 16 + r16] = s[m][rr];
  }
  __syncthreads();
  if (!(wcn & 1)) {
    float* red = (wcn == 0) ? redA : redB;
#pragma unroll
    for (int m = 0; m < 8; ++m)
#pragma unroll
      for (int rr = 0; rr < 4; ++rr)
        s[m][rr] += red[(rlb + m * 16 + rr) * 16 + r16];
  }
  __syncthreads();
  if (wcn == 2) {
#pragma unroll
    for (int m = 0; m < 8; ++m)
#pragma unroll
      for (int rr = 0; rr < 4; ++rr)
        redA[(rlb + m * 16 + rr) * 16 + r16] = s[m][rr];
  }
  __syncthreads();
  if (wcn == 0) {
    float* slice = tmpP + (size_t)ctile * M * RD;
#pragma unroll
    for (int m = 0; m < 8; ++m)
#pragma unroll
      for (int rr = 0; rr < 4; ++rr) {
        int row = row0 + rlb + m * 16 + rr;
        if (row < M)
          slice[(size_t)row * RD + r16] =
              s[m][rr] + redA[(rlb + m * 16 + rr) * 16 + r16];
      }
  }
#undef STGA8
#undef STGB8
#undef LDA8
#undef LDB8
#undef MQ8
#undef ITER8
}

// ---------------------------------------------------------------------------
// combine: temp[i] = sum_{s=0..12} tmpP[s][i]   (slice 12 = x@Br bias term)
// ---------------------------------------------------------------------------
__global__ void combine_k(const float* __restrict__ tmpP, float* __restrict__ temp,
                          size_t sl, int tot4) {
  int i = blockIdx.x * 256 + threadIdx.x;
  if (i >= tot4) return;
  float4 s = ((const float4*)(tmpP + 12 * sl))[i];
#pragma unroll
  for (int c = 0; c < 12; ++c) {
    float4 p = ((const float4*)(tmpP + (size_t)c * sl))[i];
    s.x += p.x; s.y += p.y; s.z += p.z; s.w += p.w;
  }
  ((float4*)temp)[i] = s;
}

// ---------------------------------------------------------------------------
// Final: in-place row-normalize p_t, p_g; alignment = dot of normalized rows.
// ---------------------------------------------------------------------------
__global__ void final_k(float* __restrict__ out, int n) {
  int node = (blockIdx.x * blockDim.x + threadIdx.x) >> 6;
  int lane = threadIdx.x & 63;
  if (node >= n) return;
  float* pt = out + n + (size_t)node * PD;
  float* pg = out + n + (size_t)n * PD + (size_t)node * PD;
  float2 t = ((float2*)pt)[lane];
  float2 g = ((float2*)pg)[lane];
  float tt = t.x * t.x + t.y * t.y;
  float gg = g.x * g.x + g.y * g.y;
  float tg = t.x * g.x + t.y * g.y;
#pragma unroll
  for (int s = 32; s >= 1; s >>= 1) {
    tt += __shfl_xor(tt, s);
    gg += __shfl_xor(gg, s);
    tg += __shfl_xor(tg, s);
  }
  float invt = 1.0f / fmaxf(sqrtf(tt), 1e-12f);
  float invg = 1.0f / fmaxf(sqrtf(gg), 1e-12f);
  ((float2*)pt)[lane] = make_float2(t.x * invt, t.y * invt);
  ((float2*)pg)[lane] = make_float2(g.x * invg, g.y * invg);
  if (lane == 0) out[node] = tg * invt * invg;
}

// ---------------------------------------------------------------------------
struct MgArgs {
  const u16* A; int As; const u16* WT;
  const float* b; const float* b2; int bsplit;
  void* C; u16* C2; float* tmp;
  int M, K, Nc;
};
template <int EPI, int OUTBF>
static void mg(const MgArgs& a, hipStream_t s) {
  int ncx = (a.Nc + 127) / 128, nry = (a.M + 127) / 128;
  mgemm_k<EPI, OUTBF><<<dim3(ncx * nry), 256, 0, s>>>(
      a.A, a.As, a.WT, a.b, a.b2, a.bsplit, a.C, a.C2, a.tmp,
      a.M, a.K, a.Nc, ncx);
}

extern "C" void kernel_launch(void* const* d_in, const int* in_sizes, int n_in,
                              void* d_out, int out_size, void* d_ws, size_t ws_size,
                              hipStream_t stream) {
  const float* x      = (const float*)d_in[0];
  const int*   ei     = (const int*)d_in[1];
  const float* W_gcn1 = (const float*)d_in[2];
  const float* b_gcn1 = (const float*)d_in[3];
  const float* W_ti   = (const float*)d_in[4];
  const float* b_ti   = (const float*)d_in[5];
  const float* W_gi   = (const float*)d_in[6];
  const float* b_gi   = (const float*)d_in[7];
  const float* W_v    = (const float*)d_in[8];
  const float* b_v    = (const float*)d_in[9];
  const float* Wl1    = (const float*)d_in[10];
  const float* bl1    = (const float*)d_in[11];
  const float* Wl2    = (const float*)d_in[12];
  const float* bl2    = (const float*)d_in[13];
  const float* Wr1    = (const float*)d_in[14];
  const float* br1    = (const float*)d_in[15];
  const float* Wr2    = (const float*)d_in[16];
  const float* br2    = (const float*)d_in[17];
  const float* W_gcn2 = (const float*)d_in[18];
  const float* b_gcn2 = (const float*)d_in[19];
  const float* W_gp   = (const float*)d_in[20];
  const float* b_gp   = (const float*)d_in[21];

  const int n = in_sizes[0] / FIN;   // 50000
  const int E = in_sizes[1] / 2;     // 500000
  const int* src = ei;
  const int* dst = ei + E;

  // -------- workspace carve (tmpP/ptP overlay gibf+xfbf) --------
  char* wsp = (char*)d_ws;
  auto carve = [&](size_t bytes) -> void* {
    void* p = (void*)wsp;
    wsp += (bytes + 255) & ~(size_t)255;
    return p;
  };
  u32* cnt      = (u32*)carve((size_t)2 * n * 4);   // [src | dst]
  u32* off      = (u32*)carve((size_t)2 * n * 4);
  u32* cur      = (u32*)carve((size_t)2 * n * 4);
  u32* bsum     = (u32*)carve(512);
  u32* adj      = (u32*)carve((size_t)2 * E * 4);   // [src-CSR dsts | dst-CSR srcs]
  float* dinv   = (float*)carve((size_t)n * 4);
  float* temp   = (float*)carve((size_t)n * RD * 4);

  u16* xbf    = (u16*)carve((size_t)n * FIN * 2);       // x bf16 (pristine)
  u16* tvbf   = (u16*)carve((size_t)n * 2 * FIN * 2);   // [t_info | v]; later lrbf
  u16* bufHbf = (u16*)carve((size_t)n * HD * 2);        // xw (both GCNs)
  u16* gembf  = (u16*)carve((size_t)n * HD * 2);
  u16* ptbf   = (u16*)carve((size_t)n * PD * 2);
  u16* g2bf   = (u16*)carve((size_t)n * HD * 2);

  // gibf and xfbf adjacent; tmpP (13 x n*16 fp32 = 41.6 MB) overlays them;
  // ptP (16 x n*8 bf16 = 12.8 MB) reuses the same region after combine.
  u16* gibf   = (u16*)carve((size_t)n * FIN * 2);       // g_info
  u16* xfbf   = (u16*)carve((size_t)n * FIN * 2);       // x_fused
  size_t tmpP_bytes = (size_t)13 * n * RD * 4;
  size_t overlay    = (size_t)2 * n * FIN * 2;
  carve(tmpP_bytes > overlay ? tmpP_bytes - overlay : 0);
  float* tmpP = (float*)gibf;
  u16* ptP    = (u16*)gibf;   // reused after combine_k (slices dead)

  u16* WtvT   = (u16*)carve((size_t)2 * FIN * FIN * 2); // [768][384]
  u16* WgcnT  = (u16*)carve((size_t)HD * FIN * 2);      // [128][384], contiguous
  u16* WgiT   = (u16*)carve((size_t)FIN * HD * 2);      // [384][128]
  u16* WlrT   = (u16*)carve((size_t)FIN * FIN * 2);     // [384][384]
  u16* Wl2T   = (u16*)carve((size_t)2048 * 192 * 2);
  u16* QT     = (u16*)carve((size_t)3072 * FIN * 2);    // permuted Wr2
  u16* BrT    = (u16*)carve((size_t)RD * FIN * 2);      // br2 reshaped [16][384]
  u16* Wgcn2T = (u16*)carve((size_t)HD * PD * 2);
  u16* WgpT   = (u16*)carve((size_t)PD * PD * 2);

  u16* lrbf = tvbf;   // [relu_l | relu_r], stride 384; tv dead after attn

  float* out    = (float*)d_out;
  float* pt_raw = out + n;
  float* pg_raw = out + n + (size_t)n * PD;
  float* g2     = out + n + (size_t)2 * n * PD;

  // 0a) coalesced converts (x, QT permute, Br copy)
  CvtDesc dsc;
  int nent = 0, blk = 0;
  auto addent = [&](const float* s, u16* d, int K, int N, int mode) {
    dsc.e[nent] = {s, d, K, N, mode, blk};
    blk += (K * N + 255) / 256;
    ++nent;
  };
  addent(x,   xbf, n * FIN, 1, 1);
  addent(Wr2, QT,  FIN, 3072, 2);
  addent(br2, BrT, RD * FIN, 1, 1);
  dsc.n = nent;
  cvt_all_k<<<blk, 256, 0, stream>>>(dsc);

  // 0b) tiled weight transposes (coalesced both sides)
  TrDesc tds;
  int tn = 0, tblk = 0;
  auto addtr = [&](const float* s, u16* d, int K, int N) {
    tds.e[tn] = {s, d, K, N, tblk};
    tblk += (K >> 5) * (N >> 5);
    ++tn;
  };
  addtr(W_ti,   WtvT,                       FIN, FIN);
  addtr(W_v,    WtvT + (size_t)FIN * FIN,   FIN, FIN);
  addtr(W_gcn1, WgcnT,                      FIN, HD);
  addtr(W_gi,   WgiT,                       HD,  FIN);
  addtr(Wl1,    WlrT,                       FIN, 192);
  addtr(Wr1,    WlrT + (size_t)192 * FIN,   FIN, 192);
  addtr(Wl2,    Wl2T,                       192, 2048);
  addtr(W_gcn2, Wgcn2T,                     PD,  HD);
  addtr(W_gp,   WgpT,                       PD,  PD);
  tds.n = tn;
  wtr_k<<<tblk, 256, 0, stream>>>(tds);

  // 1) CSR build + degrees (one concatenated scan over 2n)
  hipMemsetAsync(cnt, 0, (size_t)2 * n * 4, stream);
  hist_k<<<(E + 255) / 256, 256, 0, stream>>>(src, dst, cnt, n, E);
  int n2 = 2 * n;
  int nb = (n2 + 1023) / 1024;
  scanA_k<<<nb, 1024, 0, stream>>>(cnt, off, bsum, n2);
  scanB_k<<<1, 64, 0, stream>>>(bsum, nb);
  scanC_k<<<nb, 1024, 0, stream>>>(off, cur, bsum, n2);
  fill_k<<<(E + 255) / 256, 256, 0, stream>>>(src, dst, cur, adj, n, E);
  dinv_k<<<(n + 255) / 256, 256, 0, stream>>>(cnt + n, dinv, n);

  MgArgs a{};

  // 2+3a) merged GEMM: [t_info | v | xw_gcn1], Nc=896 (EPI 6)
  a = {xbf, FIN, WtvT, b_ti, b_v, FIN, tvbf, bufHbf, nullptr, n, FIN, 896};
  mg<6, 1>(a, stream);
  gcn_agg_k<0, 1><<<(n + 3) / 4, 256, 0, stream>>>(bufHbf, dinv, off + n, cnt + n, adj,
                                                   b_gcn1, nullptr, gembf, n);

  // 3b) g_info GEMM; fused single-pass online-softmax attention
  a = {gembf, HD, WgiT, b_gi, nullptr, 1 << 30, gibf, nullptr, nullptr, n, HD, FIN};
  mg<1, 1>(a, stream);
  attn_fused_k<<<(n + 3) / 4, 256, 0, stream>>>(off, cnt, adj, tvbf, 2 * FIN, gibf, FIN,
                                                tvbf + FIN, 2 * FIN, xbf, xfbf, n);

  // 4) Generators: [relu_l | relu_r] in one GEMM (overwrites tv buffer)
  a = {xfbf, FIN, WlrT, bl1, br1, 192, lrbf, nullptr, nullptr, n, FIN, FIN};
  mg<2, 1>(a, stream);

  // right path: x@Br into tmpP slice 12, 8-phase Y-GEMM partials into 0..11,
  // combine -> temp. (gibf/xfbf dead from here.)
  a = {xbf, FIN, BrT, nullptr, nullptr, 1 << 30, tmpP + (size_t)12 * n * RD, nullptr,
       nullptr, n, FIN, RD};
  mg<0, 0>(a, stream);
  ygemm8_k<<<dim3(12 * ((n + 255) / 256)), 512, 0, stream>>>(xbf, QT, lrbf + 192,
                                                             tmpP, n);
  combine_k<<<(n * RD / 4 + 255) / 256, 256, 0, stream>>>(tmpP, temp, (size_t)n * RD,
                                                          n * RD / 4);

  // left path fused (transposed-fragment fold): ptP[16][n][8], then gather
  a = {lrbf, FIN, Wl2T, bl2, nullptr, 1 << 30, ptP, nullptr, temp, n, 192, PD * RD};
  mg<4, 0>(a, stream);
  ptgather_k<<<(n * 16 + 255) / 256, 256, 0, stream>>>(ptP, pt_raw, ptbf, n);

  // 5) GCN2 + projection
  a = {ptbf, PD, Wgcn2T, nullptr, nullptr, 1 << 30, bufHbf, nullptr, nullptr, n, PD, HD};
  mg<0, 1>(a, stream);
  gcn_agg_k<1, 1><<<(n + 3) / 4, 256, 0, stream>>>(bufHbf, dinv, off + n, cnt + n, adj,
                                                   b_gcn2, g2, g2bf, n);
  a = {g2bf, HD, WgpT, b_gp, nullptr, 1 << 30, pg_raw, nullptr, nullptr, n, HD, PD};
  mg<1, 0>(a, stream);

  // 6) normalize + alignment
  final_k<<<(n + 3) / 4, 256, 0, stream>>>(out, n);
}